// Round 6
// baseline (529.117 us; speedup 1.0000x reference)
//
#include <hip/hip_runtime.h>
#include <hip/hip_bf16.h>

using bf16 = __hip_bfloat16;
typedef __attribute__((ext_vector_type(8))) short short8;
typedef __attribute__((ext_vector_type(4))) short short4v;
typedef __attribute__((ext_vector_type(4))) float floatx4;

#define DEVFN __device__ __forceinline__

DEVFN float bf2f(bf16 v) { return __bfloat162float(v); }
DEVFN bf16 f2bf(float v) { return __float2bfloat16(v); }
DEVFN float us2f(unsigned short u) {
    union { unsigned int i; float f; } c; c.i = ((unsigned int)u) << 16; return c.f;
}
DEVFN unsigned short f2bfbits(float v) {
    union { bf16 h; unsigned short u; } c; c.h = f2bf(v); return c.u;
}
// dtype-dispatched load: isf=1 -> fp32 buffer, isf=0 -> bf16 buffer
DEVFN float loadF(const void* p, size_t i, int isf) {
    return isf ? ((const float*)p)[i] : us2f(((const unsigned short*)p)[i]);
}
// async global->LDS, 16B per lane; lds dest = wave-uniform base + lane*16
DEVFN void gl_lds16(const bf16* g, short* l) {
    __builtin_amdgcn_global_load_lds(
        (const __attribute__((address_space(1))) unsigned int*)g,
        (__attribute__((address_space(3))) unsigned int*)l, 16, 0, 0);
}
// tanh-form GELU, overflow-safe
DEVFN float fast_gelu(float v) {
    float u = v * (0.7978845608028654f + 0.0356774081f * v * v);
    float e = __expf(2.f * u);
    float th = 1.f - 2.f / (e + 1.f);
    return 0.5f * v * (1.f + th);
}

// ---------------------------------------------------------------------------
// Detect input dtype: fp32 N(0,1) -> low halves random -> exp==0xFF hits.
__global__ __launch_bounds__(256) void detect_kernel(const void* x, int* flag)
{
    __shared__ int any;
    if (threadIdx.x == 0) any = 0;
    __syncthreads();
    const unsigned short* p = (const unsigned short*)x;
    int hit = 0;
    for (int i = threadIdx.x; i < 8192; i += 256) {
        if ((p[i] & 0x7F80u) == 0x7F80u) hit = 1;
    }
    if (hit) any = 1;
    __syncthreads();
    if (threadIdx.x == 0) flag[0] = any;
}

// ---------------------------------------------------------------------------
// Batched convert: 14 segments (12 params + ctx + geo) in ONE launch.
// Each block owns a 2048-element slice of its segment (bstart table).
struct CVTab {
    const void* src[14];
    bf16* dst[14];
    int cnt[14];
    int bstart[14];
};
__global__ __launch_bounds__(256) void convert_batch_kernel(
    CVTab tab, const int* __restrict__ flag)
{
    int isf = *flag;
    int b = blockIdx.x;
    int s = 0;
#pragma unroll
    for (int i = 1; i < 14; i++) if (b >= tab.bstart[i]) s = i;
    const void* src = tab.src[s];
    bf16* dst = tab.dst[s];
    int cnt = tab.cnt[s];
    int base = (b - tab.bstart[s]) * 2048;
    int lim = min(base + 2048, cnt);
    for (int i = base + (int)threadIdx.x; i < lim; i += 256)
        dst[i] = f2bf(loadF(src, i, isf));
}

// ---------------------------------------------------------------------------
// Fused: t[b,n,:] = x[b,:,n] (transpose) then t += LN1(t), all in one pass.
__global__ __launch_bounds__(256) void ln_in_kernel(
    const void* __restrict__ x, float* __restrict__ t,
    const bf16* __restrict__ g, const bf16* __restrict__ bta,
    const int* __restrict__ flag, int NN)
{
    __shared__ float tile[16][516];
    int isf = *flag;
    int b = blockIdx.y;
    int n0 = blockIdx.x * 16;
    int tid = threadIdx.x;
    int nx = tid & 15, cy = tid >> 4;
#pragma unroll
    for (int p = 0; p < 32; p++) {
        int c = p * 16 + cy;
        tile[nx][c] = loadF(x, ((size_t)b * 512 + c) * NN + n0 + nx, isf);
    }
    __syncthreads();
    int w = tid >> 6, lane = tid & 63;
    for (int rr = 0; rr < 4; rr++) {
        int r = w * 4 + rr;
        float4 v0 = *(const float4*)&tile[r][lane * 8];
        float4 v1 = *(const float4*)&tile[r][lane * 8 + 4];
        float vals[8] = {v0.x, v0.y, v0.z, v0.w, v1.x, v1.y, v1.z, v1.w};
        float s = 0.f;
#pragma unroll
        for (int i = 0; i < 8; i++) s += vals[i];
#pragma unroll
        for (int off = 32; off; off >>= 1) s += __shfl_xor(s, off, 64);
        float mu = s * (1.f / 512.f);
        float sq = 0.f;
#pragma unroll
        for (int i = 0; i < 8; i++) { float d = vals[i] - mu; sq += d * d; }
#pragma unroll
        for (int off = 32; off; off >>= 1) sq += __shfl_xor(sq, off, 64);
        float rs = rsqrtf(sq * (1.f / 512.f) + 1e-5f);
        float out[8];
#pragma unroll
        for (int i = 0; i < 8; i++) {
            int c = lane * 8 + i;
            out[i] = vals[i] + (vals[i] - mu) * rs * bf2f(g[c]) + bf2f(bta[c]);
        }
        float* tp = t + ((size_t)b * NN + n0 + r) * 512 + lane * 8;
        *(float4*)tp = make_float4(out[0], out[1], out[2], out[3]);
        *(float4*)(tp + 4) = make_float4(out[4], out[5], out[6], out[7]);
    }
}

// Transpose t (B,N,C) fp32 -> out (B,C,N) in the detected output dtype
__global__ __launch_bounds__(256) void transpose_out_kernel(
    const float* __restrict__ t, void* __restrict__ o, const int* __restrict__ flag,
    int C, int NN)
{
    __shared__ float tile[32][33];
    int isf = *flag;
    int b = blockIdx.z;
    int n0 = blockIdx.x * 32, c0 = blockIdx.y * 32;
    int tx = threadIdx.x, ty = threadIdx.y;
#pragma unroll
    for (int i = 0; i < 4; i++)
        tile[ty + i * 8][tx] = __builtin_nontemporal_load(
            &t[((size_t)b * NN + n0 + ty + i * 8) * C + c0 + tx]);
    __syncthreads();
#pragma unroll
    for (int i = 0; i < 4; i++) {
        size_t oi = ((size_t)b * C + c0 + ty + i * 8) * NN + n0 + tx;
        float val = tile[tx][ty + i * 8];
        if (isf) ((float*)o)[oi] = val;
        else ((bf16*)o)[oi] = f2bf(val);
    }
}

// ---------------------------------------------------------------------------
// Batched weight transpose: 10 matrices (W KxNc row-major -> WT NcxK bf16)
// in ONE launch. Block = one 32x32 tile; segment found via tstart table.
struct TWTab {
    const void* src[10];
    bf16* dst[10];
    int K[10];
    int Nc[10];
    int tstart[10];
};
__global__ __launch_bounds__(256) void transpose_w_batch(
    TWTab tab, const int* __restrict__ flag)
{
    __shared__ float tile[32][33];
    int isf = *flag;
    int b = blockIdx.x;
    int s = 0;
#pragma unroll
    for (int i = 1; i < 10; i++) if (b >= tab.tstart[i]) s = i;
    const void* Wm = tab.src[s];
    bf16* WT = tab.dst[s];
    int K = tab.K[s], Nc = tab.Nc[s];
    int lt = b - tab.tstart[s];
    int ntx = Nc >> 5;
    int n0 = (lt % ntx) * 32, k0 = (lt / ntx) * 32;
    int tx = threadIdx.x, ty = threadIdx.y;
#pragma unroll
    for (int i = 0; i < 4; i++)
        tile[ty + i * 8][tx] = loadF(Wm, (size_t)(k0 + ty + i * 8) * Nc + n0 + tx, isf);
    __syncthreads();
#pragma unroll
    for (int i = 0; i < 4; i++)
        WT[(size_t)(n0 + ty + i * 8) * K + k0 + tx] = f2bf(tile[tx][ty + i * 8]);
}

// ---------------------------------------------------------------------------
// LayerNorm over C=512: out = bf16(LN(t)). NT loads: t lines read once here.
__global__ __launch_bounds__(256) void ln_kernel(
    const float* __restrict__ t, const bf16* __restrict__ g, const bf16* __restrict__ bta,
    bf16* __restrict__ outp, int Mrows)
{
    int w = threadIdx.x >> 6, lane = threadIdx.x & 63;
    int row = blockIdx.x * 4 + w;
    if (row >= Mrows) return;
    const float* xr = t + (size_t)row * 512;
    floatx4 v0 = __builtin_nontemporal_load((const floatx4*)(xr + lane * 8));
    floatx4 v1 = __builtin_nontemporal_load((const floatx4*)(xr + lane * 8 + 4));
    float vals[8] = {v0[0], v0[1], v0[2], v0[3], v1[0], v1[1], v1[2], v1[3]};
    float s = 0.f;
#pragma unroll
    for (int i = 0; i < 8; i++) s += vals[i];
#pragma unroll
    for (int off = 32; off; off >>= 1) s += __shfl_xor(s, off, 64);
    float mu = s * (1.f / 512.f);
    float sq = 0.f;
#pragma unroll
    for (int i = 0; i < 8; i++) { float d = vals[i] - mu; sq += d * d; }
#pragma unroll
    for (int off = 32; off; off >>= 1) sq += __shfl_xor(sq, off, 64);
    float rs = rsqrtf(sq * (1.f / 512.f) + 1e-5f);
#pragma unroll
    for (int i = 0; i < 8; i++) {
        int c = lane * 8 + i;
        float y = (vals[i] - mu) * rs * bf2f(g[c]) + bf2f(bta[c]);
        outp[(size_t)row * 512 + c] = f2bf(y);
    }
}

// ---------------------------------------------------------------------------
// 64-tile GEMM pair: K and V projections share A; blockIdx.z picks weights.
template <int MODE>
__global__ __launch_bounds__(256) void gemm64x2(
    const bf16* __restrict__ A,
    const bf16* __restrict__ WT0, const bf16* __restrict__ WT1,
    bf16* __restrict__ o0, bf16* __restrict__ o1,
    int M, int K, int Nc)
{
    const bf16* WT = blockIdx.z ? WT1 : WT0;
    bf16* outp = blockIdx.z ? o1 : o0;
    __shared__ short As[64 * 32];
    __shared__ short Bs[64 * 32];
    const int tid = threadIdx.x;
    const int m0 = blockIdx.y * 64;
    const int n0 = blockIdx.x * 64;
    const int w = tid >> 6;
    const int lane = tid & 63;
    const int lm = lane & 15;
    const int lq = lane >> 4;

    floatx4 acc[4];
#pragma unroll
    for (int nb = 0; nb < 4; nb++) acc[nb] = (floatx4){0.f, 0.f, 0.f, 0.f};

    const int srow = tid >> 2;
    const int scol = (tid & 3) << 3;
    const int agrow = m0 + srow;
    const bool aok = agrow < M;
    const bf16* Aptr = A + (size_t)agrow * K + scol;
    const bf16* Bptr = WT + (size_t)(n0 + srow) * K + scol;

    for (int k0 = 0; k0 < K; k0 += 32) {
        __syncthreads();
        int4 av = make_int4(0, 0, 0, 0);
        if (aok) av = *(const int4*)(Aptr + k0);
        *(int4*)(&As[srow * 32 + scol]) = av;
        *(int4*)(&Bs[srow * 32 + scol]) = *(const int4*)(Bptr + k0);
        __syncthreads();
        short8 a = *(const short8*)(&As[(w * 16 + lm) * 32 + lq * 8]);
#pragma unroll
        for (int nb = 0; nb < 4; nb++) {
            short8 b = *(const short8*)(&Bs[(nb * 16 + lm) * 32 + lq * 8]);
            acc[nb] = __builtin_amdgcn_mfma_f32_16x16x32_bf16(a, b, acc[nb], 0, 0, 0);
        }
    }

#pragma unroll
    for (int nb = 0; nb < 4; nb++) {
        int col = n0 + nb * 16 + lm;
#pragma unroll
        for (int r = 0; r < 4; r++) {
            int row = m0 + w * 16 + lq * 4 + r;
            if (row < M) {
                float v = acc[nb][r];
                if (MODE == 1) v = fast_gelu(v);
                outp[(size_t)row * Nc + col] = f2bf(v);
            }
        }
    }
}

// ---------------------------------------------------------------------------
// m201-style 8-phase GEMM (verified round 5). BM=256, BK=64, 8 waves as
// 2M x 4N; per-wave output 128 x (CB*16). CB=4 -> BN=256, CB=2 -> BN=128.
// Per K-tile: 4 phases {ds_read A rb-pair (B in regs from P0); stage ONE
// unit into the slot that died last phase; barrier; setprio(1); CB*4 MFMA;
// setprio(0); lgkmcnt(0)+barrier}. Staging runs 2 K-tiles ahead IN-PLACE;
// boundary wait vmcnt(6)[CB4]/vmcnt(5)[CB2] once per K-tile (T4: loads stay
// in flight ACROSS barriers). sigma-swizzled LDS microformat: conflict-free
// ds_read_b128. A-staging base waves 4-7 at rows 128+8(w-4) (R4 fix).
// R6: non-temporal stores for MODE1 (hidden, 64MB write-once) and NT
// load+store for MODE2 (fp32 residual RMW) -- keeps L2 for the A/B panels.
// MODE 0: bf16 store; MODE 1: fast_gelu+bf16; MODE 2: fp32 +=.
// REQUIRES M%256==0, Nc%(CB*64)==0, K%64==0, K>=128, nwg%8==0.
#define MFMA_PAIR(RB, A00, A01, A10, A11)                                              \
    _Pragma("unroll")                                                                   \
    for (int cb = 0; cb < CB; cb++) {                                                   \
        acc[cb][RB]     = __builtin_amdgcn_mfma_f32_16x16x32_bf16(bf0[cb], A00, acc[cb][RB], 0, 0, 0);     \
        acc[cb][RB]     = __builtin_amdgcn_mfma_f32_16x16x32_bf16(bf1[cb], A01, acc[cb][RB], 0, 0, 0);     \
        acc[cb][RB + 1] = __builtin_amdgcn_mfma_f32_16x16x32_bf16(bf0[cb], A10, acc[cb][RB + 1], 0, 0, 0); \
        acc[cb][RB + 1] = __builtin_amdgcn_mfma_f32_16x16x32_bf16(bf1[cb], A11, acc[cb][RB + 1], 0, 0, 0); \
    }

template <int MODE, int CB>
__global__ __launch_bounds__(512, 2) void gemm8p(
    const bf16* __restrict__ A, const bf16* __restrict__ WT,
    const bf16* __restrict__ bias, void* __restrict__ outp,
    int K, int Nc)
{
    constexpr int BN = CB * 64;
    constexpr int ABUF = 256 * 64;   // shorts per A buffer (32 KB)
    constexpr int BBUF = BN * 64;    // shorts per B buffer
    __shared__ short As[2 * ABUF];
    __shared__ short Bs[2 * BBUF];

    const int tid = threadIdx.x;
    const int gx = gridDim.x;
    int g = blockIdx.y * gx + blockIdx.x;
    const int cpx = (gx * gridDim.y) >> 3;
    g = (g & 7) * cpx + (g >> 3);
    const int m0 = (g / gx) * 256;
    const int n0 = (g % gx) * BN;

    const int w = tid >> 6, lane = tid & 63;
    const int lm = lane & 15, lq = lane >> 4;
    const int wm = w >> 2, wn = w & 3;

    floatx4 acc[CB][8];
#pragma unroll
    for (int cb = 0; cb < CB; cb++)
#pragma unroll
        for (int rb = 0; rb < 8; rb++) acc[cb][rb] = (floatx4){0.f, 0.f, 0.f, 0.f};

    // ---- staging thread constants (pre-swizzled global source) ----
    const int rbaseA = (tid >> 3) + ((tid >= 256) ? 96 : 0);
    const int chk = (((tid & 7) ^ ((tid >> 3) & 7)) << 3);
    const bf16* pA = A + (size_t)(m0 + rbaseA) * K + chk;
    const int rbaseB = ((tid >> 7) << (CB == 4 ? 6 : 5)) + ((tid >> 3) & 15);
    const bf16* pB = WT + (size_t)(n0 + rbaseB) * K + chk;
    // LDS base: waves 0-3 stage rows 8w.. ; waves 4-7 stage rows 128+8(w-4)..
    const int wbA = w * 512 + ((w >= 4) ? 6144 : 0);
    const int wbB = (CB == 4) ? ((w >> 1) * 4096 + (w & 1) * 512)
                              : ((w >> 1) * 2048 + (w & 1) * 512);
    const size_t K32 = (size_t)K * 32;
    const size_t K16 = (size_t)K * 16;

    // ---- fragment-read constants ----
    const int arow = (wm * 128 + lm) * 64;
    const int brow = (wn * CB * 16 + lm) * 64;
    const int sl0 = ((lq ^ (lm & 7)) << 3);
    const int sl1 = (((4 + lq) ^ (lm & 7)) << 3);

    const int nt = K >> 6;

    // ---- prologue: tile0 full, tile1 minus its last A units ----
#pragma unroll
    for (int q = 0; q < 4; q++) gl_lds16(pA + (size_t)q * K32, As + q * 2048 + wbA);
    if constexpr (CB == 4) {
        gl_lds16(pB,           Bs + wbB);
        gl_lds16(pB + K16,     Bs + 1024 + wbB);
        gl_lds16(pB + 2 * K16, Bs + 2048 + wbB);
        gl_lds16(pB + 3 * K16, Bs + 3072 + wbB);
    } else {
        gl_lds16(pB,       Bs + wbB);
        gl_lds16(pB + K16, Bs + 1024 + wbB);
    }
    {
        const bf16* qA = pA + 64;
        const bf16* qB = pB + 64;
        if constexpr (CB == 4) {
            gl_lds16(qB,           Bs + BBUF + wbB);
            gl_lds16(qB + K16,     Bs + BBUF + 1024 + wbB);
            gl_lds16(qB + 2 * K16, Bs + BBUF + 2048 + wbB);
            gl_lds16(qB + 3 * K16, Bs + BBUF + 3072 + wbB);
            gl_lds16(qA,           As + ABUF + wbA);
            gl_lds16(qA + K32,     As + ABUF + 2048 + wbA);
            asm volatile("s_waitcnt vmcnt(6)\n\ts_barrier" ::: "memory");
        } else {
            gl_lds16(qB,           Bs + BBUF + wbB);
            gl_lds16(qB + K16, Bs + BBUF + 1024 + wbB);
            gl_lds16(qA,           As + ABUF + wbA);
            gl_lds16(qA + K32,     As + ABUF + 2048 + wbA);
            gl_lds16(qA + 2 * K32, As + ABUF + 4096 + wbA);
            asm volatile("s_waitcnt vmcnt(5)\n\ts_barrier" ::: "memory");
        }
    }

    for (int s = 0; s < nt; ++s) {
        const int cu = s & 1;
        const short* cA = As + cu * ABUF;
        const short* cB = Bs + cu * BBUF;
        short* oA = As + (cu ^ 1) * ABUF;   // buffer of tile s+1
        short* sA = As + cu * ABUF;         // in-place dest for tile s+2
        short* sB = Bs + cu * BBUF;
        const bf16* pA1 = pA + (s + 1) * 64;
        const bf16* pA2 = pA + (s + 2) * 64;
        const bf16* pB2 = pB + (s + 2) * 64;
        short8 bf0[CB], bf1[CB], x0, x1, y0, y1;

        // ---------------- P0: read B-all + A rb0,1; stage (s+1) last A units
#pragma unroll
        for (int cb = 0; cb < CB; cb++) {
            bf0[cb] = *(const short8*)&cB[brow + cb * 1024 + sl0];
            bf1[cb] = *(const short8*)&cB[brow + cb * 1024 + sl1];
        }
        x0 = *(const short8*)&cA[arow + sl0];
        x1 = *(const short8*)&cA[arow + sl1];
        y0 = *(const short8*)&cA[arow + 1024 + sl0];
        y1 = *(const short8*)&cA[arow + 1024 + sl1];
        if (s + 1 < nt) {
            if constexpr (CB == 4) {
                gl_lds16(pA1 + 2 * K32, oA + 2 * 2048 + wbA);
                gl_lds16(pA1 + 3 * K32, oA + 3 * 2048 + wbA);
            } else {
                gl_lds16(pA1 + 3 * K32, oA + 3 * 2048 + wbA);
            }
        }
        asm volatile("s_barrier" ::: "memory");
        __builtin_amdgcn_s_setprio(1);
        MFMA_PAIR(0, x0, x1, y0, y1)
        __builtin_amdgcn_s_setprio(0);
        asm volatile("s_waitcnt lgkmcnt(0)\n\ts_barrier" ::: "memory");

        // ---------------- P1: read A rb2,3; stage (s+2).B first two units
        x0 = *(const short8*)&cA[arow + 2 * 1024 + sl0];
        x1 = *(const short8*)&cA[arow + 2 * 1024 + sl1];
        y0 = *(const short8*)&cA[arow + 3 * 1024 + sl0];
        y1 = *(const short8*)&cA[arow + 3 * 1024 + sl1];
        if (s + 2 < nt) {
            gl_lds16(pB2,       sB + wbB);
            gl_lds16(pB2 + K16, sB + 1024 + wbB);
        }
        asm volatile("s_barrier" ::: "memory");
        __builtin_amdgcn_s_setprio(1);
        MFMA_PAIR(2, x0, x1, y0, y1)
        __builtin_amdgcn_s_setprio(0);
        asm volatile("s_waitcnt lgkmcnt(0)\n\ts_barrier" ::: "memory");

        // ---------------- P2: read A rb4,5; stage (s+2) B-u1 [CB4] / A0 [CB2]
        x0 = *(const short8*)&cA[arow + 4 * 1024 + sl0];
        x1 = *(const short8*)&cA[arow + 4 * 1024 + sl1];
        y0 = *(const short8*)&cA[arow + 5 * 1024 + sl0];
        y1 = *(const short8*)&cA[arow + 5 * 1024 + sl1];
        if (s + 2 < nt) {
            if constexpr (CB == 4) {
                gl_lds16(pB2 + 2 * K16, sB + 2048 + wbB);
                gl_lds16(pB2 + 3 * K16, sB + 3072 + wbB);
            } else {
                gl_lds16(pA2, sA + wbA);
            }
        }
        asm volatile("s_barrier" ::: "memory");
        __builtin_amdgcn_s_setprio(1);
        MFMA_PAIR(4, x0, x1, y0, y1)
        __builtin_amdgcn_s_setprio(0);
        asm volatile("s_waitcnt lgkmcnt(0)\n\ts_barrier" ::: "memory");

        // ---------------- P3: read A rb6,7; stage (s+2) early A units
        x0 = *(const short8*)&cA[arow + 6 * 1024 + sl0];
        x1 = *(const short8*)&cA[arow + 6 * 1024 + sl1];
        y0 = *(const short8*)&cA[arow + 7 * 1024 + sl0];
        y1 = *(const short8*)&cA[arow + 7 * 1024 + sl1];
        if (s + 2 < nt) {
            if constexpr (CB == 4) {
                gl_lds16(pA2,       sA + wbA);
                gl_lds16(pA2 + K32, sA + 2048 + wbA);
            } else {
                gl_lds16(pA2 + K32,     sA + 2048 + wbA);
                gl_lds16(pA2 + 2 * K32, sA + 4096 + wbA);
            }
        }
        asm volatile("s_barrier" ::: "memory");
        __builtin_amdgcn_s_setprio(1);
        MFMA_PAIR(6, x0, x1, y0, y1)
        __builtin_amdgcn_s_setprio(0);
        // K-tile boundary: counted wait -- tile s+1 fully landed, tile s+2's
        // trailing units stay in flight across the barrier.
        if (s <= nt - 3) {
            if constexpr (CB == 4)
                asm volatile("s_waitcnt vmcnt(6) lgkmcnt(0)\n\ts_barrier" ::: "memory");
            else
                asm volatile("s_waitcnt vmcnt(5) lgkmcnt(0)\n\ts_barrier" ::: "memory");
        } else if (s == nt - 2) {
            asm volatile("s_waitcnt vmcnt(0) lgkmcnt(0)\n\ts_barrier" ::: "memory");
        } else {
            asm volatile("s_waitcnt lgkmcnt(0)\n\ts_barrier" ::: "memory");
        }
    }
    __syncthreads();

    // D: out col = n0 + wn*(CB*16) + cb*16 + lq*4 + r, row = m0 + wm*128 + rb*16 + lm
    float4 bias4[CB];
#pragma unroll
    for (int cb = 0; cb < CB; cb++) {
        if (bias) {
            const bf16* bp = bias + n0 + wn * (CB * 16) + cb * 16 + lq * 4;
            bias4[cb] = make_float4(bf2f(bp[0]), bf2f(bp[1]), bf2f(bp[2]), bf2f(bp[3]));
        } else {
            bias4[cb] = make_float4(0.f, 0.f, 0.f, 0.f);
        }
    }

    if constexpr (MODE == 2) {
        float* po = (float*)outp;
#pragma unroll
        for (int rb = 0; rb < 8; rb++) {
            size_t m = m0 + wm * 128 + rb * 16 + lm;
#pragma unroll
            for (int cb = 0; cb < CB; cb++) {
                float* p = po + m * Nc + n0 + wn * (CB * 16) + cb * 16 + lq * 4;
                floatx4 f = __builtin_nontemporal_load((const floatx4*)p);
                f[0] += acc[cb][rb][0] + bias4[cb].x;
                f[1] += acc[cb][rb][1] + bias4[cb].y;
                f[2] += acc[cb][rb][2] + bias4[cb].z;
                f[3] += acc[cb][rb][3] + bias4[cb].w;
                __builtin_nontemporal_store(f, (floatx4*)p);
            }
        }
    } else if constexpr (CB == 2) {
        // direct 8B stores (qb/u outputs: re-read soon -> keep cacheable)
        unsigned short* op = (unsigned short*)outp;
#pragma unroll
        for (int rb = 0; rb < 8; rb++) {
            size_t m = m0 + wm * 128 + rb * 16 + lm;
#pragma unroll
            for (int cb = 0; cb < 2; cb++) {
                short4v pk;
#pragma unroll
                for (int r = 0; r < 4; r++) {
                    float vv = acc[cb][rb][r] + ((const float*)&bias4[cb])[r];
                    if (MODE == 1) vv = fast_gelu(vv);
                    pk[r] = (short)f2bfbits(vv);
                }
                *(short4v*)(op + m * Nc + n0 + wn * 32 + cb * 16 + lq * 4) = pk;
            }
        }
    } else {
        // LDS-staged short8 stores (reuse As after final barrier).
        // MODE 1 (64MB hidden, write-once): non-temporal.
        unsigned short* stgb = (unsigned short*)&As[w * 1024];
        unsigned short* op = (unsigned short*)outp;
#pragma unroll
        for (int rb = 0; rb < 8; rb++) {
#pragma unroll
            for (int cb = 0; cb < 4; cb++) {
                short4v pk;
#pragma unroll
                for (int r = 0; r < 4; r++) {
                    float vv = acc[cb][rb][r] + ((const float*)&bias4[cb])[r];
                    if (MODE == 1) vv = fast_gelu(vv);
                    pk[r] = (short)f2bfbits(vv);
                }
                int chunk = (cb * 2 + (lq >> 1)) ^ (lm & 7);
                *(short4v*)(&stgb[lm * 64 + chunk * 8 + (lq & 1) * 4]) = pk;
            }
#pragma unroll
            for (int p = 0; p < 2; p++) {
                int row = p * 8 + (lane >> 3);
                int chunk = lane & 7;
                short8 ov = *(const short8*)(&stgb[row * 64 + ((chunk ^ (row & 7)) * 8)]);
                size_t m = m0 + wm * 128 + rb * 16 + row;
                short8* dst = (short8*)(op + m * Nc + n0 + wn * 64 + chunk * 8);
                if (MODE == 1) __builtin_nontemporal_store(ov, dst);
                else *dst = ov;
            }
        }
    }
}

// ---------------------------------------------------------------------------
// MFMA attention. Block = one (b,h) x 64-query tile; 4 waves, 16 q each.
template <int SPAD, int SVALID>
__global__ __launch_bounds__(256) void attn_mfma_kernel(
    const bf16* __restrict__ q, const bf16* __restrict__ k, const bf16* __restrict__ v,
    bf16* __restrict__ o, int N)
{
    constexpr int MB = SPAD / 16;   // score m-blocks over s
    constexpr int KS = SPAD / 32;   // PV k-steps over s
    __shared__ unsigned short lds[SPAD * 64 + 64 * SPAD];
    unsigned short* Ks = lds;                 // [s][64], chunk-swizzled by s&7
    unsigned short* Vt = lds + SPAD * 64;     // [d][SPAD], chunk-swizzled by d&7
    unsigned short* Pw = lds;                 // alias (after barrier)

    const int tid = threadIdx.x;
    const int b = blockIdx.x >> 3;
    const int h = blockIdx.x & 7;
    const int n0 = blockIdx.y * 64;
    const int w = tid >> 6, lane = tid & 63;
    const int lm = lane & 15, lq = lane >> 4;

    const unsigned short* kp = (const unsigned short*)k;
    const unsigned short* vp = (const unsigned short*)v;
    for (int idx = tid * 8; idx < SPAD * 64; idx += 2048) {
        int s = idx >> 6, d0 = idx & 63;
        short8 kv = {0, 0, 0, 0, 0, 0, 0, 0};
        short8 vv = {0, 0, 0, 0, 0, 0, 0, 0};
        if (s < SVALID) {
            size_t gb = ((size_t)(b * SVALID + s)) * 512 + h * 64 + d0;
            kv = *(const short8*)(kp + gb);
            vv = *(const short8*)(vp + gb);
        }
        int kc = (d0 >> 3) ^ (s & 7);
        *(short8*)(&Ks[s * 64 + kc * 8]) = kv;
        const unsigned short* vvp = (const unsigned short*)&vv;
#pragma unroll
        for (int i = 0; i < 8; i++) {
            int d = d0 + i;
            int sc = (s >> 3) ^ (d & 7);
            Vt[d * SPAD + sc * 8 + (s & 7)] = vvp[i];
        }
    }

    const int q0 = n0 + w * 16;
    const unsigned short* qp = (const unsigned short*)q;
    size_t qbase = ((size_t)(b * N + q0 + lm)) * 512 + h * 64 + lq * 8;
    short8 qf0 = *(const short8*)(qp + qbase);
    short8 qf1 = *(const short8*)(qp + qbase + 32);
    __syncthreads();

    floatx4 sacc[MB];
#pragma unroll
    for (int mb = 0; mb < MB; mb++) sacc[mb] = (floatx4){0.f, 0.f, 0.f, 0.f};
#pragma unroll
    for (int mb = 0; mb < MB; mb++) {
        int srow = mb * 16 + lm;
        short8 a0 = *(const short8*)(&Ks[srow * 64 + ((lq ^ (lm & 7)) * 8)]);
        short8 a1 = *(const short8*)(&Ks[srow * 64 + (((4 + lq) ^ (lm & 7)) * 8)]);
        sacc[mb] = __builtin_amdgcn_mfma_f32_16x16x32_bf16(a0, qf0, sacc[mb], 0, 0, 0);
        sacc[mb] = __builtin_amdgcn_mfma_f32_16x16x32_bf16(a1, qf1, sacc[mb], 0, 0, 0);
    }

    float mx = -1e30f;
#pragma unroll
    for (int mb = 0; mb < MB; mb++)
#pragma unroll
        for (int r = 0; r < 4; r++) {
            int s = mb * 16 + lq * 4 + r;
            if (s < SVALID) mx = fmaxf(mx, sacc[mb][r]);
        }
    mx = fmaxf(mx, __shfl_xor(mx, 16, 64));
    mx = fmaxf(mx, __shfl_xor(mx, 32, 64));
    mx *= 0.125f;
    float sum = 0.f;
#pragma unroll
    for (int mb = 0; mb < MB; mb++)
#pragma unroll
        for (int r = 0; r < 4; r++) {
            int s = mb * 16 + lq * 4 + r;
            float e = (s < SVALID) ? __expf(sacc[mb][r] * 0.125f - mx) : 0.f;
            sacc[mb][r] = e;
            sum += e;
        }
    sum += __shfl_xor(sum, 16, 64);
    sum += __shfl_xor(sum, 32, 64);
    float inv = 1.f / sum;

    __syncthreads();

    unsigned short* Pme = Pw + w * 16 * SPAD;
#pragma unroll
    for (int mb = 0; mb < MB; mb++) {
        short4v pk;
        pk[0] = (short)f2bfbits(sacc[mb][0] * inv);
        pk[1] = (short)f2bfbits(sacc[mb][1] * inv);
        pk[2] = (short)f2bfbits(sacc[mb][2] * inv);
        pk[3] = (short)f2bfbits(sacc[mb][3] * inv);
        int chunk = (mb * 2 + (lq >> 1)) ^ (lm & 7);
        *(short4v*)(&Pme[lm * SPAD + chunk * 8 + (lq & 1) * 4]) = pk;
    }

    floatx4 oacc[4];
#pragma unroll
    for (int mb2 = 0; mb2 < 4; mb2++) oacc[mb2] = (floatx4){0.f, 0.f, 0.f, 0.f};
    for (int ks = 0; ks < KS; ks++) {
        int sch = ((ks * 4 + lq) ^ (lm & 7)) * 8;
        short8 bfrag = *(const short8*)(&Pme[lm * SPAD + sch]);
#pragma unroll
        for (int mb2 = 0; mb2 < 4; mb2++) {
            int d = mb2 * 16 + lm;
            short8 afrag = *(const short8*)(&Vt[d * SPAD + sch]);
            oacc[mb2] = __builtin_amdgcn_mfma_f32_16x16x32_bf16(afrag, bfrag, oacc[mb2], 0, 0, 0);
        }
    }

#pragma unroll
    for (int mb2 = 0; mb2 < 4; mb2++) {
        short4v ok;
        ok[0] = (short)f2bfbits(oacc[mb2][0]);
        ok[1] = (short)f2bfbits(oacc[mb2][1]);
        ok[2] = (short)f2bfbits(oacc[mb2][2]);
        ok[3] = (short)f2bfbits(oacc[mb2][3]);
        int chunk = (mb2 * 2 + (lq >> 1)) ^ (lm & 7);
        *(short4v*)(&Pme[lm * 64 + chunk * 8 + (lq & 1) * 4]) = ok;
    }
    unsigned short* op = (unsigned short*)o;
#pragma unroll
    for (int p = 0; p < 2; p++) {
        int row = p * 8 + (lane >> 3);
        int chunk = lane & 7;
        short8 ov = *(const short8*)(&Pme[row * 64 + ((chunk ^ (row & 7)) * 8)]);
        *(short8*)(op + ((size_t)(b * N + n0 + w * 16 + row)) * 512 + h * 64 + chunk * 8) = ov;
    }
}

// ---------------------------------------------------------------------------
extern "C" void kernel_launch(void* const* d_in, const int* in_sizes, int n_in,
                              void* d_out, int out_size, void* d_ws, size_t ws_size,
                              hipStream_t stream)
{
    const void* x   = d_in[0];
    const void* ctx = d_in[1];
    const void* geo = d_in[2];
    const void* g1 = d_in[3];  const void* b1 = d_in[4];
    const void* g2 = d_in[5];  const void* b2 = d_in[6];
    const void* g3 = d_in[7];  const void* b3 = d_in[8];
    const void* g4 = d_in[9];  const void* b4 = d_in[10];
    const void* cWq = d_in[11]; const void* cWk = d_in[12];
    const void* cWv = d_in[13]; const void* cWo = d_in[14];
    const void* cbo = d_in[15];
    const void* gWq = d_in[16]; const void* gWk = d_in[17];
    const void* gWv = d_in[18]; const void* gWo = d_in[19];
    const void* gbo = d_in[20];
    const void* W1 = d_in[21];  const void* bf1 = d_in[22];
    const void* W2 = d_in[23];  const void* bf2 = d_in[24];

    const int B = 4, C = 512, NN = 4096;
    const int M = B * NN;  // 16384 token rows

    char* ws = (char*)d_ws;
    size_t off = 0;
    auto alloc = [&](size_t bytes) -> void* {
        void* p = ws + off; off += (bytes + 255) & ~(size_t)255; return p;
    };
    int*   flag = (int*)alloc(256);
    float* t  = (float*)alloc((size_t)M * C * 4);        // fp32 residual stream
    bf16* u   = (bf16*)alloc((size_t)M * C * 2);         // LN out; ob aliases u
    bf16* qb  = (bf16*)alloc((size_t)M * C * 2);         // Q
    bf16* kb  = (bf16*)alloc((size_t)B * 256 * C * 2);
    bf16* vb  = (bf16*)alloc((size_t)B * 256 * C * 2);
    bf16* ctxb = (bf16*)alloc((size_t)B * 77 * 768 * 2);
    bf16* geob = (bf16*)alloc((size_t)B * 256 * 512 * 2);
    bf16* cWqT = (bf16*)alloc((size_t)512 * 512 * 2);
    bf16* cWkT = (bf16*)alloc((size_t)512 * 768 * 2);
    bf16* cWvT = (bf16*)alloc((size_t)512 * 768 * 2);
    bf16* cWoT = (bf16*)alloc((size_t)512 * 512 * 2);
    bf16* gWqT = (bf16*)alloc((size_t)512 * 512 * 2);
    bf16* gWkT = (bf16*)alloc((size_t)512 * 512 * 2);
    bf16* gWvT = (bf16*)alloc((size_t)512 * 512 * 2);
    bf16* gWoT = (bf16*)alloc((size_t)512 * 512 * 2);
    bf16* W1T  = (bf16*)alloc((size_t)2048 * 512 * 2);
    bf16* W2T  = (bf16*)alloc((size_t)512 * 2048 * 2);
    bf16* prm  = (bf16*)alloc((size_t)7680 * 2);
    bf16* ob = u;   // attention output aliases u (u dead after Q projection)

    // FFN hidden buffer: pick largest chunking the workspace allows
    int chunk;
    bf16* hb;
    size_t rem = (ws_size > off) ? (ws_size - off) : 0;
    if (rem >= (size_t)16384 * 2048 * 2) { chunk = 16384; hb = (bf16*)alloc((size_t)16384 * 2048 * 2); }
    else if (rem >= (size_t)8192 * 2048 * 2) { chunk = 8192; hb = (bf16*)alloc((size_t)8192 * 2048 * 2); }
    else { chunk = 4096; hb = qb; }  // alias qb (dead after attention)
    (void)in_sizes; (void)n_in; (void)out_size;

    // param block layout (bf16)
    bf16 *pg1 = prm, *pb1 = prm + 512, *pg2 = prm + 1024, *pb2 = prm + 1536;
    bf16 *pg3 = prm + 2048, *pb3 = prm + 2560, *pg4 = prm + 3072, *pb4 = prm + 3584;
    bf16 *pcbo = prm + 4096, *pgbo = prm + 4608, *pbf1 = prm + 5120, *pbf2 = prm + 7168;

    dim3 tb(32, 8);

    // dtype detection
    detect_kernel<<<1, 256, 0, stream>>>(x, flag);

    // ---- batched conversion: 12 params + ctx + geo in ONE launch ----
    {
        CVTab cv;
        const void* csrc[14] = {g1, b1, g2, b2, g3, b3, g4, b4, cbo, gbo, bf1, bf2, ctx, geo};
        bf16* cdst[14] = {prm, prm + 512, prm + 1024, prm + 1536, prm + 2048, prm + 2560,
                          prm + 3072, prm + 3584, prm + 4096, prm + 4608, prm + 5120,
                          prm + 7168, ctxb, geob};
        int ccnt[14] = {512, 512, 512, 512, 512, 512, 512, 512, 512, 512, 2048, 512,
                        B * 77 * 768, B * 256 * 512};
        int bacc = 0;
        for (int i = 0; i < 14; i++) {
            cv.src[i] = csrc[i]; cv.dst[i] = cdst[i]; cv.cnt[i] = ccnt[i];
            cv.bstart[i] = bacc;
            bacc += (ccnt[i] + 2047) / 2048;
        }
        convert_batch_kernel<<<bacc, 256, 0, stream>>>(cv, flag);
    }

    // fused: t = transpose(x) + LN1
    ln_in_kernel<<<dim3(NN / 16, B), 256, 0, stream>>>(x, t, pg1, pb1, flag, NN);

    // ---- batched weight transposes: 10 matrices in ONE launch ----
    {
        TWTab tw;
        const void* wsrc[10] = {cWq, cWk, cWv, cWo, gWq, gWk, gWv, gWo, W1, W2};
        bf16* wdst[10] = {cWqT, cWkT, cWvT, cWoT, gWqT, gWkT, gWvT, gWoT, W1T, W2T};
        int wK[10]  = {512, 768, 768, 512, 512, 512, 512, 512, 512, 2048};
        int wNc[10] = {512, 512, 512, 512, 512, 512, 512, 512, 2048, 512};
        int tacc = 0;
        for (int i = 0; i < 10; i++) {
            tw.src[i] = wsrc[i]; tw.dst[i] = wdst[i]; tw.K[i] = wK[i]; tw.Nc[i] = wNc[i];
            tw.tstart[i] = tacc;
            tacc += (wNc[i] / 32) * (wK[i] / 32);
        }
        transpose_w_batch<<<tacc, tb, 0, stream>>>(tw, flag);
    }

    // ---- context cross-attention ----
    ln_kernel<<<M / 4, 256, 0, stream>>>(t, pg2, pb2, u, M);
    gemm8p<0, 2><<<dim3(4, M / 256), 512, 0, stream>>>(u, cWqT, nullptr, qb, 512, 512);
    gemm64x2<0><<<dim3(8, (308 + 63) / 64, 2), 256, 0, stream>>>(ctxb, cWkT, cWvT, kb, vb, 308, 768, 512);
    attn_mfma_kernel<128, 77><<<dim3(B * 8, NN / 64), 256, 0, stream>>>(qb, kb, vb, ob, NN);
    gemm8p<2, 2><<<dim3(4, M / 256), 512, 0, stream>>>(ob, cWoT, pcbo, t, 512, 512);

    // ---- geometry cross-attention ----
    ln_kernel<<<M / 4, 256, 0, stream>>>(t, pg3, pb3, u, M);
    gemm8p<0, 2><<<dim3(4, M / 256), 512, 0, stream>>>(u, gWqT, nullptr, qb, 512, 512);
    gemm64x2<0><<<dim3(8, 1024 / 64, 2), 256, 0, stream>>>(geob, gWkT, gWvT, kb, vb, 1024, 512, 512);
    attn_mfma_kernel<256, 256><<<dim3(B * 8, NN / 64), 256, 0, stream>>>(qb, kb, vb, ob, NN);
    gemm8p<2, 2><<<dim3(4, M / 256), 512, 0, stream>>>(ob, gWoT, pgbo, t, 512, 512);

    // ---- FFN (ws-adaptive chunking) ----
    ln_kernel<<<M / 4, 256, 0, stream>>>(t, pg4, pb4, u, M);
    for (int mc = 0; mc < M / chunk; mc++) {
        bf16* uc = u + (size_t)mc * chunk * 512;
        float* tc = t + (size_t)mc * chunk * 512;
        gemm8p<1, 4><<<dim3(2048 / 256, chunk / 256), 512, 0, stream>>>(uc, W1T, pbf1, hb, 512, 2048);
        gemm8p<2, 2><<<dim3(512 / 128, chunk / 256), 512, 0, stream>>>(hb, W2T, pbf2, tc, 2048, 512);
    }

    // out = transpose(t) in detected dtype
    transpose_out_kernel<<<dim3(NN / 32, C / 32, B), tb, 0, stream>>>(t, d_out, flag, C, NN);
}

// Round 7
// 472.000 us; speedup vs baseline: 1.1210x; 1.1210x over previous
//
#include <hip/hip_runtime.h>
#include <hip/hip_bf16.h>

using bf16 = __hip_bfloat16;
typedef __attribute__((ext_vector_type(8))) short short8;
typedef __attribute__((ext_vector_type(4))) short short4v;
typedef __attribute__((ext_vector_type(4))) float floatx4;

#define DEVFN __device__ __forceinline__

DEVFN float bf2f(bf16 v) { return __bfloat162float(v); }
DEVFN bf16 f2bf(float v) { return __float2bfloat16(v); }
DEVFN float us2f(unsigned short u) {
    union { unsigned int i; float f; } c; c.i = ((unsigned int)u) << 16; return c.f;
}
DEVFN unsigned short f2bfbits(float v) {
    union { bf16 h; unsigned short u; } c; c.h = f2bf(v); return c.u;
}
// dtype-dispatched load: isf=1 -> fp32 buffer, isf=0 -> bf16 buffer
DEVFN float loadF(const void* p, size_t i, int isf) {
    return isf ? ((const float*)p)[i] : us2f(((const unsigned short*)p)[i]);
}
// async global->LDS, 16B per lane; lds dest = wave-uniform base + lane*16
DEVFN void gl_lds16(const bf16* g, short* l) {
    __builtin_amdgcn_global_load_lds(
        (const __attribute__((address_space(1))) unsigned int*)g,
        (__attribute__((address_space(3))) unsigned int*)l, 16, 0, 0);
}
// tanh-form GELU, overflow-safe
DEVFN float fast_gelu(float v) {
    float u = v * (0.7978845608028654f + 0.0356774081f * v * v);
    float e = __expf(2.f * u);
    float th = 1.f - 2.f / (e + 1.f);
    return 0.5f * v * (1.f + th);
}

// ---------------------------------------------------------------------------
// Detect input dtype: fp32 N(0,1) -> low halves random -> exp==0xFF hits.
__global__ __launch_bounds__(256) void detect_kernel(const void* x, int* flag)
{
    __shared__ int any;
    if (threadIdx.x == 0) any = 0;
    __syncthreads();
    const unsigned short* p = (const unsigned short*)x;
    int hit = 0;
    for (int i = threadIdx.x; i < 8192; i += 256) {
        if ((p[i] & 0x7F80u) == 0x7F80u) hit = 1;
    }
    if (hit) any = 1;
    __syncthreads();
    if (threadIdx.x == 0) flag[0] = any;
}

// ---------------------------------------------------------------------------
// Batched convert: 14 segments (12 params + ctx + geo) in ONE launch.
struct CVTab {
    const void* src[14];
    bf16* dst[14];
    int cnt[14];
    int bstart[14];
};
__global__ __launch_bounds__(256) void convert_batch_kernel(
    CVTab tab, const int* __restrict__ flag)
{
    int isf = *flag;
    int b = blockIdx.x;
    int s = 0;
#pragma unroll
    for (int i = 1; i < 14; i++) if (b >= tab.bstart[i]) s = i;
    const void* src = tab.src[s];
    bf16* dst = tab.dst[s];
    int cnt = tab.cnt[s];
    int base = (b - tab.bstart[s]) * 2048;
    int lim = min(base + 2048, cnt);
    for (int i = base + (int)threadIdx.x; i < lim; i += 256)
        dst[i] = f2bf(loadF(src, i, isf));
}

// ---------------------------------------------------------------------------
// Fused: t[b,n,:] = x[b,:,n] (transpose) then t += LN1(t), all in one pass.
__global__ __launch_bounds__(256) void ln_in_kernel(
    const void* __restrict__ x, float* __restrict__ t,
    const bf16* __restrict__ g, const bf16* __restrict__ bta,
    const int* __restrict__ flag, int NN)
{
    __shared__ float tile[16][516];
    int isf = *flag;
    int b = blockIdx.y;
    int n0 = blockIdx.x * 16;
    int tid = threadIdx.x;
    int nx = tid & 15, cy = tid >> 4;
#pragma unroll
    for (int p = 0; p < 32; p++) {
        int c = p * 16 + cy;
        tile[nx][c] = loadF(x, ((size_t)b * 512 + c) * NN + n0 + nx, isf);
    }
    __syncthreads();
    int w = tid >> 6, lane = tid & 63;
    for (int rr = 0; rr < 4; rr++) {
        int r = w * 4 + rr;
        float4 v0 = *(const float4*)&tile[r][lane * 8];
        float4 v1 = *(const float4*)&tile[r][lane * 8 + 4];
        float vals[8] = {v0.x, v0.y, v0.z, v0.w, v1.x, v1.y, v1.z, v1.w};
        float s = 0.f;
#pragma unroll
        for (int i = 0; i < 8; i++) s += vals[i];
#pragma unroll
        for (int off = 32; off; off >>= 1) s += __shfl_xor(s, off, 64);
        float mu = s * (1.f / 512.f);
        float sq = 0.f;
#pragma unroll
        for (int i = 0; i < 8; i++) { float d = vals[i] - mu; sq += d * d; }
#pragma unroll
        for (int off = 32; off; off >>= 1) sq += __shfl_xor(sq, off, 64);
        float rs = rsqrtf(sq * (1.f / 512.f) + 1e-5f);
        float out[8];
#pragma unroll
        for (int i = 0; i < 8; i++) {
            int c = lane * 8 + i;
            out[i] = vals[i] + (vals[i] - mu) * rs * bf2f(g[c]) + bf2f(bta[c]);
        }
        float* tp = t + ((size_t)b * NN + n0 + r) * 512 + lane * 8;
        *(float4*)tp = make_float4(out[0], out[1], out[2], out[3]);
        *(float4*)(tp + 4) = make_float4(out[4], out[5], out[6], out[7]);
    }
}

// Transpose (t + f) (B,N,C) -> out (B,C,N) in the detected output dtype.
// f = deferred FFN output (bf16), added here instead of a fp32 RMW in W2.
__global__ __launch_bounds__(256) void transpose_out_kernel(
    const float* __restrict__ t, const bf16* __restrict__ f,
    void* __restrict__ o, const int* __restrict__ flag,
    int C, int NN)
{
    __shared__ float tile[32][33];
    int isf = *flag;
    int b = blockIdx.z;
    int n0 = blockIdx.x * 32, c0 = blockIdx.y * 32;
    int tx = threadIdx.x, ty = threadIdx.y;
#pragma unroll
    for (int i = 0; i < 4; i++) {
        size_t idx = ((size_t)b * NN + n0 + ty + i * 8) * C + c0 + tx;
        tile[ty + i * 8][tx] = t[idx] + bf2f(f[idx]);
    }
    __syncthreads();
#pragma unroll
    for (int i = 0; i < 4; i++) {
        size_t oi = ((size_t)b * C + c0 + ty + i * 8) * NN + n0 + tx;
        float val = tile[tx][ty + i * 8];
        if (isf) ((float*)o)[oi] = val;
        else ((bf16*)o)[oi] = f2bf(val);
    }
}

// ---------------------------------------------------------------------------
// Batched weight transpose: 10 matrices (W KxNc row-major -> WT NcxK bf16)
struct TWTab {
    const void* src[10];
    bf16* dst[10];
    int K[10];
    int Nc[10];
    int tstart[10];
};
__global__ __launch_bounds__(256) void transpose_w_batch(
    TWTab tab, const int* __restrict__ flag)
{
    __shared__ float tile[32][33];
    int isf = *flag;
    int b = blockIdx.x;
    int s = 0;
#pragma unroll
    for (int i = 1; i < 10; i++) if (b >= tab.tstart[i]) s = i;
    const void* Wm = tab.src[s];
    bf16* WT = tab.dst[s];
    int K = tab.K[s], Nc = tab.Nc[s];
    int lt = b - tab.tstart[s];
    int ntx = Nc >> 5;
    int n0 = (lt % ntx) * 32, k0 = (lt / ntx) * 32;
    int tx = threadIdx.x, ty = threadIdx.y;
#pragma unroll
    for (int i = 0; i < 4; i++)
        tile[ty + i * 8][tx] = loadF(Wm, (size_t)(k0 + ty + i * 8) * Nc + n0 + tx, isf);
    __syncthreads();
#pragma unroll
    for (int i = 0; i < 4; i++)
        WT[(size_t)(n0 + ty + i * 8) * K + k0 + tx] = f2bf(tile[tx][ty + i * 8]);
}

// ---------------------------------------------------------------------------
// LayerNorm over C=512: out = bf16(LN(t)).
__global__ __launch_bounds__(256) void ln_kernel(
    const float* __restrict__ t, const bf16* __restrict__ g, const bf16* __restrict__ bta,
    bf16* __restrict__ outp, int Mrows)
{
    int w = threadIdx.x >> 6, lane = threadIdx.x & 63;
    int row = blockIdx.x * 4 + w;
    if (row >= Mrows) return;
    const float* xr = t + (size_t)row * 512;
    float4 v0 = *(const float4*)(xr + lane * 8);
    float4 v1 = *(const float4*)(xr + lane * 8 + 4);
    float vals[8] = {v0.x, v0.y, v0.z, v0.w, v1.x, v1.y, v1.z, v1.w};
    float s = 0.f;
#pragma unroll
    for (int i = 0; i < 8; i++) s += vals[i];
#pragma unroll
    for (int off = 32; off; off >>= 1) s += __shfl_xor(s, off, 64);
    float mu = s * (1.f / 512.f);
    float sq = 0.f;
#pragma unroll
    for (int i = 0; i < 8; i++) { float d = vals[i] - mu; sq += d * d; }
#pragma unroll
    for (int off = 32; off; off >>= 1) sq += __shfl_xor(sq, off, 64);
    float rs = rsqrtf(sq * (1.f / 512.f) + 1e-5f);
#pragma unroll
    for (int i = 0; i < 8; i++) {
        int c = lane * 8 + i;
        float y = (vals[i] - mu) * rs * bf2f(g[c]) + bf2f(bta[c]);
        outp[(size_t)row * 512 + c] = f2bf(y);
    }
}

// ---------------------------------------------------------------------------
// 64-tile GEMM pair: K and V projections share A; blockIdx.z picks weights.
template <int MODE>
__global__ __launch_bounds__(256) void gemm64x2(
    const bf16* __restrict__ A,
    const bf16* __restrict__ WT0, const bf16* __restrict__ WT1,
    bf16* __restrict__ o0, bf16* __restrict__ o1,
    int M, int K, int Nc)
{
    const bf16* WT = blockIdx.z ? WT1 : WT0;
    bf16* outp = blockIdx.z ? o1 : o0;
    __shared__ short As[64 * 32];
    __shared__ short Bs[64 * 32];
    const int tid = threadIdx.x;
    const int m0 = blockIdx.y * 64;
    const int n0 = blockIdx.x * 64;
    const int w = tid >> 6;
    const int lane = tid & 63;
    const int lm = lane & 15;
    const int lq = lane >> 4;

    floatx4 acc[4];
#pragma unroll
    for (int nb = 0; nb < 4; nb++) acc[nb] = (floatx4){0.f, 0.f, 0.f, 0.f};

    const int srow = tid >> 2;
    const int scol = (tid & 3) << 3;
    const int agrow = m0 + srow;
    const bool aok = agrow < M;
    const bf16* Aptr = A + (size_t)agrow * K + scol;
    const bf16* Bptr = WT + (size_t)(n0 + srow) * K + scol;

    for (int k0 = 0; k0 < K; k0 += 32) {
        __syncthreads();
        int4 av = make_int4(0, 0, 0, 0);
        if (aok) av = *(const int4*)(Aptr + k0);
        *(int4*)(&As[srow * 32 + scol]) = av;
        *(int4*)(&Bs[srow * 32 + scol]) = *(const int4*)(Bptr + k0);
        __syncthreads();
        short8 a = *(const short8*)(&As[(w * 16 + lm) * 32 + lq * 8]);
#pragma unroll
        for (int nb = 0; nb < 4; nb++) {
            short8 b = *(const short8*)(&Bs[(nb * 16 + lm) * 32 + lq * 8]);
            acc[nb] = __builtin_amdgcn_mfma_f32_16x16x32_bf16(a, b, acc[nb], 0, 0, 0);
        }
    }

#pragma unroll
    for (int nb = 0; nb < 4; nb++) {
        int col = n0 + nb * 16 + lm;
#pragma unroll
        for (int r = 0; r < 4; r++) {
            int row = m0 + w * 16 + lq * 4 + r;
            if (row < M) {
                float v = acc[nb][r];
                if (MODE == 1) v = fast_gelu(v);
                outp[(size_t)row * Nc + col] = f2bf(v);
            }
        }
    }
}

// ---------------------------------------------------------------------------
// m201-style 8-phase GEMM (verified round 5; NT hints reverted -- r6 showed
// NT bypasses L3 which was serving the 64MB hidden + fp32 residual across
// dispatches: W2 84us w/ NT vs ~60 without).
// BM=256, BK=64, 8 waves as 2M x 4N; per-wave 128 x (CB*16).
// 4 phases/K-tile {ds_read A rb-pair (B in regs from P0); stage ONE unit into
// the slot that died last phase; barrier; setprio(1); CB*4 MFMA; setprio(0);
// lgkmcnt(0)+barrier}. Staging 2 K-tiles ahead IN-PLACE; boundary wait
// vmcnt(6)[CB4]/vmcnt(5)[CB2] once per K-tile. sigma-swizzled LDS microformat
// (conflict-free, r2-verified). A-staging base waves 4-7 rows 128+8(w-4).
// MODE 0: bf16 store (+bias); MODE 1: fast_gelu+bf16; MODE 2: fp32 +=.
// REQUIRES M%256==0, Nc%(CB*64)==0, K%64==0, K>=128, nwg%8==0.
#define MFMA_PAIR(RB, A00, A01, A10, A11)                                              \
    _Pragma("unroll")                                                                   \
    for (int cb = 0; cb < CB; cb++) {                                                   \
        acc[cb][RB]     = __builtin_amdgcn_mfma_f32_16x16x32_bf16(bf0[cb], A00, acc[cb][RB], 0, 0, 0);     \
        acc[cb][RB]     = __builtin_amdgcn_mfma_f32_16x16x32_bf16(bf1[cb], A01, acc[cb][RB], 0, 0, 0);     \
        acc[cb][RB + 1] = __builtin_amdgcn_mfma_f32_16x16x32_bf16(bf0[cb], A10, acc[cb][RB + 1], 0, 0, 0); \
        acc[cb][RB + 1] = __builtin_amdgcn_mfma_f32_16x16x32_bf16(bf1[cb], A11, acc[cb][RB + 1], 0, 0, 0); \
    }

template <int MODE, int CB>
__global__ __launch_bounds__(512, 2) void gemm8p(
    const bf16* __restrict__ A, const bf16* __restrict__ WT,
    const bf16* __restrict__ bias, void* __restrict__ outp,
    int K, int Nc)
{
    constexpr int BN = CB * 64;
    constexpr int ABUF = 256 * 64;   // shorts per A buffer (32 KB)
    constexpr int BBUF = BN * 64;    // shorts per B buffer
    __shared__ short As[2 * ABUF];
    __shared__ short Bs[2 * BBUF];

    const int tid = threadIdx.x;
    const int gx = gridDim.x;
    int g = blockIdx.y * gx + blockIdx.x;
    const int cpx = (gx * gridDim.y) >> 3;
    g = (g & 7) * cpx + (g >> 3);
    const int m0 = (g / gx) * 256;
    const int n0 = (g % gx) * BN;

    const int w = tid >> 6, lane = tid & 63;
    const int lm = lane & 15, lq = lane >> 4;
    const int wm = w >> 2, wn = w & 3;

    floatx4 acc[CB][8];
#pragma unroll
    for (int cb = 0; cb < CB; cb++)
#pragma unroll
        for (int rb = 0; rb < 8; rb++) acc[cb][rb] = (floatx4){0.f, 0.f, 0.f, 0.f};

    // ---- staging thread constants (pre-swizzled global source) ----
    const int rbaseA = (tid >> 3) + ((tid >= 256) ? 96 : 0);
    const int chk = (((tid & 7) ^ ((tid >> 3) & 7)) << 3);
    const bf16* pA = A + (size_t)(m0 + rbaseA) * K + chk;
    const int rbaseB = ((tid >> 7) << (CB == 4 ? 6 : 5)) + ((tid >> 3) & 15);
    const bf16* pB = WT + (size_t)(n0 + rbaseB) * K + chk;
    // LDS base: waves 0-3 stage rows 8w.. ; waves 4-7 stage rows 128+8(w-4)..
    const int wbA = w * 512 + ((w >= 4) ? 6144 : 0);
    const int wbB = (CB == 4) ? ((w >> 1) * 4096 + (w & 1) * 512)
                              : ((w >> 1) * 2048 + (w & 1) * 512);
    const size_t K32 = (size_t)K * 32;
    const size_t K16 = (size_t)K * 16;

    // ---- fragment-read constants ----
    const int arow = (wm * 128 + lm) * 64;
    const int brow = (wn * CB * 16 + lm) * 64;
    const int sl0 = ((lq ^ (lm & 7)) << 3);
    const int sl1 = (((4 + lq) ^ (lm & 7)) << 3);

    const int nt = K >> 6;

    // ---- prologue: tile0 full, tile1 minus its last A units ----
#pragma unroll
    for (int q = 0; q < 4; q++) gl_lds16(pA + (size_t)q * K32, As + q * 2048 + wbA);
    if constexpr (CB == 4) {
        gl_lds16(pB,           Bs + wbB);
        gl_lds16(pB + K16,     Bs + 1024 + wbB);
        gl_lds16(pB + 2 * K16, Bs + 2048 + wbB);
        gl_lds16(pB + 3 * K16, Bs + 3072 + wbB);
    } else {
        gl_lds16(pB,       Bs + wbB);
        gl_lds16(pB + K16, Bs + 1024 + wbB);
    }
    {
        const bf16* qA = pA + 64;
        const bf16* qB = pB + 64;
        if constexpr (CB == 4) {
            gl_lds16(qB,           Bs + BBUF + wbB);
            gl_lds16(qB + K16,     Bs + BBUF + 1024 + wbB);
            gl_lds16(qB + 2 * K16, Bs + BBUF + 2048 + wbB);
            gl_lds16(qB + 3 * K16, Bs + BBUF + 3072 + wbB);
            gl_lds16(qA,           As + ABUF + wbA);
            gl_lds16(qA + K32,     As + ABUF + 2048 + wbA);
            asm volatile("s_waitcnt vmcnt(6)\n\ts_barrier" ::: "memory");
        } else {
            gl_lds16(qB,           Bs + BBUF + wbB);
            gl_lds16(qB + K16, Bs + BBUF + 1024 + wbB);
            gl_lds16(qA,           As + ABUF + wbA);
            gl_lds16(qA + K32,     As + ABUF + 2048 + wbA);
            gl_lds16(qA + 2 * K32, As + ABUF + 4096 + wbA);
            asm volatile("s_waitcnt vmcnt(5)\n\ts_barrier" ::: "memory");
        }
    }

    for (int s = 0; s < nt; ++s) {
        const int cu = s & 1;
        const short* cA = As + cu * ABUF;
        const short* cB = Bs + cu * BBUF;
        short* oA = As + (cu ^ 1) * ABUF;   // buffer of tile s+1
        short* sA = As + cu * ABUF;         // in-place dest for tile s+2
        short* sB = Bs + cu * BBUF;
        const bf16* pA1 = pA + (s + 1) * 64;
        const bf16* pA2 = pA + (s + 2) * 64;
        const bf16* pB2 = pB + (s + 2) * 64;
        short8 bf0[CB], bf1[CB], x0, x1, y0, y1;

        // ---------------- P0: read B-all + A rb0,1; stage (s+1) last A units
#pragma unroll
        for (int cb = 0; cb < CB; cb++) {
            bf0[cb] = *(const short8*)&cB[brow + cb * 1024 + sl0];
            bf1[cb] = *(const short8*)&cB[brow + cb * 1024 + sl1];
        }
        x0 = *(const short8*)&cA[arow + sl0];
        x1 = *(const short8*)&cA[arow + sl1];
        y0 = *(const short8*)&cA[arow + 1024 + sl0];
        y1 = *(const short8*)&cA[arow + 1024 + sl1];
        if (s + 1 < nt) {
            if constexpr (CB == 4) {
                gl_lds16(pA1 + 2 * K32, oA + 2 * 2048 + wbA);
                gl_lds16(pA1 + 3 * K32, oA + 3 * 2048 + wbA);
            } else {
                gl_lds16(pA1 + 3 * K32, oA + 3 * 2048 + wbA);
            }
        }
        asm volatile("s_barrier" ::: "memory");
        __builtin_amdgcn_s_setprio(1);
        MFMA_PAIR(0, x0, x1, y0, y1)
        __builtin_amdgcn_s_setprio(0);
        asm volatile("s_waitcnt lgkmcnt(0)\n\ts_barrier" ::: "memory");

        // ---------------- P1: read A rb2,3; stage (s+2).B first two units
        x0 = *(const short8*)&cA[arow + 2 * 1024 + sl0];
        x1 = *(const short8*)&cA[arow + 2 * 1024 + sl1];
        y0 = *(const short8*)&cA[arow + 3 * 1024 + sl0];
        y1 = *(const short8*)&cA[arow + 3 * 1024 + sl1];
        if (s + 2 < nt) {
            gl_lds16(pB2,       sB + wbB);
            gl_lds16(pB2 + K16, sB + 1024 + wbB);
        }
        asm volatile("s_barrier" ::: "memory");
        __builtin_amdgcn_s_setprio(1);
        MFMA_PAIR(2, x0, x1, y0, y1)
        __builtin_amdgcn_s_setprio(0);
        asm volatile("s_waitcnt lgkmcnt(0)\n\ts_barrier" ::: "memory");

        // ---------------- P2: read A rb4,5; stage (s+2) B-u1 [CB4] / A0 [CB2]
        x0 = *(const short8*)&cA[arow + 4 * 1024 + sl0];
        x1 = *(const short8*)&cA[arow + 4 * 1024 + sl1];
        y0 = *(const short8*)&cA[arow + 5 * 1024 + sl0];
        y1 = *(const short8*)&cA[arow + 5 * 1024 + sl1];
        if (s + 2 < nt) {
            if constexpr (CB == 4) {
                gl_lds16(pB2 + 2 * K16, sB + 2048 + wbB);
                gl_lds16(pB2 + 3 * K16, sB + 3072 + wbB);
            } else {
                gl_lds16(pA2, sA + wbA);
            }
        }
        asm volatile("s_barrier" ::: "memory");
        __builtin_amdgcn_s_setprio(1);
        MFMA_PAIR(4, x0, x1, y0, y1)
        __builtin_amdgcn_s_setprio(0);
        asm volatile("s_waitcnt lgkmcnt(0)\n\ts_barrier" ::: "memory");

        // ---------------- P3: read A rb6,7; stage (s+2) early A units
        x0 = *(const short8*)&cA[arow + 6 * 1024 + sl0];
        x1 = *(const short8*)&cA[arow + 6 * 1024 + sl1];
        y0 = *(const short8*)&cA[arow + 7 * 1024 + sl0];
        y1 = *(const short8*)&cA[arow + 7 * 1024 + sl1];
        if (s + 2 < nt) {
            if constexpr (CB == 4) {
                gl_lds16(pA2,       sA + wbA);
                gl_lds16(pA2 + K32, sA + 2048 + wbA);
            } else {
                gl_lds16(pA2 + K32,     sA + 2048 + wbA);
                gl_lds16(pA2 + 2 * K32, sA + 4096 + wbA);
            }
        }
        asm volatile("s_barrier" ::: "memory");
        __builtin_amdgcn_s_setprio(1);
        MFMA_PAIR(6, x0, x1, y0, y1)
        __builtin_amdgcn_s_setprio(0);
        // K-tile boundary: counted wait -- tile s+1 fully landed, tile s+2's
        // trailing units stay in flight across the barrier.
        if (s <= nt - 3) {
            if constexpr (CB == 4)
                asm volatile("s_waitcnt vmcnt(6) lgkmcnt(0)\n\ts_barrier" ::: "memory");
            else
                asm volatile("s_waitcnt vmcnt(5) lgkmcnt(0)\n\ts_barrier" ::: "memory");
        } else if (s == nt - 2) {
            asm volatile("s_waitcnt vmcnt(0) lgkmcnt(0)\n\ts_barrier" ::: "memory");
        } else {
            asm volatile("s_waitcnt lgkmcnt(0)\n\ts_barrier" ::: "memory");
        }
    }
    __syncthreads();

    // D: out col = n0 + wn*(CB*16) + cb*16 + lq*4 + r, row = m0 + wm*128 + rb*16 + lm
    float4 bias4[CB];
#pragma unroll
    for (int cb = 0; cb < CB; cb++) {
        if (bias) {
            const bf16* bp = bias + n0 + wn * (CB * 16) + cb * 16 + lq * 4;
            bias4[cb] = make_float4(bf2f(bp[0]), bf2f(bp[1]), bf2f(bp[2]), bf2f(bp[3]));
        } else {
            bias4[cb] = make_float4(0.f, 0.f, 0.f, 0.f);
        }
    }

    if constexpr (MODE == 2) {
        float* po = (float*)outp;
#pragma unroll
        for (int rb = 0; rb < 8; rb++) {
            size_t m = m0 + wm * 128 + rb * 16 + lm;
#pragma unroll
            for (int cb = 0; cb < CB; cb++) {
                float* p = po + m * Nc + n0 + wn * (CB * 16) + cb * 16 + lq * 4;
                float4 f = *(float4*)p;
                f.x += acc[cb][rb][0] + bias4[cb].x;
                f.y += acc[cb][rb][1] + bias4[cb].y;
                f.z += acc[cb][rb][2] + bias4[cb].z;
                f.w += acc[cb][rb][3] + bias4[cb].w;
                *(float4*)p = f;
            }
        }
    } else if constexpr (CB == 2) {
        // direct 8B stores
        unsigned short* op = (unsigned short*)outp;
#pragma unroll
        for (int rb = 0; rb < 8; rb++) {
            size_t m = m0 + wm * 128 + rb * 16 + lm;
#pragma unroll
            for (int cb = 0; cb < 2; cb++) {
                short4v pk;
#pragma unroll
                for (int r = 0; r < 4; r++) {
                    float vv = acc[cb][rb][r] + ((const float*)&bias4[cb])[r];
                    if (MODE == 1) vv = fast_gelu(vv);
                    pk[r] = (short)f2bfbits(vv);
                }
                *(short4v*)(op + m * Nc + n0 + wn * 32 + cb * 16 + lq * 4) = pk;
            }
        }
    } else {
        // LDS-staged short8 stores (reuse As after final barrier)
        unsigned short* stgb = (unsigned short*)&As[w * 1024];
        unsigned short* op = (unsigned short*)outp;
#pragma unroll
        for (int rb = 0; rb < 8; rb++) {
#pragma unroll
            for (int cb = 0; cb < 4; cb++) {
                short4v pk;
#pragma unroll
                for (int r = 0; r < 4; r++) {
                    float vv = acc[cb][rb][r] + ((const float*)&bias4[cb])[r];
                    if (MODE == 1) vv = fast_gelu(vv);
                    pk[r] = (short)f2bfbits(vv);
                }
                int chunk = (cb * 2 + (lq >> 1)) ^ (lm & 7);
                *(short4v*)(&stgb[lm * 64 + chunk * 8 + (lq & 1) * 4]) = pk;
            }
#pragma unroll
            for (int p = 0; p < 2; p++) {
                int row = p * 8 + (lane >> 3);
                int chunk = lane & 7;
                short8 ov = *(const short8*)(&stgb[row * 64 + ((chunk ^ (row & 7)) * 8)]);
                size_t m = m0 + wm * 128 + rb * 16 + row;
                *(short8*)(op + m * Nc + n0 + wn * 64 + chunk * 8) = ov;
            }
        }
    }
}

// ---------------------------------------------------------------------------
// MFMA attention. Block = one (b,h) x 64-query tile; 4 waves, 16 q each.
template <int SPAD, int SVALID>
__global__ __launch_bounds__(256) void attn_mfma_kernel(
    const bf16* __restrict__ q, const bf16* __restrict__ k, const bf16* __restrict__ v,
    bf16* __restrict__ o, int N)
{
    constexpr int MB = SPAD / 16;   // score m-blocks over s
    constexpr int KS = SPAD / 32;   // PV k-steps over s
    __shared__ unsigned short lds[SPAD * 64 + 64 * SPAD];
    unsigned short* Ks = lds;                 // [s][64], chunk-swizzled by s&7
    unsigned short* Vt = lds + SPAD * 64;     // [d][SPAD], chunk-swizzled by d&7
    unsigned short* Pw = lds;                 // alias (after barrier)

    const int tid = threadIdx.x;
    const int b = blockIdx.x >> 3;
    const int h = blockIdx.x & 7;
    const int n0 = blockIdx.y * 64;
    const int w = tid >> 6, lane = tid & 63;
    const int lm = lane & 15, lq = lane >> 4;

    const unsigned short* kp = (const unsigned short*)k;
    const unsigned short* vp = (const unsigned short*)v;
    for (int idx = tid * 8; idx < SPAD * 64; idx += 2048) {
        int s = idx >> 6, d0 = idx & 63;
        short8 kv = {0, 0, 0, 0, 0, 0, 0, 0};
        short8 vv = {0, 0, 0, 0, 0, 0, 0, 0};
        if (s < SVALID) {
            size_t gb = ((size_t)(b * SVALID + s)) * 512 + h * 64 + d0;
            kv = *(const short8*)(kp + gb);
            vv = *(const short8*)(vp + gb);
        }
        int kc = (d0 >> 3) ^ (s & 7);
        *(short8*)(&Ks[s * 64 + kc * 8]) = kv;
        const unsigned short* vvp = (const unsigned short*)&vv;
#pragma unroll
        for (int i = 0; i < 8; i++) {
            int d = d0 + i;
            int sc = (s >> 3) ^ (d & 7);
            Vt[d * SPAD + sc * 8 + (s & 7)] = vvp[i];
        }
    }

    const int q0 = n0 + w * 16;
    const unsigned short* qp = (const unsigned short*)q;
    size_t qbase = ((size_t)(b * N + q0 + lm)) * 512 + h * 64 + lq * 8;
    short8 qf0 = *(const short8*)(qp + qbase);
    short8 qf1 = *(const short8*)(qp + qbase + 32);
    __syncthreads();

    floatx4 sacc[MB];
#pragma unroll
    for (int mb = 0; mb < MB; mb++) sacc[mb] = (floatx4){0.f, 0.f, 0.f, 0.f};
#pragma unroll
    for (int mb = 0; mb < MB; mb++) {
        int srow = mb * 16 + lm;
        short8 a0 = *(const short8*)(&Ks[srow * 64 + ((lq ^ (lm & 7)) * 8)]);
        short8 a1 = *(const short8*)(&Ks[srow * 64 + (((4 + lq) ^ (lm & 7)) * 8)]);
        sacc[mb] = __builtin_amdgcn_mfma_f32_16x16x32_bf16(a0, qf0, sacc[mb], 0, 0, 0);
        sacc[mb] = __builtin_amdgcn_mfma_f32_16x16x32_bf16(a1, qf1, sacc[mb], 0, 0, 0);
    }

    float mx = -1e30f;
#pragma unroll
    for (int mb = 0; mb < MB; mb++)
#pragma unroll
        for (int r = 0; r < 4; r++) {
            int s = mb * 16 + lq * 4 + r;
            if (s < SVALID) mx = fmaxf(mx, sacc[mb][r]);
        }
    mx = fmaxf(mx, __shfl_xor(mx, 16, 64));
    mx = fmaxf(mx, __shfl_xor(mx, 32, 64));
    mx *= 0.125f;
    float sum = 0.f;
#pragma unroll
    for (int mb = 0; mb < MB; mb++)
#pragma unroll
        for (int r = 0; r < 4; r++) {
            int s = mb * 16 + lq * 4 + r;
            float e = (s < SVALID) ? __expf(sacc[mb][r] * 0.125f - mx) : 0.f;
            sacc[mb][r] = e;
            sum += e;
        }
    sum += __shfl_xor(sum, 16, 64);
    sum += __shfl_xor(sum, 32, 64);
    float inv = 1.f / sum;

    __syncthreads();

    unsigned short* Pme = Pw + w * 16 * SPAD;
#pragma unroll
    for (int mb = 0; mb < MB; mb++) {
        short4v pk;
        pk[0] = (short)f2bfbits(sacc[mb][0] * inv);
        pk[1] = (short)f2bfbits(sacc[mb][1] * inv);
        pk[2] = (short)f2bfbits(sacc[mb][2] * inv);
        pk[3] = (short)f2bfbits(sacc[mb][3] * inv);
        int chunk = (mb * 2 + (lq >> 1)) ^ (lm & 7);
        *(short4v*)(&Pme[lm * SPAD + chunk * 8 + (lq & 1) * 4]) = pk;
    }

    floatx4 oacc[4];
#pragma unroll
    for (int mb2 = 0; mb2 < 4; mb2++) oacc[mb2] = (floatx4){0.f, 0.f, 0.f, 0.f};
    for (int ks = 0; ks < KS; ks++) {
        int sch = ((ks * 4 + lq) ^ (lm & 7)) * 8;
        short8 bfrag = *(const short8*)(&Pme[lm * SPAD + sch]);
#pragma unroll
        for (int mb2 = 0; mb2 < 4; mb2++) {
            int d = mb2 * 16 + lm;
            short8 afrag = *(const short8*)(&Vt[d * SPAD + sch]);
            oacc[mb2] = __builtin_amdgcn_mfma_f32_16x16x32_bf16(afrag, bfrag, oacc[mb2], 0, 0, 0);
        }
    }

#pragma unroll
    for (int mb2 = 0; mb2 < 4; mb2++) {
        short4v ok;
        ok[0] = (short)f2bfbits(oacc[mb2][0]);
        ok[1] = (short)f2bfbits(oacc[mb2][1]);
        ok[2] = (short)f2bfbits(oacc[mb2][2]);
        ok[3] = (short)f2bfbits(oacc[mb2][3]);
        int chunk = (mb2 * 2 + (lq >> 1)) ^ (lm & 7);
        *(short4v*)(&Pme[lm * 64 + chunk * 8 + (lq & 1) * 4]) = ok;
    }
    unsigned short* op = (unsigned short*)o;
#pragma unroll
    for (int p = 0; p < 2; p++) {
        int row = p * 8 + (lane >> 3);
        int chunk = lane & 7;
        short8 ov = *(const short8*)(&Pme[row * 64 + ((chunk ^ (row & 7)) * 8)]);
        *(short8*)(op + ((size_t)(b * N + n0 + w * 16 + row)) * 512 + h * 64 + chunk * 8) = ov;
    }
}

// ---------------------------------------------------------------------------
extern "C" void kernel_launch(void* const* d_in, const int* in_sizes, int n_in,
                              void* d_out, int out_size, void* d_ws, size_t ws_size,
                              hipStream_t stream)
{
    const void* x   = d_in[0];
    const void* ctx = d_in[1];
    const void* geo = d_in[2];
    const void* g1 = d_in[3];  const void* b1 = d_in[4];
    const void* g2 = d_in[5];  const void* b2 = d_in[6];
    const void* g3 = d_in[7];  const void* b3 = d_in[8];
    const void* g4 = d_in[9];  const void* b4 = d_in[10];
    const void* cWq = d_in[11]; const void* cWk = d_in[12];
    const void* cWv = d_in[13]; const void* cWo = d_in[14];
    const void* cbo = d_in[15];
    const void* gWq = d_in[16]; const void* gWk = d_in[17];
    const void* gWv = d_in[18]; const void* gWo = d_in[19];
    const void* gbo = d_in[20];
    const void* W1 = d_in[21];  const void* bf1 = d_in[22];
    const void* W2 = d_in[23];  const void* bf2 = d_in[24];

    const int B = 4, C = 512, NN = 4096;
    const int M = B * NN;  // 16384 token rows

    char* ws = (char*)d_ws;
    size_t off = 0;
    auto alloc = [&](size_t bytes) -> void* {
        void* p = ws + off; off += (bytes + 255) & ~(size_t)255; return p;
    };
    int*   flag = (int*)alloc(256);
    float* t  = (float*)alloc((size_t)M * C * 4);        // fp32 residual stream
    bf16* u   = (bf16*)alloc((size_t)M * C * 2);         // LN out; ob aliases u
    bf16* qb  = (bf16*)alloc((size_t)M * C * 2);         // Q
    bf16* fb  = (bf16*)alloc((size_t)M * C * 2);         // deferred FFN output
    bf16* kb  = (bf16*)alloc((size_t)B * 256 * C * 2);
    bf16* vb  = (bf16*)alloc((size_t)B * 256 * C * 2);
    bf16* ctxb = (bf16*)alloc((size_t)B * 77 * 768 * 2);
    bf16* geob = (bf16*)alloc((size_t)B * 256 * 512 * 2);
    bf16* cWqT = (bf16*)alloc((size_t)512 * 512 * 2);
    bf16* cWkT = (bf16*)alloc((size_t)512 * 768 * 2);
    bf16* cWvT = (bf16*)alloc((size_t)512 * 768 * 2);
    bf16* cWoT = (bf16*)alloc((size_t)512 * 512 * 2);
    bf16* gWqT = (bf16*)alloc((size_t)512 * 512 * 2);
    bf16* gWkT = (bf16*)alloc((size_t)512 * 512 * 2);
    bf16* gWvT = (bf16*)alloc((size_t)512 * 512 * 2);
    bf16* gWoT = (bf16*)alloc((size_t)512 * 512 * 2);
    bf16* W1T  = (bf16*)alloc((size_t)2048 * 512 * 2);
    bf16* W2T  = (bf16*)alloc((size_t)512 * 2048 * 2);
    bf16* prm  = (bf16*)alloc((size_t)7680 * 2);
    bf16* ob = u;   // attention output aliases u (u dead after Q projection)

    // FFN hidden buffer: pick largest chunking the workspace allows
    int chunk;
    bf16* hb;
    size_t rem = (ws_size > off) ? (ws_size - off) : 0;
    if (rem >= (size_t)16384 * 2048 * 2) { chunk = 16384; hb = (bf16*)alloc((size_t)16384 * 2048 * 2); }
    else if (rem >= (size_t)8192 * 2048 * 2) { chunk = 8192; hb = (bf16*)alloc((size_t)8192 * 2048 * 2); }
    else { chunk = 4096; hb = qb; }  // alias qb (dead after attention)
    (void)in_sizes; (void)n_in; (void)out_size;

    // param block layout (bf16)
    bf16 *pg1 = prm, *pb1 = prm + 512, *pg2 = prm + 1024, *pb2 = prm + 1536;
    bf16 *pg3 = prm + 2048, *pb3 = prm + 2560, *pg4 = prm + 3072, *pb4 = prm + 3584;
    bf16 *pcbo = prm + 4096, *pgbo = prm + 4608, *pbf1 = prm + 5120, *pbf2 = prm + 7168;

    dim3 tb(32, 8);

    // dtype detection
    detect_kernel<<<1, 256, 0, stream>>>(x, flag);

    // ---- batched conversion: 12 params + ctx + geo in ONE launch ----
    {
        CVTab cv;
        const void* csrc[14] = {g1, b1, g2, b2, g3, b3, g4, b4, cbo, gbo, bf1, bf2, ctx, geo};
        bf16* cdst[14] = {prm, prm + 512, prm + 1024, prm + 1536, prm + 2048, prm + 2560,
                          prm + 3072, prm + 3584, prm + 4096, prm + 4608, prm + 5120,
                          prm + 7168, ctxb, geob};
        int ccnt[14] = {512, 512, 512, 512, 512, 512, 512, 512, 512, 512, 2048, 512,
                        B * 77 * 768, B * 256 * 512};
        int bacc = 0;
        for (int i = 0; i < 14; i++) {
            cv.src[i] = csrc[i]; cv.dst[i] = cdst[i]; cv.cnt[i] = ccnt[i];
            cv.bstart[i] = bacc;
            bacc += (ccnt[i] + 2047) / 2048;
        }
        convert_batch_kernel<<<bacc, 256, 0, stream>>>(cv, flag);
    }

    // fused: t = transpose(x) + LN1
    ln_in_kernel<<<dim3(NN / 16, B), 256, 0, stream>>>(x, t, pg1, pb1, flag, NN);

    // ---- batched weight transposes: 10 matrices in ONE launch ----
    {
        TWTab tw;
        const void* wsrc[10] = {cWq, cWk, cWv, cWo, gWq, gWk, gWv, gWo, W1, W2};
        bf16* wdst[10] = {cWqT, cWkT, cWvT, cWoT, gWqT, gWkT, gWvT, gWoT, W1T, W2T};
        int wK[10]  = {512, 768, 768, 512, 512, 512, 512, 512, 512, 2048};
        int wNc[10] = {512, 512, 512, 512, 512, 512, 512, 512, 2048, 512};
        int tacc = 0;
        for (int i = 0; i < 10; i++) {
            tw.src[i] = wsrc[i]; tw.dst[i] = wdst[i]; tw.K[i] = wK[i]; tw.Nc[i] = wNc[i];
            tw.tstart[i] = tacc;
            tacc += (wNc[i] / 32) * (wK[i] / 32);
        }
        transpose_w_batch<<<tacc, tb, 0, stream>>>(tw, flag);
    }

    // ---- context cross-attention ----
    ln_kernel<<<M / 4, 256, 0, stream>>>(t, pg2, pb2, u, M);
    gemm8p<0, 2><<<dim3(4, M / 256), 512, 0, stream>>>(u, cWqT, nullptr, qb, 512, 512);
    gemm64x2<0><<<dim3(8, (308 + 63) / 64, 2), 256, 0, stream>>>(ctxb, cWkT, cWvT, kb, vb, 308, 768, 512);
    attn_mfma_kernel<128, 77><<<dim3(B * 8, NN / 64), 256, 0, stream>>>(qb, kb, vb, ob, NN);
    gemm8p<2, 2><<<dim3(4, M / 256), 512, 0, stream>>>(ob, cWoT, pcbo, t, 512, 512);

    // ---- geometry cross-attention ----
    ln_kernel<<<M / 4, 256, 0, stream>>>(t, pg3, pb3, u, M);
    gemm8p<0, 2><<<dim3(4, M / 256), 512, 0, stream>>>(u, gWqT, nullptr, qb, 512, 512);
    gemm64x2<0><<<dim3(8, 1024 / 64, 2), 256, 0, stream>>>(geob, gWkT, gWvT, kb, vb, 1024, 512, 512);
    attn_mfma_kernel<256, 256><<<dim3(B * 8, NN / 64), 256, 0, stream>>>(qb, kb, vb, ob, NN);
    gemm8p<2, 2><<<dim3(4, M / 256), 512, 0, stream>>>(ob, gWoT, pgbo, t, 512, 512);

    // ---- FFN (ws-adaptive chunking); W2 -> bf16 fb, residual add deferred
    // to transpose_out (saves the 64MB fp32 RMW on t).
    ln_kernel<<<M / 4, 256, 0, stream>>>(t, pg4, pb4, u, M);
    for (int mc = 0; mc < M / chunk; mc++) {
        bf16* uc = u + (size_t)mc * chunk * 512;
        bf16* fc = fb + (size_t)mc * chunk * 512;
        gemm8p<1, 4><<<dim3(2048 / 256, chunk / 256), 512, 0, stream>>>(uc, W1T, pbf1, hb, 512, 2048);
        gemm8p<0, 2><<<dim3(512 / 128, chunk / 256), 512, 0, stream>>>(hb, W2T, pbf2, fc, 2048, 512);
    }

    // out = transpose(t + fb) in detected dtype
    transpose_out_kernel<<<dim3(NN / 32, C / 32, B), tb, 0, stream>>>(t, fb, d_out, flag, C, NN);
}

// Round 8
// 470.072 us; speedup vs baseline: 1.1256x; 1.0041x over previous
//
#include <hip/hip_runtime.h>
#include <hip/hip_bf16.h>

using bf16 = __hip_bfloat16;
typedef __attribute__((ext_vector_type(8))) short short8;
typedef __attribute__((ext_vector_type(4))) short short4v;
typedef __attribute__((ext_vector_type(4))) float floatx4;

#define DEVFN __device__ __forceinline__

DEVFN float bf2f(bf16 v) { return __bfloat162float(v); }
DEVFN bf16 f2bf(float v) { return __float2bfloat16(v); }
DEVFN float us2f(unsigned short u) {
    union { unsigned int i; float f; } c; c.i = ((unsigned int)u) << 16; return c.f;
}
DEVFN unsigned short f2bfbits(float v) {
    union { bf16 h; unsigned short u; } c; c.h = f2bf(v); return c.u;
}
// dtype-dispatched load: isf=1 -> fp32 buffer, isf=0 -> bf16 buffer
DEVFN float loadF(const void* p, size_t i, int isf) {
    return isf ? ((const float*)p)[i] : us2f(((const unsigned short*)p)[i]);
}
// async global->LDS, 16B per lane; lds dest = wave-uniform base + lane*16
DEVFN void gl_lds16(const bf16* g, short* l) {
    __builtin_amdgcn_global_load_lds(
        (const __attribute__((address_space(1))) unsigned int*)g,
        (__attribute__((address_space(3))) unsigned int*)l, 16, 0, 0);
}
// tanh-form GELU, overflow-safe
DEVFN float fast_gelu(float v) {
    float u = v * (0.7978845608028654f + 0.0356774081f * v * v);
    float e = __expf(2.f * u);
    float th = 1.f - 2.f / (e + 1.f);
    return 0.5f * v * (1.f + th);
}

// ---------------------------------------------------------------------------
// Detect input dtype: fp32 N(0,1) -> low halves random -> exp==0xFF hits.
__global__ __launch_bounds__(256) void detect_kernel(const void* x, int* flag)
{
    __shared__ int any;
    if (threadIdx.x == 0) any = 0;
    __syncthreads();
    const unsigned short* p = (const unsigned short*)x;
    int hit = 0;
    for (int i = threadIdx.x; i < 8192; i += 256) {
        if ((p[i] & 0x7F80u) == 0x7F80u) hit = 1;
    }
    if (hit) any = 1;
    __syncthreads();
    if (threadIdx.x == 0) flag[0] = any;
}

// ---------------------------------------------------------------------------
// Batched convert: 14 segments (12 params + ctx + geo) in ONE launch.
struct CVTab {
    const void* src[14];
    bf16* dst[14];
    int cnt[14];
    int bstart[14];
};
__global__ __launch_bounds__(256) void convert_batch_kernel(
    CVTab tab, const int* __restrict__ flag)
{
    int isf = *flag;
    int b = blockIdx.x;
    int s = 0;
#pragma unroll
    for (int i = 1; i < 14; i++) if (b >= tab.bstart[i]) s = i;
    const void* src = tab.src[s];
    bf16* dst = tab.dst[s];
    int cnt = tab.cnt[s];
    int base = (b - tab.bstart[s]) * 2048;
    int lim = min(base + 2048, cnt);
    for (int i = base + (int)threadIdx.x; i < lim; i += 256)
        dst[i] = f2bf(loadF(src, i, isf));
}

// ---------------------------------------------------------------------------
// Fused: t[b,n,:] = x[b,:,n] + LN1(x_row)  AND  u = bf16(LN2(t_row)).
// Rows are complete in registers, so the second LN is ~free (removes the
// standalone ln#1 dispatch, 80MB).
__global__ __launch_bounds__(256) void ln_in_kernel(
    const void* __restrict__ x, float* __restrict__ t,
    const bf16* __restrict__ g1c, const bf16* __restrict__ b1c,
    const bf16* __restrict__ g2c, const bf16* __restrict__ b2c,
    bf16* __restrict__ u,
    const int* __restrict__ flag, int NN)
{
    __shared__ float tile[16][516];
    int isf = *flag;
    int b = blockIdx.y;
    int n0 = blockIdx.x * 16;
    int tid = threadIdx.x;
    int nx = tid & 15, cy = tid >> 4;
#pragma unroll
    for (int p = 0; p < 32; p++) {
        int c = p * 16 + cy;
        tile[nx][c] = loadF(x, ((size_t)b * 512 + c) * NN + n0 + nx, isf);
    }
    __syncthreads();
    int w = tid >> 6, lane = tid & 63;
    for (int rr = 0; rr < 4; rr++) {
        int r = w * 4 + rr;
        float4 v0 = *(const float4*)&tile[r][lane * 8];
        float4 v1 = *(const float4*)&tile[r][lane * 8 + 4];
        float vals[8] = {v0.x, v0.y, v0.z, v0.w, v1.x, v1.y, v1.z, v1.w};
        float s = 0.f;
#pragma unroll
        for (int i = 0; i < 8; i++) s += vals[i];
#pragma unroll
        for (int off = 32; off; off >>= 1) s += __shfl_xor(s, off, 64);
        float mu = s * (1.f / 512.f);
        float sq = 0.f;
#pragma unroll
        for (int i = 0; i < 8; i++) { float d = vals[i] - mu; sq += d * d; }
#pragma unroll
        for (int off = 32; off; off >>= 1) sq += __shfl_xor(sq, off, 64);
        float rs = rsqrtf(sq * (1.f / 512.f) + 1e-5f);
        float out[8];
#pragma unroll
        for (int i = 0; i < 8; i++) {
            int c = lane * 8 + i;
            out[i] = vals[i] + (vals[i] - mu) * rs * bf2f(g1c[c]) + bf2f(b1c[c]);
        }
        size_t rbase = ((size_t)b * NN + n0 + r) * 512 + lane * 8;
        float* tp = t + rbase;
        *(float4*)tp = make_float4(out[0], out[1], out[2], out[3]);
        *(float4*)(tp + 4) = make_float4(out[4], out[5], out[6], out[7]);
        // second LN (LN2) over the just-computed row -> u
        float s2 = 0.f;
#pragma unroll
        for (int i = 0; i < 8; i++) s2 += out[i];
#pragma unroll
        for (int off = 32; off; off >>= 1) s2 += __shfl_xor(s2, off, 64);
        float mu2 = s2 * (1.f / 512.f);
        float sq2 = 0.f;
#pragma unroll
        for (int i = 0; i < 8; i++) { float d = out[i] - mu2; sq2 += d * d; }
#pragma unroll
        for (int off = 32; off; off >>= 1) sq2 += __shfl_xor(sq2, off, 64);
        float rs2 = rsqrtf(sq2 * (1.f / 512.f) + 1e-5f);
        short4v uo[2];
#pragma unroll
        for (int i = 0; i < 8; i++) {
            int c = lane * 8 + i;
            uo[i >> 2][i & 3] =
                (short)f2bfbits((out[i] - mu2) * rs2 * bf2f(g2c[c]) + bf2f(b2c[c]));
        }
        *(short4v*)((unsigned short*)u + rbase) = uo[0];
        *(short4v*)((unsigned short*)u + rbase + 4) = uo[1];
    }
}

// ---------------------------------------------------------------------------
// Fused residual + LayerNorm: u = bf16(LN(t0 + r1 [+ r2])). Residual stream
// is fully deferred -- t0 is never rewritten after ln_in (saves two 64MB
// fp32 RMWs and repeated t round-trips vs r7).
__global__ __launch_bounds__(256) void ln_res_kernel(
    const float* __restrict__ t, const bf16* __restrict__ r1,
    const bf16* __restrict__ r2,
    const bf16* __restrict__ g, const bf16* __restrict__ bta,
    bf16* __restrict__ outp, int Mrows)
{
    int w = threadIdx.x >> 6, lane = threadIdx.x & 63;
    int row = blockIdx.x * 4 + w;
    if (row >= Mrows) return;
    size_t base = (size_t)row * 512 + lane * 8;
    float4 v0 = *(const float4*)(t + base);
    float4 v1 = *(const float4*)(t + base + 4);
    float vals[8] = {v0.x, v0.y, v0.z, v0.w, v1.x, v1.y, v1.z, v1.w};
    {
        short8 a = *(const short8*)((const unsigned short*)r1 + base);
#pragma unroll
        for (int i = 0; i < 8; i++) vals[i] += us2f(((unsigned short*)&a)[i]);
    }
    if (r2) {
        short8 a = *(const short8*)((const unsigned short*)r2 + base);
#pragma unroll
        for (int i = 0; i < 8; i++) vals[i] += us2f(((unsigned short*)&a)[i]);
    }
    float s = 0.f;
#pragma unroll
    for (int i = 0; i < 8; i++) s += vals[i];
#pragma unroll
    for (int off = 32; off; off >>= 1) s += __shfl_xor(s, off, 64);
    float mu = s * (1.f / 512.f);
    float sq = 0.f;
#pragma unroll
    for (int i = 0; i < 8; i++) { float d = vals[i] - mu; sq += d * d; }
#pragma unroll
    for (int off = 32; off; off >>= 1) sq += __shfl_xor(sq, off, 64);
    float rs = rsqrtf(sq * (1.f / 512.f) + 1e-5f);
    short4v uo[2];
#pragma unroll
    for (int i = 0; i < 8; i++) {
        int c = lane * 8 + i;
        uo[i >> 2][i & 3] =
            (short)f2bfbits((vals[i] - mu) * rs * bf2f(g[c]) + bf2f(bta[c]));
    }
    *(short4v*)((unsigned short*)outp + base) = uo[0];
    *(short4v*)((unsigned short*)outp + base + 4) = uo[1];
}

// Transpose (t0 + rc + rg + fb) (B,N,C) -> out (B,C,N) in detected dtype.
__global__ __launch_bounds__(256) void transpose_out_kernel(
    const float* __restrict__ t, const bf16* __restrict__ rc,
    const bf16* __restrict__ rg, const bf16* __restrict__ f,
    void* __restrict__ o, const int* __restrict__ flag,
    int C, int NN)
{
    __shared__ float tile[32][33];
    int isf = *flag;
    int b = blockIdx.z;
    int n0 = blockIdx.x * 32, c0 = blockIdx.y * 32;
    int tx = threadIdx.x, ty = threadIdx.y;
#pragma unroll
    for (int i = 0; i < 4; i++) {
        size_t idx = ((size_t)b * NN + n0 + ty + i * 8) * C + c0 + tx;
        tile[ty + i * 8][tx] = t[idx] + bf2f(rc[idx]) + bf2f(rg[idx]) + bf2f(f[idx]);
    }
    __syncthreads();
#pragma unroll
    for (int i = 0; i < 4; i++) {
        size_t oi = ((size_t)b * C + c0 + ty + i * 8) * NN + n0 + tx;
        float val = tile[tx][ty + i * 8];
        if (isf) ((float*)o)[oi] = val;
        else ((bf16*)o)[oi] = f2bf(val);
    }
}

// ---------------------------------------------------------------------------
// Batched weight transpose: 10 matrices (W KxNc row-major -> WT NcxK bf16)
struct TWTab {
    const void* src[10];
    bf16* dst[10];
    int K[10];
    int Nc[10];
    int tstart[10];
};
__global__ __launch_bounds__(256) void transpose_w_batch(
    TWTab tab, const int* __restrict__ flag)
{
    __shared__ float tile[32][33];
    int isf = *flag;
    int b = blockIdx.x;
    int s = 0;
#pragma unroll
    for (int i = 1; i < 10; i++) if (b >= tab.tstart[i]) s = i;
    const void* Wm = tab.src[s];
    bf16* WT = tab.dst[s];
    int K = tab.K[s], Nc = tab.Nc[s];
    int lt = b - tab.tstart[s];
    int ntx = Nc >> 5;
    int n0 = (lt % ntx) * 32, k0 = (lt / ntx) * 32;
    int tx = threadIdx.x, ty = threadIdx.y;
#pragma unroll
    for (int i = 0; i < 4; i++)
        tile[ty + i * 8][tx] = loadF(Wm, (size_t)(k0 + ty + i * 8) * Nc + n0 + tx, isf);
    __syncthreads();
#pragma unroll
    for (int i = 0; i < 4; i++)
        WT[(size_t)(n0 + ty + i * 8) * K + k0 + tx] = f2bf(tile[tx][ty + i * 8]);
}

// ---------------------------------------------------------------------------
// 64-tile GEMM pair: K and V projections share A; blockIdx.z picks weights.
template <int MODE>
__global__ __launch_bounds__(256) void gemm64x2(
    const bf16* __restrict__ A,
    const bf16* __restrict__ WT0, const bf16* __restrict__ WT1,
    bf16* __restrict__ o0, bf16* __restrict__ o1,
    int M, int K, int Nc)
{
    const bf16* WT = blockIdx.z ? WT1 : WT0;
    bf16* outp = blockIdx.z ? o1 : o0;
    __shared__ short As[64 * 32];
    __shared__ short Bs[64 * 32];
    const int tid = threadIdx.x;
    const int m0 = blockIdx.y * 64;
    const int n0 = blockIdx.x * 64;
    const int w = tid >> 6;
    const int lane = tid & 63;
    const int lm = lane & 15;
    const int lq = lane >> 4;

    floatx4 acc[4];
#pragma unroll
    for (int nb = 0; nb < 4; nb++) acc[nb] = (floatx4){0.f, 0.f, 0.f, 0.f};

    const int srow = tid >> 2;
    const int scol = (tid & 3) << 3;
    const int agrow = m0 + srow;
    const bool aok = agrow < M;
    const bf16* Aptr = A + (size_t)agrow * K + scol;
    const bf16* Bptr = WT + (size_t)(n0 + srow) * K + scol;

    for (int k0 = 0; k0 < K; k0 += 32) {
        __syncthreads();
        int4 av = make_int4(0, 0, 0, 0);
        if (aok) av = *(const int4*)(Aptr + k0);
        *(int4*)(&As[srow * 32 + scol]) = av;
        *(int4*)(&Bs[srow * 32 + scol]) = *(const int4*)(Bptr + k0);
        __syncthreads();
        short8 a = *(const short8*)(&As[(w * 16 + lm) * 32 + lq * 8]);
#pragma unroll
        for (int nb = 0; nb < 4; nb++) {
            short8 b = *(const short8*)(&Bs[(nb * 16 + lm) * 32 + lq * 8]);
            acc[nb] = __builtin_amdgcn_mfma_f32_16x16x32_bf16(a, b, acc[nb], 0, 0, 0);
        }
    }

#pragma unroll
    for (int nb = 0; nb < 4; nb++) {
        int col = n0 + nb * 16 + lm;
#pragma unroll
        for (int r = 0; r < 4; r++) {
            int row = m0 + w * 16 + lq * 4 + r;
            if (row < M) {
                float v = acc[nb][r];
                if (MODE == 1) v = fast_gelu(v);
                outp[(size_t)row * Nc + col] = f2bf(v);
            }
        }
    }
}

// ---------------------------------------------------------------------------
// m201-style 8-phase GEMM (verified round 5; NT hints reverted per r6).
// BM=256, BK=64, 8 waves as 2M x 4N; per-wave 128 x (CB*16).
// 4 phases/K-tile {ds_read A rb-pair (B in regs from P0); stage ONE unit into
// the slot that died last phase; barrier; setprio(1); CB*4 MFMA; setprio(0);
// lgkmcnt(0)+barrier}. Staging 2 K-tiles ahead IN-PLACE; boundary wait
// vmcnt(6)[CB4]/vmcnt(5)[CB2] once per K-tile. sigma-swizzled LDS microformat
// (conflict-free, r2-verified). A-staging base waves 4-7 rows 128+8(w-4).
// MODE 0: bf16 store (+bias); MODE 1: fast_gelu+bf16; MODE 2: fp32 +=.
// REQUIRES M%256==0, Nc%(CB*64)==0, K%64==0, K>=128, nwg%8==0.
#define MFMA_PAIR(RB, A00, A01, A10, A11)                                              \
    _Pragma("unroll")                                                                   \
    for (int cb = 0; cb < CB; cb++) {                                                   \
        acc[cb][RB]     = __builtin_amdgcn_mfma_f32_16x16x32_bf16(bf0[cb], A00, acc[cb][RB], 0, 0, 0);     \
        acc[cb][RB]     = __builtin_amdgcn_mfma_f32_16x16x32_bf16(bf1[cb], A01, acc[cb][RB], 0, 0, 0);     \
        acc[cb][RB + 1] = __builtin_amdgcn_mfma_f32_16x16x32_bf16(bf0[cb], A10, acc[cb][RB + 1], 0, 0, 0); \
        acc[cb][RB + 1] = __builtin_amdgcn_mfma_f32_16x16x32_bf16(bf1[cb], A11, acc[cb][RB + 1], 0, 0, 0); \
    }

template <int MODE, int CB>
__global__ __launch_bounds__(512, 2) void gemm8p(
    const bf16* __restrict__ A, const bf16* __restrict__ WT,
    const bf16* __restrict__ bias, void* __restrict__ outp,
    int K, int Nc)
{
    constexpr int BN = CB * 64;
    constexpr int ABUF = 256 * 64;   // shorts per A buffer (32 KB)
    constexpr int BBUF = BN * 64;    // shorts per B buffer
    __shared__ short As[2 * ABUF];
    __shared__ short Bs[2 * BBUF];

    const int tid = threadIdx.x;
    const int gx = gridDim.x;
    int g = blockIdx.y * gx + blockIdx.x;
    const int cpx = (gx * gridDim.y) >> 3;
    g = (g & 7) * cpx + (g >> 3);
    const int m0 = (g / gx) * 256;
    const int n0 = (g % gx) * BN;

    const int w = tid >> 6, lane = tid & 63;
    const int lm = lane & 15, lq = lane >> 4;
    const int wm = w >> 2, wn = w & 3;

    floatx4 acc[CB][8];
#pragma unroll
    for (int cb = 0; cb < CB; cb++)
#pragma unroll
        for (int rb = 0; rb < 8; rb++) acc[cb][rb] = (floatx4){0.f, 0.f, 0.f, 0.f};

    // ---- staging thread constants (pre-swizzled global source) ----
    const int rbaseA = (tid >> 3) + ((tid >= 256) ? 96 : 0);
    const int chk = (((tid & 7) ^ ((tid >> 3) & 7)) << 3);
    const bf16* pA = A + (size_t)(m0 + rbaseA) * K + chk;
    const int rbaseB = ((tid >> 7) << (CB == 4 ? 6 : 5)) + ((tid >> 3) & 15);
    const bf16* pB = WT + (size_t)(n0 + rbaseB) * K + chk;
    // LDS base: waves 0-3 stage rows 8w.. ; waves 4-7 stage rows 128+8(w-4)..
    const int wbA = w * 512 + ((w >= 4) ? 6144 : 0);
    const int wbB = (CB == 4) ? ((w >> 1) * 4096 + (w & 1) * 512)
                              : ((w >> 1) * 2048 + (w & 1) * 512);
    const size_t K32 = (size_t)K * 32;
    const size_t K16 = (size_t)K * 16;

    // ---- fragment-read constants ----
    const int arow = (wm * 128 + lm) * 64;
    const int brow = (wn * CB * 16 + lm) * 64;
    const int sl0 = ((lq ^ (lm & 7)) << 3);
    const int sl1 = (((4 + lq) ^ (lm & 7)) << 3);

    const int nt = K >> 6;

    // ---- prologue: tile0 full, tile1 minus its last A units ----
#pragma unroll
    for (int q = 0; q < 4; q++) gl_lds16(pA + (size_t)q * K32, As + q * 2048 + wbA);
    if constexpr (CB == 4) {
        gl_lds16(pB,           Bs + wbB);
        gl_lds16(pB + K16,     Bs + 1024 + wbB);
        gl_lds16(pB + 2 * K16, Bs + 2048 + wbB);
        gl_lds16(pB + 3 * K16, Bs + 3072 + wbB);
    } else {
        gl_lds16(pB,       Bs + wbB);
        gl_lds16(pB + K16, Bs + 1024 + wbB);
    }
    {
        const bf16* qA = pA + 64;
        const bf16* qB = pB + 64;
        if constexpr (CB == 4) {
            gl_lds16(qB,           Bs + BBUF + wbB);
            gl_lds16(qB + K16,     Bs + BBUF + 1024 + wbB);
            gl_lds16(qB + 2 * K16, Bs + BBUF + 2048 + wbB);
            gl_lds16(qB + 3 * K16, Bs + BBUF + 3072 + wbB);
            gl_lds16(qA,           As + ABUF + wbA);
            gl_lds16(qA + K32,     As + ABUF + 2048 + wbA);
            asm volatile("s_waitcnt vmcnt(6)\n\ts_barrier" ::: "memory");
        } else {
            gl_lds16(qB,           Bs + BBUF + wbB);
            gl_lds16(qB + K16, Bs + BBUF + 1024 + wbB);
            gl_lds16(qA,           As + ABUF + wbA);
            gl_lds16(qA + K32,     As + ABUF + 2048 + wbA);
            gl_lds16(qA + 2 * K32, As + ABUF + 4096 + wbA);
            asm volatile("s_waitcnt vmcnt(5)\n\ts_barrier" ::: "memory");
        }
    }

    for (int s = 0; s < nt; ++s) {
        const int cu = s & 1;
        const short* cA = As + cu * ABUF;
        const short* cB = Bs + cu * BBUF;
        short* oA = As + (cu ^ 1) * ABUF;   // buffer of tile s+1
        short* sA = As + cu * ABUF;         // in-place dest for tile s+2
        short* sB = Bs + cu * BBUF;
        const bf16* pA1 = pA + (s + 1) * 64;
        const bf16* pA2 = pA + (s + 2) * 64;
        const bf16* pB2 = pB + (s + 2) * 64;
        short8 bf0[CB], bf1[CB], x0, x1, y0, y1;

        // ---------------- P0: read B-all + A rb0,1; stage (s+1) last A units
#pragma unroll
        for (int cb = 0; cb < CB; cb++) {
            bf0[cb] = *(const short8*)&cB[brow + cb * 1024 + sl0];
            bf1[cb] = *(const short8*)&cB[brow + cb * 1024 + sl1];
        }
        x0 = *(const short8*)&cA[arow + sl0];
        x1 = *(const short8*)&cA[arow + sl1];
        y0 = *(const short8*)&cA[arow + 1024 + sl0];
        y1 = *(const short8*)&cA[arow + 1024 + sl1];
        if (s + 1 < nt) {
            if constexpr (CB == 4) {
                gl_lds16(pA1 + 2 * K32, oA + 2 * 2048 + wbA);
                gl_lds16(pA1 + 3 * K32, oA + 3 * 2048 + wbA);
            } else {
                gl_lds16(pA1 + 3 * K32, oA + 3 * 2048 + wbA);
            }
        }
        asm volatile("s_barrier" ::: "memory");
        __builtin_amdgcn_s_setprio(1);
        MFMA_PAIR(0, x0, x1, y0, y1)
        __builtin_amdgcn_s_setprio(0);
        asm volatile("s_waitcnt lgkmcnt(0)\n\ts_barrier" ::: "memory");

        // ---------------- P1: read A rb2,3; stage (s+2).B first two units
        x0 = *(const short8*)&cA[arow + 2 * 1024 + sl0];
        x1 = *(const short8*)&cA[arow + 2 * 1024 + sl1];
        y0 = *(const short8*)&cA[arow + 3 * 1024 + sl0];
        y1 = *(const short8*)&cA[arow + 3 * 1024 + sl1];
        if (s + 2 < nt) {
            gl_lds16(pB2,       sB + wbB);
            gl_lds16(pB2 + K16, sB + 1024 + wbB);
        }
        asm volatile("s_barrier" ::: "memory");
        __builtin_amdgcn_s_setprio(1);
        MFMA_PAIR(2, x0, x1, y0, y1)
        __builtin_amdgcn_s_setprio(0);
        asm volatile("s_waitcnt lgkmcnt(0)\n\ts_barrier" ::: "memory");

        // ---------------- P2: read A rb4,5; stage (s+2) B-u1 [CB4] / A0 [CB2]
        x0 = *(const short8*)&cA[arow + 4 * 1024 + sl0];
        x1 = *(const short8*)&cA[arow + 4 * 1024 + sl1];
        y0 = *(const short8*)&cA[arow + 5 * 1024 + sl0];
        y1 = *(const short8*)&cA[arow + 5 * 1024 + sl1];
        if (s + 2 < nt) {
            if constexpr (CB == 4) {
                gl_lds16(pB2 + 2 * K16, sB + 2048 + wbB);
                gl_lds16(pB2 + 3 * K16, sB + 3072 + wbB);
            } else {
                gl_lds16(pA2, sA + wbA);
            }
        }
        asm volatile("s_barrier" ::: "memory");
        __builtin_amdgcn_s_setprio(1);
        MFMA_PAIR(4, x0, x1, y0, y1)
        __builtin_amdgcn_s_setprio(0);
        asm volatile("s_waitcnt lgkmcnt(0)\n\ts_barrier" ::: "memory");

        // ---------------- P3: read A rb6,7; stage (s+2) early A units
        x0 = *(const short8*)&cA[arow + 6 * 1024 + sl0];
        x1 = *(const short8*)&cA[arow + 6 * 1024 + sl1];
        y0 = *(const short8*)&cA[arow + 7 * 1024 + sl0];
        y1 = *(const short8*)&cA[arow + 7 * 1024 + sl1];
        if (s + 2 < nt) {
            if constexpr (CB == 4) {
                gl_lds16(pA2,       sA + wbA);
                gl_lds16(pA2 + K32, sA + 2048 + wbA);
            } else {
                gl_lds16(pA2 + K32,     sA + 2048 + wbA);
                gl_lds16(pA2 + 2 * K32, sA + 4096 + wbA);
            }
        }
        asm volatile("s_barrier" ::: "memory");
        __builtin_amdgcn_s_setprio(1);
        MFMA_PAIR(6, x0, x1, y0, y1)
        __builtin_amdgcn_s_setprio(0);
        // K-tile boundary: counted wait -- tile s+1 fully landed, tile s+2's
        // trailing units stay in flight across the barrier.
        if (s <= nt - 3) {
            if constexpr (CB == 4)
                asm volatile("s_waitcnt vmcnt(6) lgkmcnt(0)\n\ts_barrier" ::: "memory");
            else
                asm volatile("s_waitcnt vmcnt(5) lgkmcnt(0)\n\ts_barrier" ::: "memory");
        } else if (s == nt - 2) {
            asm volatile("s_waitcnt vmcnt(0) lgkmcnt(0)\n\ts_barrier" ::: "memory");
        } else {
            asm volatile("s_waitcnt lgkmcnt(0)\n\ts_barrier" ::: "memory");
        }
    }
    __syncthreads();

    // D: out col = n0 + wn*(CB*16) + cb*16 + lq*4 + r, row = m0 + wm*128 + rb*16 + lm
    float4 bias4[CB];
#pragma unroll
    for (int cb = 0; cb < CB; cb++) {
        if (bias) {
            const bf16* bp = bias + n0 + wn * (CB * 16) + cb * 16 + lq * 4;
            bias4[cb] = make_float4(bf2f(bp[0]), bf2f(bp[1]), bf2f(bp[2]), bf2f(bp[3]));
        } else {
            bias4[cb] = make_float4(0.f, 0.f, 0.f, 0.f);
        }
    }

    if constexpr (MODE == 2) {
        float* po = (float*)outp;
#pragma unroll
        for (int rb = 0; rb < 8; rb++) {
            size_t m = m0 + wm * 128 + rb * 16 + lm;
#pragma unroll
            for (int cb = 0; cb < CB; cb++) {
                float* p = po + m * Nc + n0 + wn * (CB * 16) + cb * 16 + lq * 4;
                float4 f = *(float4*)p;
                f.x += acc[cb][rb][0] + bias4[cb].x;
                f.y += acc[cb][rb][1] + bias4[cb].y;
                f.z += acc[cb][rb][2] + bias4[cb].z;
                f.w += acc[cb][rb][3] + bias4[cb].w;
                *(float4*)p = f;
            }
        }
    } else if constexpr (CB == 2) {
        // direct 8B stores
        unsigned short* op = (unsigned short*)outp;
#pragma unroll
        for (int rb = 0; rb < 8; rb++) {
            size_t m = m0 + wm * 128 + rb * 16 + lm;
#pragma unroll
            for (int cb = 0; cb < 2; cb++) {
                short4v pk;
#pragma unroll
                for (int r = 0; r < 4; r++) {
                    float vv = acc[cb][rb][r] + ((const float*)&bias4[cb])[r];
                    if (MODE == 1) vv = fast_gelu(vv);
                    pk[r] = (short)f2bfbits(vv);
                }
                *(short4v*)(op + m * Nc + n0 + wn * 32 + cb * 16 + lq * 4) = pk;
            }
        }
    } else {
        // LDS-staged short8 stores (reuse As after final barrier)
        unsigned short* stgb = (unsigned short*)&As[w * 1024];
        unsigned short* op = (unsigned short*)outp;
#pragma unroll
        for (int rb = 0; rb < 8; rb++) {
#pragma unroll
            for (int cb = 0; cb < 4; cb++) {
                short4v pk;
#pragma unroll
                for (int r = 0; r < 4; r++) {
                    float vv = acc[cb][rb][r] + ((const float*)&bias4[cb])[r];
                    if (MODE == 1) vv = fast_gelu(vv);
                    pk[r] = (short)f2bfbits(vv);
                }
                int chunk = (cb * 2 + (lq >> 1)) ^ (lm & 7);
                *(short4v*)(&stgb[lm * 64 + chunk * 8 + (lq & 1) * 4]) = pk;
            }
#pragma unroll
            for (int p = 0; p < 2; p++) {
                int row = p * 8 + (lane >> 3);
                int chunk = lane & 7;
                short8 ov = *(const short8*)(&stgb[row * 64 + ((chunk ^ (row & 7)) * 8)]);
                size_t m = m0 + wm * 128 + rb * 16 + row;
                *(short8*)(op + m * Nc + n0 + wn * 64 + chunk * 8) = ov;
            }
        }
    }
}

// ---------------------------------------------------------------------------
// MFMA attention. Block = one (b,h) x 64-query tile; 4 waves, 16 q each.
template <int SPAD, int SVALID>
__global__ __launch_bounds__(256) void attn_mfma_kernel(
    const bf16* __restrict__ q, const bf16* __restrict__ k, const bf16* __restrict__ v,
    bf16* __restrict__ o, int N)
{
    constexpr int MB = SPAD / 16;   // score m-blocks over s
    constexpr int KS = SPAD / 32;   // PV k-steps over s
    __shared__ unsigned short lds[SPAD * 64 + 64 * SPAD];
    unsigned short* Ks = lds;                 // [s][64], chunk-swizzled by s&7
    unsigned short* Vt = lds + SPAD * 64;     // [d][SPAD], chunk-swizzled by d&7
    unsigned short* Pw = lds;                 // alias (after barrier)

    const int tid = threadIdx.x;
    const int b = blockIdx.x >> 3;
    const int h = blockIdx.x & 7;
    const int n0 = blockIdx.y * 64;
    const int w = tid >> 6, lane = tid & 63;
    const int lm = lane & 15, lq = lane >> 4;

    const unsigned short* kp = (const unsigned short*)k;
    const unsigned short* vp = (const unsigned short*)v;
    for (int idx = tid * 8; idx < SPAD * 64; idx += 2048) {
        int s = idx >> 6, d0 = idx & 63;
        short8 kv = {0, 0, 0, 0, 0, 0, 0, 0};
        short8 vv = {0, 0, 0, 0, 0, 0, 0, 0};
        if (s < SVALID) {
            size_t gb = ((size_t)(b * SVALID + s)) * 512 + h * 64 + d0;
            kv = *(const short8*)(kp + gb);
            vv = *(const short8*)(vp + gb);
        }
        int kc = (d0 >> 3) ^ (s & 7);
        *(short8*)(&Ks[s * 64 + kc * 8]) = kv;
        const unsigned short* vvp = (const unsigned short*)&vv;
#pragma unroll
        for (int i = 0; i < 8; i++) {
            int d = d0 + i;
            int sc = (s >> 3) ^ (d & 7);
            Vt[d * SPAD + sc * 8 + (s & 7)] = vvp[i];
        }
    }

    const int q0 = n0 + w * 16;
    const unsigned short* qp = (const unsigned short*)q;
    size_t qbase = ((size_t)(b * N + q0 + lm)) * 512 + h * 64 + lq * 8;
    short8 qf0 = *(const short8*)(qp + qbase);
    short8 qf1 = *(const short8*)(qp + qbase + 32);
    __syncthreads();

    floatx4 sacc[MB];
#pragma unroll
    for (int mb = 0; mb < MB; mb++) sacc[mb] = (floatx4){0.f, 0.f, 0.f, 0.f};
#pragma unroll
    for (int mb = 0; mb < MB; mb++) {
        int srow = mb * 16 + lm;
        short8 a0 = *(const short8*)(&Ks[srow * 64 + ((lq ^ (lm & 7)) * 8)]);
        short8 a1 = *(const short8*)(&Ks[srow * 64 + (((4 + lq) ^ (lm & 7)) * 8)]);
        sacc[mb] = __builtin_amdgcn_mfma_f32_16x16x32_bf16(a0, qf0, sacc[mb], 0, 0, 0);
        sacc[mb] = __builtin_amdgcn_mfma_f32_16x16x32_bf16(a1, qf1, sacc[mb], 0, 0, 0);
    }

    float mx = -1e30f;
#pragma unroll
    for (int mb = 0; mb < MB; mb++)
#pragma unroll
        for (int r = 0; r < 4; r++) {
            int s = mb * 16 + lq * 4 + r;
            if (s < SVALID) mx = fmaxf(mx, sacc[mb][r]);
        }
    mx = fmaxf(mx, __shfl_xor(mx, 16, 64));
    mx = fmaxf(mx, __shfl_xor(mx, 32, 64));
    mx *= 0.125f;
    float sum = 0.f;
#pragma unroll
    for (int mb = 0; mb < MB; mb++)
#pragma unroll
        for (int r = 0; r < 4; r++) {
            int s = mb * 16 + lq * 4 + r;
            float e = (s < SVALID) ? __expf(sacc[mb][r] * 0.125f - mx) : 0.f;
            sacc[mb][r] = e;
            sum += e;
        }
    sum += __shfl_xor(sum, 16, 64);
    sum += __shfl_xor(sum, 32, 64);
    float inv = 1.f / sum;

    __syncthreads();

    unsigned short* Pme = Pw + w * 16 * SPAD;
#pragma unroll
    for (int mb = 0; mb < MB; mb++) {
        short4v pk;
        pk[0] = (short)f2bfbits(sacc[mb][0] * inv);
        pk[1] = (short)f2bfbits(sacc[mb][1] * inv);
        pk[2] = (short)f2bfbits(sacc[mb][2] * inv);
        pk[3] = (short)f2bfbits(sacc[mb][3] * inv);
        int chunk = (mb * 2 + (lq >> 1)) ^ (lm & 7);
        *(short4v*)(&Pme[lm * SPAD + chunk * 8 + (lq & 1) * 4]) = pk;
    }

    floatx4 oacc[4];
#pragma unroll
    for (int mb2 = 0; mb2 < 4; mb2++) oacc[mb2] = (floatx4){0.f, 0.f, 0.f, 0.f};
    for (int ks = 0; ks < KS; ks++) {
        int sch = ((ks * 4 + lq) ^ (lm & 7)) * 8;
        short8 bfrag = *(const short8*)(&Pme[lm * SPAD + sch]);
#pragma unroll
        for (int mb2 = 0; mb2 < 4; mb2++) {
            int d = mb2 * 16 + lm;
            short8 afrag = *(const short8*)(&Vt[d * SPAD + sch]);
            oacc[mb2] = __builtin_amdgcn_mfma_f32_16x16x32_bf16(afrag, bfrag, oacc[mb2], 0, 0, 0);
        }
    }

#pragma unroll
    for (int mb2 = 0; mb2 < 4; mb2++) {
        short4v ok;
        ok[0] = (short)f2bfbits(oacc[mb2][0]);
        ok[1] = (short)f2bfbits(oacc[mb2][1]);
        ok[2] = (short)f2bfbits(oacc[mb2][2]);
        ok[3] = (short)f2bfbits(oacc[mb2][3]);
        int chunk = (mb2 * 2 + (lq >> 1)) ^ (lm & 7);
        *(short4v*)(&Pme[lm * 64 + chunk * 8 + (lq & 1) * 4]) = ok;
    }
    unsigned short* op = (unsigned short*)o;
#pragma unroll
    for (int p = 0; p < 2; p++) {
        int row = p * 8 + (lane >> 3);
        int chunk = lane & 7;
        short8 ov = *(const short8*)(&Pme[row * 64 + ((chunk ^ (row & 7)) * 8)]);
        *(short8*)(op + ((size_t)(b * N + n0 + w * 16 + row)) * 512 + h * 64 + chunk * 8) = ov;
    }
}

// ---------------------------------------------------------------------------
extern "C" void kernel_launch(void* const* d_in, const int* in_sizes, int n_in,
                              void* d_out, int out_size, void* d_ws, size_t ws_size,
                              hipStream_t stream)
{
    const void* x   = d_in[0];
    const void* ctx = d_in[1];
    const void* geo = d_in[2];
    const void* g1 = d_in[3];  const void* b1 = d_in[4];
    const void* g2 = d_in[5];  const void* b2 = d_in[6];
    const void* g3 = d_in[7];  const void* b3 = d_in[8];
    const void* g4 = d_in[9];  const void* b4 = d_in[10];
    const void* cWq = d_in[11]; const void* cWk = d_in[12];
    const void* cWv = d_in[13]; const void* cWo = d_in[14];
    const void* cbo = d_in[15];
    const void* gWq = d_in[16]; const void* gWk = d_in[17];
    const void* gWv = d_in[18]; const void* gWo = d_in[19];
    const void* gbo = d_in[20];
    const void* W1 = d_in[21];  const void* bf1 = d_in[22];
    const void* W2 = d_in[23];  const void* bf2 = d_in[24];

    const int B = 4, C = 512, NN = 4096;
    const int M = B * NN;  // 16384 token rows

    char* ws = (char*)d_ws;
    size_t off = 0;
    auto alloc = [&](size_t bytes) -> void* {
        void* p = ws + off; off += (bytes + 255) & ~(size_t)255; return p;
    };
    int*   flag = (int*)alloc(256);
    float* t  = (float*)alloc((size_t)M * C * 4);        // fp32 residual base (written once)
    bf16* u   = (bf16*)alloc((size_t)M * C * 2);         // LN out; ob aliases u
    bf16* qb  = (bf16*)alloc((size_t)M * C * 2);         // Q
    bf16* rc  = (bf16*)alloc((size_t)M * C * 2);         // ctx-attn branch output
    bf16* rg  = (bf16*)alloc((size_t)M * C * 2);         // geo-attn branch output
    bf16* fb  = (bf16*)alloc((size_t)M * C * 2);         // FFN branch output
    bf16* kb  = (bf16*)alloc((size_t)B * 256 * C * 2);
    bf16* vb  = (bf16*)alloc((size_t)B * 256 * C * 2);
    bf16* ctxb = (bf16*)alloc((size_t)B * 77 * 768 * 2);
    bf16* geob = (bf16*)alloc((size_t)B * 256 * 512 * 2);
    bf16* cWqT = (bf16*)alloc((size_t)512 * 512 * 2);
    bf16* cWkT = (bf16*)alloc((size_t)512 * 768 * 2);
    bf16* cWvT = (bf16*)alloc((size_t)512 * 768 * 2);
    bf16* cWoT = (bf16*)alloc((size_t)512 * 512 * 2);
    bf16* gWqT = (bf16*)alloc((size_t)512 * 512 * 2);
    bf16* gWkT = (bf16*)alloc((size_t)512 * 512 * 2);
    bf16* gWvT = (bf16*)alloc((size_t)512 * 512 * 2);
    bf16* gWoT = (bf16*)alloc((size_t)512 * 512 * 2);
    bf16* W1T  = (bf16*)alloc((size_t)2048 * 512 * 2);
    bf16* W2T  = (bf16*)alloc((size_t)512 * 2048 * 2);
    bf16* prm  = (bf16*)alloc((size_t)7680 * 2);
    bf16* ob = u;   // attention output aliases u (u dead after Q projection)

    // FFN hidden buffer: pick largest chunking the workspace allows
    int chunk;
    bf16* hb;
    size_t rem = (ws_size > off) ? (ws_size - off) : 0;
    if (rem >= (size_t)16384 * 2048 * 2) { chunk = 16384; hb = (bf16*)alloc((size_t)16384 * 2048 * 2); }
    else if (rem >= (size_t)8192 * 2048 * 2) { chunk = 8192; hb = (bf16*)alloc((size_t)8192 * 2048 * 2); }
    else { chunk = 4096; hb = qb; }  // alias qb (dead after attention)
    (void)in_sizes; (void)n_in; (void)out_size;

    // param block layout (bf16)
    bf16 *pg1 = prm, *pb1 = prm + 512, *pg2 = prm + 1024, *pb2 = prm + 1536;
    bf16 *pg3 = prm + 2048, *pb3 = prm + 2560, *pg4 = prm + 3072, *pb4 = prm + 3584;
    bf16 *pcbo = prm + 4096, *pgbo = prm + 4608, *pbf1 = prm + 5120, *pbf2 = prm + 7168;

    dim3 tb(32, 8);

    // dtype detection
    detect_kernel<<<1, 256, 0, stream>>>(x, flag);

    // ---- batched conversion: 12 params + ctx + geo in ONE launch ----
    {
        CVTab cv;
        const void* csrc[14] = {g1, b1, g2, b2, g3, b3, g4, b4, cbo, gbo, bf1, bf2, ctx, geo};
        bf16* cdst[14] = {prm, prm + 512, prm + 1024, prm + 1536, prm + 2048, prm + 2560,
                          prm + 3072, prm + 3584, prm + 4096, prm + 4608, prm + 5120,
                          prm + 7168, ctxb, geob};
        int ccnt[14] = {512, 512, 512, 512, 512, 512, 512, 512, 512, 512, 2048, 512,
                        B * 77 * 768, B * 256 * 512};
        int bacc = 0;
        for (int i = 0; i < 14; i++) {
            cv.src[i] = csrc[i]; cv.dst[i] = cdst[i]; cv.cnt[i] = ccnt[i];
            cv.bstart[i] = bacc;
            bacc += (ccnt[i] + 2047) / 2048;
        }
        convert_batch_kernel<<<bacc, 256, 0, stream>>>(cv, flag);
    }

    // fused: t = transpose(x) + LN1; u = LN2(t)
    ln_in_kernel<<<dim3(NN / 16, B), 256, 0, stream>>>(x, t, pg1, pb1, pg2, pb2, u, flag, NN);

    // ---- batched weight transposes: 10 matrices in ONE launch ----
    {
        TWTab tw;
        const void* wsrc[10] = {cWq, cWk, cWv, cWo, gWq, gWk, gWv, gWo, W1, W2};
        bf16* wdst[10] = {cWqT, cWkT, cWvT, cWoT, gWqT, gWkT, gWvT, gWoT, W1T, W2T};
        int wK[10]  = {512, 768, 768, 512, 512, 512, 512, 512, 512, 2048};
        int wNc[10] = {512, 512, 512, 512, 512, 512, 512, 512, 2048, 512};
        int tacc = 0;
        for (int i = 0; i < 10; i++) {
            tw.src[i] = wsrc[i]; tw.dst[i] = wdst[i]; tw.K[i] = wK[i]; tw.Nc[i] = wNc[i];
            tw.tstart[i] = tacc;
            tacc += (wNc[i] / 32) * (wK[i] / 32);
        }
        transpose_w_batch<<<tacc, tb, 0, stream>>>(tw, flag);
    }

    // ---- context cross-attention (branch output rc, residual deferred) ----
    gemm8p<0, 2><<<dim3(4, M / 256), 512, 0, stream>>>(u, cWqT, nullptr, qb, 512, 512);
    gemm64x2<0><<<dim3(8, (308 + 63) / 64, 2), 256, 0, stream>>>(ctxb, cWkT, cWvT, kb, vb, 308, 768, 512);
    attn_mfma_kernel<128, 77><<<dim3(B * 8, NN / 64), 256, 0, stream>>>(qb, kb, vb, ob, NN);
    gemm8p<0, 2><<<dim3(4, M / 256), 512, 0, stream>>>(ob, cWoT, pcbo, rc, 512, 512);
    ln_res_kernel<<<M / 4, 256, 0, stream>>>(t, rc, nullptr, pg3, pb3, u, M);

    // ---- geometry cross-attention (branch output rg) ----
    gemm8p<0, 2><<<dim3(4, M / 256), 512, 0, stream>>>(u, gWqT, nullptr, qb, 512, 512);
    gemm64x2<0><<<dim3(8, 1024 / 64, 2), 256, 0, stream>>>(geob, gWkT, gWvT, kb, vb, 1024, 512, 512);
    attn_mfma_kernel<256, 256><<<dim3(B * 8, NN / 64), 256, 0, stream>>>(qb, kb, vb, ob, NN);
    gemm8p<0, 2><<<dim3(4, M / 256), 512, 0, stream>>>(ob, gWoT, pgbo, rg, 512, 512);
    ln_res_kernel<<<M / 4, 256, 0, stream>>>(t, rc, rg, pg4, pb4, u, M);

    // ---- FFN (ws-adaptive chunking); branch output fb ----
    for (int mc = 0; mc < M / chunk; mc++) {
        bf16* uc = u + (size_t)mc * chunk * 512;
        bf16* fc = fb + (size_t)mc * chunk * 512;
        gemm8p<1, 4><<<dim3(2048 / 256, chunk / 256), 512, 0, stream>>>(uc, W1T, pbf1, hb, 512, 2048);
        gemm8p<0, 2><<<dim3(512 / 128, chunk / 256), 512, 0, stream>>>(hb, W2T, pbf2, fc, 2048, 512);
    }

    // out = transpose(t + rc + rg + fb) in detected dtype
    transpose_out_kernel<<<dim3(NN / 32, C / 32, B), tb, 0, stream>>>(t, rc, rg, fb, d_out, flag, C, NN);
}

// Round 9
// 465.563 us; speedup vs baseline: 1.1365x; 1.0097x over previous
//
#include <hip/hip_runtime.h>
#include <hip/hip_bf16.h>

using bf16 = __hip_bfloat16;
typedef __attribute__((ext_vector_type(8))) short short8;
typedef __attribute__((ext_vector_type(4))) short short4v;
typedef __attribute__((ext_vector_type(4))) float floatx4;

#define DEVFN __device__ __forceinline__

DEVFN float bf2f(bf16 v) { return __bfloat162float(v); }
DEVFN bf16 f2bf(float v) { return __float2bfloat16(v); }
DEVFN float us2f(unsigned short u) {
    union { unsigned int i; float f; } c; c.i = ((unsigned int)u) << 16; return c.f;
}
DEVFN unsigned short f2bfbits(float v) {
    union { bf16 h; unsigned short u; } c; c.h = f2bf(v); return c.u;
}
// dtype-dispatched load: isf=1 -> fp32 buffer, isf=0 -> bf16 buffer
DEVFN float loadF(const void* p, size_t i, int isf) {
    return isf ? ((const float*)p)[i] : us2f(((const unsigned short*)p)[i]);
}
// async global->LDS, 16B per lane; lds dest = wave-uniform base + lane*16
DEVFN void gl_lds16(const bf16* g, short* l) {
    __builtin_amdgcn_global_load_lds(
        (const __attribute__((address_space(1))) unsigned int*)g,
        (__attribute__((address_space(3))) unsigned int*)l, 16, 0, 0);
}
// tanh-form GELU, overflow-safe
DEVFN float fast_gelu(float v) {
    float u = v * (0.7978845608028654f + 0.0356774081f * v * v);
    float e = __expf(2.f * u);
    float th = 1.f - 2.f / (e + 1.f);
    return 0.5f * v * (1.f + th);
}

// ---------------------------------------------------------------------------
// Detect input dtype: fp32 N(0,1) -> low halves random -> exp==0xFF hits.
__global__ __launch_bounds__(256) void detect_kernel(const void* x, int* flag)
{
    __shared__ int any;
    if (threadIdx.x == 0) any = 0;
    __syncthreads();
    const unsigned short* p = (const unsigned short*)x;
    int hit = 0;
    for (int i = threadIdx.x; i < 8192; i += 256) {
        if ((p[i] & 0x7F80u) == 0x7F80u) hit = 1;
    }
    if (hit) any = 1;
    __syncthreads();
    if (threadIdx.x == 0) flag[0] = any;
}

// ---------------------------------------------------------------------------
// Batched convert: 14 segments (12 params + ctx + geo) in ONE launch.
struct CVTab {
    const void* src[14];
    bf16* dst[14];
    int cnt[14];
    int bstart[14];
};
__global__ __launch_bounds__(256) void convert_batch_kernel(
    CVTab tab, const int* __restrict__ flag)
{
    int isf = *flag;
    int b = blockIdx.x;
    int s = 0;
#pragma unroll
    for (int i = 1; i < 14; i++) if (b >= tab.bstart[i]) s = i;
    const void* src = tab.src[s];
    bf16* dst = tab.dst[s];
    int cnt = tab.cnt[s];
    int base = (b - tab.bstart[s]) * 2048;
    int lim = min(base + 2048, cnt);
    for (int i = base + (int)threadIdx.x; i < lim; i += 256)
        dst[i] = f2bf(loadF(src, i, isf));
}

// ---------------------------------------------------------------------------
// Fused: t[b,n,:] = x[b,:,n] + LN1(x_row)  AND  u = bf16(LN2(t_row)).
__global__ __launch_bounds__(256) void ln_in_kernel(
    const void* __restrict__ x, float* __restrict__ t,
    const bf16* __restrict__ g1c, const bf16* __restrict__ b1c,
    const bf16* __restrict__ g2c, const bf16* __restrict__ b2c,
    bf16* __restrict__ u,
    const int* __restrict__ flag, int NN)
{
    __shared__ float tile[16][516];
    int isf = *flag;
    int b = blockIdx.y;
    int n0 = blockIdx.x * 16;
    int tid = threadIdx.x;
    int nx = tid & 15, cy = tid >> 4;
#pragma unroll
    for (int p = 0; p < 32; p++) {
        int c = p * 16 + cy;
        tile[nx][c] = loadF(x, ((size_t)b * 512 + c) * NN + n0 + nx, isf);
    }
    __syncthreads();
    int w = tid >> 6, lane = tid & 63;
    for (int rr = 0; rr < 4; rr++) {
        int r = w * 4 + rr;
        float4 v0 = *(const float4*)&tile[r][lane * 8];
        float4 v1 = *(const float4*)&tile[r][lane * 8 + 4];
        float vals[8] = {v0.x, v0.y, v0.z, v0.w, v1.x, v1.y, v1.z, v1.w};
        float s = 0.f;
#pragma unroll
        for (int i = 0; i < 8; i++) s += vals[i];
#pragma unroll
        for (int off = 32; off; off >>= 1) s += __shfl_xor(s, off, 64);
        float mu = s * (1.f / 512.f);
        float sq = 0.f;
#pragma unroll
        for (int i = 0; i < 8; i++) { float d = vals[i] - mu; sq += d * d; }
#pragma unroll
        for (int off = 32; off; off >>= 1) sq += __shfl_xor(sq, off, 64);
        float rs = rsqrtf(sq * (1.f / 512.f) + 1e-5f);
        float out[8];
#pragma unroll
        for (int i = 0; i < 8; i++) {
            int c = lane * 8 + i;
            out[i] = vals[i] + (vals[i] - mu) * rs * bf2f(g1c[c]) + bf2f(b1c[c]);
        }
        size_t rbase = ((size_t)b * NN + n0 + r) * 512 + lane * 8;
        float* tp = t + rbase;
        *(float4*)tp = make_float4(out[0], out[1], out[2], out[3]);
        *(float4*)(tp + 4) = make_float4(out[4], out[5], out[6], out[7]);
        // second LN (LN2) over the just-computed row -> u
        float s2 = 0.f;
#pragma unroll
        for (int i = 0; i < 8; i++) s2 += out[i];
#pragma unroll
        for (int off = 32; off; off >>= 1) s2 += __shfl_xor(s2, off, 64);
        float mu2 = s2 * (1.f / 512.f);
        float sq2 = 0.f;
#pragma unroll
        for (int i = 0; i < 8; i++) { float d = out[i] - mu2; sq2 += d * d; }
#pragma unroll
        for (int off = 32; off; off >>= 1) sq2 += __shfl_xor(sq2, off, 64);
        float rs2 = rsqrtf(sq2 * (1.f / 512.f) + 1e-5f);
        short4v uo[2];
#pragma unroll
        for (int i = 0; i < 8; i++) {
            int c = lane * 8 + i;
            uo[i >> 2][i & 3] =
                (short)f2bfbits((out[i] - mu2) * rs2 * bf2f(g2c[c]) + bf2f(b2c[c]));
        }
        *(short4v*)((unsigned short*)u + rbase) = uo[0];
        *(short4v*)((unsigned short*)u + rbase + 4) = uo[1];
    }
}

// ---------------------------------------------------------------------------
// Fused residual + LayerNorm: u = bf16(LN(t0 + r1 [+ r2])).
__global__ __launch_bounds__(256) void ln_res_kernel(
    const float* __restrict__ t, const bf16* __restrict__ r1,
    const bf16* __restrict__ r2,
    const bf16* __restrict__ g, const bf16* __restrict__ bta,
    bf16* __restrict__ outp, int Mrows)
{
    int w = threadIdx.x >> 6, lane = threadIdx.x & 63;
    int row = blockIdx.x * 4 + w;
    if (row >= Mrows) return;
    size_t base = (size_t)row * 512 + lane * 8;
    float4 v0 = *(const float4*)(t + base);
    float4 v1 = *(const float4*)(t + base + 4);
    float vals[8] = {v0.x, v0.y, v0.z, v0.w, v1.x, v1.y, v1.z, v1.w};
    {
        short8 a = *(const short8*)((const unsigned short*)r1 + base);
#pragma unroll
        for (int i = 0; i < 8; i++) vals[i] += us2f(((unsigned short*)&a)[i]);
    }
    if (r2) {
        short8 a = *(const short8*)((const unsigned short*)r2 + base);
#pragma unroll
        for (int i = 0; i < 8; i++) vals[i] += us2f(((unsigned short*)&a)[i]);
    }
    float s = 0.f;
#pragma unroll
    for (int i = 0; i < 8; i++) s += vals[i];
#pragma unroll
    for (int off = 32; off; off >>= 1) s += __shfl_xor(s, off, 64);
    float mu = s * (1.f / 512.f);
    float sq = 0.f;
#pragma unroll
    for (int i = 0; i < 8; i++) { float d = vals[i] - mu; sq += d * d; }
#pragma unroll
    for (int off = 32; off; off >>= 1) sq += __shfl_xor(sq, off, 64);
    float rs = rsqrtf(sq * (1.f / 512.f) + 1e-5f);
    short4v uo[2];
#pragma unroll
    for (int i = 0; i < 8; i++) {
        int c = lane * 8 + i;
        uo[i >> 2][i & 3] =
            (short)f2bfbits((vals[i] - mu) * rs * bf2f(g[c]) + bf2f(bta[c]));
    }
    *(short4v*)((unsigned short*)outp + base) = uo[0];
    *(short4v*)((unsigned short*)outp + base + 4) = uo[1];
}

// Transpose (t0 + rc + rg + fb) (B,N,C) -> out (B,C,N) in detected dtype.
__global__ __launch_bounds__(256) void transpose_out_kernel(
    const float* __restrict__ t, const bf16* __restrict__ rc,
    const bf16* __restrict__ rg, const bf16* __restrict__ f,
    void* __restrict__ o, const int* __restrict__ flag,
    int C, int NN)
{
    __shared__ float tile[32][33];
    int isf = *flag;
    int b = blockIdx.z;
    int n0 = blockIdx.x * 32, c0 = blockIdx.y * 32;
    int tx = threadIdx.x, ty = threadIdx.y;
#pragma unroll
    for (int i = 0; i < 4; i++) {
        size_t idx = ((size_t)b * NN + n0 + ty + i * 8) * C + c0 + tx;
        tile[ty + i * 8][tx] = t[idx] + bf2f(rc[idx]) + bf2f(rg[idx]) + bf2f(f[idx]);
    }
    __syncthreads();
#pragma unroll
    for (int i = 0; i < 4; i++) {
        size_t oi = ((size_t)b * C + c0 + ty + i * 8) * NN + n0 + tx;
        float val = tile[tx][ty + i * 8];
        if (isf) ((float*)o)[oi] = val;
        else ((bf16*)o)[oi] = f2bf(val);
    }
}

// ---------------------------------------------------------------------------
// Batched weight transpose: 10 matrices (W KxNc row-major -> WT NcxK bf16)
struct TWTab {
    const void* src[10];
    bf16* dst[10];
    int K[10];
    int Nc[10];
    int tstart[10];
};
__global__ __launch_bounds__(256) void transpose_w_batch(
    TWTab tab, const int* __restrict__ flag)
{
    __shared__ float tile[32][33];
    int isf = *flag;
    int b = blockIdx.x;
    int s = 0;
#pragma unroll
    for (int i = 1; i < 10; i++) if (b >= tab.tstart[i]) s = i;
    const void* Wm = tab.src[s];
    bf16* WT = tab.dst[s];
    int K = tab.K[s], Nc = tab.Nc[s];
    int lt = b - tab.tstart[s];
    int ntx = Nc >> 5;
    int n0 = (lt % ntx) * 32, k0 = (lt / ntx) * 32;
    int tx = threadIdx.x, ty = threadIdx.y;
#pragma unroll
    for (int i = 0; i < 4; i++)
        tile[ty + i * 8][tx] = loadF(Wm, (size_t)(k0 + ty + i * 8) * Nc + n0 + tx, isf);
    __syncthreads();
#pragma unroll
    for (int i = 0; i < 4; i++)
        WT[(size_t)(n0 + ty + i * 8) * K + k0 + tx] = f2bf(tile[tx][ty + i * 8]);
}

// ---------------------------------------------------------------------------
// 64-tile GEMM pair: K and V projections share A; blockIdx.z picks weights.
template <int MODE>
__global__ __launch_bounds__(256) void gemm64x2(
    const bf16* __restrict__ A,
    const bf16* __restrict__ WT0, const bf16* __restrict__ WT1,
    bf16* __restrict__ o0, bf16* __restrict__ o1,
    int M, int K, int Nc)
{
    const bf16* WT = blockIdx.z ? WT1 : WT0;
    bf16* outp = blockIdx.z ? o1 : o0;
    __shared__ short As[64 * 32];
    __shared__ short Bs[64 * 32];
    const int tid = threadIdx.x;
    const int m0 = blockIdx.y * 64;
    const int n0 = blockIdx.x * 64;
    const int w = tid >> 6;
    const int lane = tid & 63;
    const int lm = lane & 15;
    const int lq = lane >> 4;

    floatx4 acc[4];
#pragma unroll
    for (int nb = 0; nb < 4; nb++) acc[nb] = (floatx4){0.f, 0.f, 0.f, 0.f};

    const int srow = tid >> 2;
    const int scol = (tid & 3) << 3;
    const int agrow = m0 + srow;
    const bool aok = agrow < M;
    const bf16* Aptr = A + (size_t)agrow * K + scol;
    const bf16* Bptr = WT + (size_t)(n0 + srow) * K + scol;

    for (int k0 = 0; k0 < K; k0 += 32) {
        __syncthreads();
        int4 av = make_int4(0, 0, 0, 0);
        if (aok) av = *(const int4*)(Aptr + k0);
        *(int4*)(&As[srow * 32 + scol]) = av;
        *(int4*)(&Bs[srow * 32 + scol]) = *(const int4*)(Bptr + k0);
        __syncthreads();
        short8 a = *(const short8*)(&As[(w * 16 + lm) * 32 + lq * 8]);
#pragma unroll
        for (int nb = 0; nb < 4; nb++) {
            short8 b = *(const short8*)(&Bs[(nb * 16 + lm) * 32 + lq * 8]);
            acc[nb] = __builtin_amdgcn_mfma_f32_16x16x32_bf16(a, b, acc[nb], 0, 0, 0);
        }
    }

#pragma unroll
    for (int nb = 0; nb < 4; nb++) {
        int col = n0 + nb * 16 + lm;
#pragma unroll
        for (int r = 0; r < 4; r++) {
            int row = m0 + w * 16 + lq * 4 + r;
            if (row < M) {
                float v = acc[nb][r];
                if (MODE == 1) v = fast_gelu(v);
                outp[(size_t)row * Nc + col] = f2bf(v);
            }
        }
    }
}

// ---------------------------------------------------------------------------
// m201-style 8-phase GEMM. R9 CHANGE: pre-MFMA barriers REMOVED (4 vs 8
// barriers/K-tile). Hazard re-derivation: (H1) gl_lds16 overwrite of a dead
// slot vs prior ds_reads -> post-phase lgkmcnt(0)+barrier (KEPT); (H2)
// ds_read vs staging completion -> boundary vmcnt+barrier (KEPT); (H3)
// in-place staging targets only slots whose last read was >=1 post-phase
// barrier earlier (checked unit-by-unit, CB2 & CB4, incl. cross-buffer
// unit-3). The pre-MFMA barrier protected nothing; removing it also lets
// waves de-lockstep (role diversity -> setprio has something to arbitrate).
// Rest unchanged from verified r5/r8: BM=256, BK=64, 8 waves as 2M x 4N;
// staging 2 K-tiles ahead in-place; boundary vmcnt(6)[CB4]/vmcnt(5)[CB2];
// sigma-swizzled conflict-free LDS; A-staging base waves 4-7 rows 128+8(w-4).
// MODE 0: bf16 store (+bias); MODE 1: fast_gelu+bf16; MODE 2: fp32 +=.
// REQUIRES M%256==0, Nc%(CB*64)==0, K%64==0, K>=128, nwg%8==0.
#define MFMA_PAIR(RB, A00, A01, A10, A11)                                              \
    _Pragma("unroll")                                                                   \
    for (int cb = 0; cb < CB; cb++) {                                                   \
        acc[cb][RB]     = __builtin_amdgcn_mfma_f32_16x16x32_bf16(bf0[cb], A00, acc[cb][RB], 0, 0, 0);     \
        acc[cb][RB]     = __builtin_amdgcn_mfma_f32_16x16x32_bf16(bf1[cb], A01, acc[cb][RB], 0, 0, 0);     \
        acc[cb][RB + 1] = __builtin_amdgcn_mfma_f32_16x16x32_bf16(bf0[cb], A10, acc[cb][RB + 1], 0, 0, 0); \
        acc[cb][RB + 1] = __builtin_amdgcn_mfma_f32_16x16x32_bf16(bf1[cb], A11, acc[cb][RB + 1], 0, 0, 0); \
    }

template <int MODE, int CB>
__global__ __launch_bounds__(512, 2) void gemm8p(
    const bf16* __restrict__ A, const bf16* __restrict__ WT,
    const bf16* __restrict__ bias, void* __restrict__ outp,
    int K, int Nc)
{
    constexpr int BN = CB * 64;
    constexpr int ABUF = 256 * 64;   // shorts per A buffer (32 KB)
    constexpr int BBUF = BN * 64;    // shorts per B buffer
    __shared__ short As[2 * ABUF];
    __shared__ short Bs[2 * BBUF];

    const int tid = threadIdx.x;
    const int gx = gridDim.x;
    int g = blockIdx.y * gx + blockIdx.x;
    const int cpx = (gx * gridDim.y) >> 3;
    g = (g & 7) * cpx + (g >> 3);
    const int m0 = (g / gx) * 256;
    const int n0 = (g % gx) * BN;

    const int w = tid >> 6, lane = tid & 63;
    const int lm = lane & 15, lq = lane >> 4;
    const int wm = w >> 2, wn = w & 3;

    floatx4 acc[CB][8];
#pragma unroll
    for (int cb = 0; cb < CB; cb++)
#pragma unroll
        for (int rb = 0; rb < 8; rb++) acc[cb][rb] = (floatx4){0.f, 0.f, 0.f, 0.f};

    // ---- staging thread constants (pre-swizzled global source) ----
    const int rbaseA = (tid >> 3) + ((tid >= 256) ? 96 : 0);
    const int chk = (((tid & 7) ^ ((tid >> 3) & 7)) << 3);
    const bf16* pA = A + (size_t)(m0 + rbaseA) * K + chk;
    const int rbaseB = ((tid >> 7) << (CB == 4 ? 6 : 5)) + ((tid >> 3) & 15);
    const bf16* pB = WT + (size_t)(n0 + rbaseB) * K + chk;
    // LDS base: waves 0-3 stage rows 8w.. ; waves 4-7 stage rows 128+8(w-4)..
    const int wbA = w * 512 + ((w >= 4) ? 6144 : 0);
    const int wbB = (CB == 4) ? ((w >> 1) * 4096 + (w & 1) * 512)
                              : ((w >> 1) * 2048 + (w & 1) * 512);
    const size_t K32 = (size_t)K * 32;
    const size_t K16 = (size_t)K * 16;

    // ---- fragment-read constants ----
    const int arow = (wm * 128 + lm) * 64;
    const int brow = (wn * CB * 16 + lm) * 64;
    const int sl0 = ((lq ^ (lm & 7)) << 3);
    const int sl1 = (((4 + lq) ^ (lm & 7)) << 3);

    const int nt = K >> 6;

    // ---- prologue: tile0 full, tile1 minus its last A units ----
#pragma unroll
    for (int q = 0; q < 4; q++) gl_lds16(pA + (size_t)q * K32, As + q * 2048 + wbA);
    if constexpr (CB == 4) {
        gl_lds16(pB,           Bs + wbB);
        gl_lds16(pB + K16,     Bs + 1024 + wbB);
        gl_lds16(pB + 2 * K16, Bs + 2048 + wbB);
        gl_lds16(pB + 3 * K16, Bs + 3072 + wbB);
    } else {
        gl_lds16(pB,       Bs + wbB);
        gl_lds16(pB + K16, Bs + 1024 + wbB);
    }
    {
        const bf16* qA = pA + 64;
        const bf16* qB = pB + 64;
        if constexpr (CB == 4) {
            gl_lds16(qB,           Bs + BBUF + wbB);
            gl_lds16(qB + K16,     Bs + BBUF + 1024 + wbB);
            gl_lds16(qB + 2 * K16, Bs + BBUF + 2048 + wbB);
            gl_lds16(qB + 3 * K16, Bs + BBUF + 3072 + wbB);
            gl_lds16(qA,           As + ABUF + wbA);
            gl_lds16(qA + K32,     As + ABUF + 2048 + wbA);
            asm volatile("s_waitcnt vmcnt(6)\n\ts_barrier" ::: "memory");
        } else {
            gl_lds16(qB,           Bs + BBUF + wbB);
            gl_lds16(qB + K16, Bs + BBUF + 1024 + wbB);
            gl_lds16(qA,           As + ABUF + wbA);
            gl_lds16(qA + K32,     As + ABUF + 2048 + wbA);
            gl_lds16(qA + 2 * K32, As + ABUF + 4096 + wbA);
            asm volatile("s_waitcnt vmcnt(5)\n\ts_barrier" ::: "memory");
        }
    }

    for (int s = 0; s < nt; ++s) {
        const int cu = s & 1;
        const short* cA = As + cu * ABUF;
        const short* cB = Bs + cu * BBUF;
        short* oA = As + (cu ^ 1) * ABUF;   // buffer of tile s+1
        short* sA = As + cu * ABUF;         // in-place dest for tile s+2
        short* sB = Bs + cu * BBUF;
        const bf16* pA1 = pA + (s + 1) * 64;
        const bf16* pA2 = pA + (s + 2) * 64;
        const bf16* pB2 = pB + (s + 2) * 64;
        short8 bf0[CB], bf1[CB], x0, x1, y0, y1;

        // ---------------- P0: read B-all + A rb0,1; stage (s+1) last A units
#pragma unroll
        for (int cb = 0; cb < CB; cb++) {
            bf0[cb] = *(const short8*)&cB[brow + cb * 1024 + sl0];
            bf1[cb] = *(const short8*)&cB[brow + cb * 1024 + sl1];
        }
        x0 = *(const short8*)&cA[arow + sl0];
        x1 = *(const short8*)&cA[arow + sl1];
        y0 = *(const short8*)&cA[arow + 1024 + sl0];
        y1 = *(const short8*)&cA[arow + 1024 + sl1];
        if (s + 1 < nt) {
            if constexpr (CB == 4) {
                gl_lds16(pA1 + 2 * K32, oA + 2 * 2048 + wbA);
                gl_lds16(pA1 + 3 * K32, oA + 3 * 2048 + wbA);
            } else {
                gl_lds16(pA1 + 3 * K32, oA + 3 * 2048 + wbA);
            }
        }
        __builtin_amdgcn_s_setprio(1);
        MFMA_PAIR(0, x0, x1, y0, y1)
        __builtin_amdgcn_s_setprio(0);
        asm volatile("s_waitcnt lgkmcnt(0)\n\ts_barrier" ::: "memory");

        // ---------------- P1: read A rb2,3; stage (s+2).B first two units
        x0 = *(const short8*)&cA[arow + 2 * 1024 + sl0];
        x1 = *(const short8*)&cA[arow + 2 * 1024 + sl1];
        y0 = *(const short8*)&cA[arow + 3 * 1024 + sl0];
        y1 = *(const short8*)&cA[arow + 3 * 1024 + sl1];
        if (s + 2 < nt) {
            gl_lds16(pB2,       sB + wbB);
            gl_lds16(pB2 + K16, sB + 1024 + wbB);
        }
        __builtin_amdgcn_s_setprio(1);
        MFMA_PAIR(2, x0, x1, y0, y1)
        __builtin_amdgcn_s_setprio(0);
        asm volatile("s_waitcnt lgkmcnt(0)\n\ts_barrier" ::: "memory");

        // ---------------- P2: read A rb4,5; stage (s+2) B-u1 [CB4] / A0 [CB2]
        x0 = *(const short8*)&cA[arow + 4 * 1024 + sl0];
        x1 = *(const short8*)&cA[arow + 4 * 1024 + sl1];
        y0 = *(const short8*)&cA[arow + 5 * 1024 + sl0];
        y1 = *(const short8*)&cA[arow + 5 * 1024 + sl1];
        if (s + 2 < nt) {
            if constexpr (CB == 4) {
                gl_lds16(pB2 + 2 * K16, sB + 2048 + wbB);
                gl_lds16(pB2 + 3 * K16, sB + 3072 + wbB);
            } else {
                gl_lds16(pA2, sA + wbA);
            }
        }
        __builtin_amdgcn_s_setprio(1);
        MFMA_PAIR(4, x0, x1, y0, y1)
        __builtin_amdgcn_s_setprio(0);
        asm volatile("s_waitcnt lgkmcnt(0)\n\ts_barrier" ::: "memory");

        // ---------------- P3: read A rb6,7; stage (s+2) early A units
        x0 = *(const short8*)&cA[arow + 6 * 1024 + sl0];
        x1 = *(const short8*)&cA[arow + 6 * 1024 + sl1];
        y0 = *(const short8*)&cA[arow + 7 * 1024 + sl0];
        y1 = *(const short8*)&cA[arow + 7 * 1024 + sl1];
        if (s + 2 < nt) {
            if constexpr (CB == 4) {
                gl_lds16(pA2,       sA + wbA);
                gl_lds16(pA2 + K32, sA + 2048 + wbA);
            } else {
                gl_lds16(pA2 + K32,     sA + 2048 + wbA);
                gl_lds16(pA2 + 2 * K32, sA + 4096 + wbA);
            }
        }
        __builtin_amdgcn_s_setprio(1);
        MFMA_PAIR(6, x0, x1, y0, y1)
        __builtin_amdgcn_s_setprio(0);
        // K-tile boundary: counted wait -- tile s+1 fully landed, tile s+2's
        // trailing units stay in flight across the barrier.
        if (s <= nt - 3) {
            if constexpr (CB == 4)
                asm volatile("s_waitcnt vmcnt(6) lgkmcnt(0)\n\ts_barrier" ::: "memory");
            else
                asm volatile("s_waitcnt vmcnt(5) lgkmcnt(0)\n\ts_barrier" ::: "memory");
        } else if (s == nt - 2) {
            asm volatile("s_waitcnt vmcnt(0) lgkmcnt(0)\n\ts_barrier" ::: "memory");
        } else {
            asm volatile("s_waitcnt lgkmcnt(0)\n\ts_barrier" ::: "memory");
        }
    }
    __syncthreads();

    // D: out col = n0 + wn*(CB*16) + cb*16 + lq*4 + r, row = m0 + wm*128 + rb*16 + lm
    float4 bias4[CB];
#pragma unroll
    for (int cb = 0; cb < CB; cb++) {
        if (bias) {
            const bf16* bp = bias + n0 + wn * (CB * 16) + cb * 16 + lq * 4;
            bias4[cb] = make_float4(bf2f(bp[0]), bf2f(bp[1]), bf2f(bp[2]), bf2f(bp[3]));
        } else {
            bias4[cb] = make_float4(0.f, 0.f, 0.f, 0.f);
        }
    }

    if constexpr (MODE == 2) {
        float* po = (float*)outp;
#pragma unroll
        for (int rb = 0; rb < 8; rb++) {
            size_t m = m0 + wm * 128 + rb * 16 + lm;
#pragma unroll
            for (int cb = 0; cb < CB; cb++) {
                float* p = po + m * Nc + n0 + wn * (CB * 16) + cb * 16 + lq * 4;
                float4 f = *(float4*)p;
                f.x += acc[cb][rb][0] + bias4[cb].x;
                f.y += acc[cb][rb][1] + bias4[cb].y;
                f.z += acc[cb][rb][2] + bias4[cb].z;
                f.w += acc[cb][rb][3] + bias4[cb].w;
                *(float4*)p = f;
            }
        }
    } else if constexpr (CB == 2) {
        // direct 8B stores
        unsigned short* op = (unsigned short*)outp;
#pragma unroll
        for (int rb = 0; rb < 8; rb++) {
            size_t m = m0 + wm * 128 + rb * 16 + lm;
#pragma unroll
            for (int cb = 0; cb < 2; cb++) {
                short4v pk;
#pragma unroll
                for (int r = 0; r < 4; r++) {
                    float vv = acc[cb][rb][r] + ((const float*)&bias4[cb])[r];
                    if (MODE == 1) vv = fast_gelu(vv);
                    pk[r] = (short)f2bfbits(vv);
                }
                *(short4v*)(op + m * Nc + n0 + wn * 32 + cb * 16 + lq * 4) = pk;
            }
        }
    } else {
        // LDS-staged short8 stores (reuse As after final barrier)
        unsigned short* stgb = (unsigned short*)&As[w * 1024];
        unsigned short* op = (unsigned short*)outp;
#pragma unroll
        for (int rb = 0; rb < 8; rb++) {
#pragma unroll
            for (int cb = 0; cb < 4; cb++) {
                short4v pk;
#pragma unroll
                for (int r = 0; r < 4; r++) {
                    float vv = acc[cb][rb][r] + ((const float*)&bias4[cb])[r];
                    if (MODE == 1) vv = fast_gelu(vv);
                    pk[r] = (short)f2bfbits(vv);
                }
                int chunk = (cb * 2 + (lq >> 1)) ^ (lm & 7);
                *(short4v*)(&stgb[lm * 64 + chunk * 8 + (lq & 1) * 4]) = pk;
            }
#pragma unroll
            for (int p = 0; p < 2; p++) {
                int row = p * 8 + (lane >> 3);
                int chunk = lane & 7;
                short8 ov = *(const short8*)(&stgb[row * 64 + ((chunk ^ (row & 7)) * 8)]);
                size_t m = m0 + wm * 128 + rb * 16 + row;
                *(short8*)(op + m * Nc + n0 + wn * 64 + chunk * 8) = ov;
            }
        }
    }
}

// ---------------------------------------------------------------------------
// MFMA attention. Block = one (b,h) x 64-query tile; 4 waves, 16 q each.
template <int SPAD, int SVALID>
__global__ __launch_bounds__(256) void attn_mfma_kernel(
    const bf16* __restrict__ q, const bf16* __restrict__ k, const bf16* __restrict__ v,
    bf16* __restrict__ o, int N)
{
    constexpr int MB = SPAD / 16;   // score m-blocks over s
    constexpr int KS = SPAD / 32;   // PV k-steps over s
    __shared__ unsigned short lds[SPAD * 64 + 64 * SPAD];
    unsigned short* Ks = lds;                 // [s][64], chunk-swizzled by s&7
    unsigned short* Vt = lds + SPAD * 64;     // [d][SPAD], chunk-swizzled by d&7
    unsigned short* Pw = lds;                 // alias (after barrier)

    const int tid = threadIdx.x;
    const int b = blockIdx.x >> 3;
    const int h = blockIdx.x & 7;
    const int n0 = blockIdx.y * 64;
    const int w = tid >> 6, lane = tid & 63;
    const int lm = lane & 15, lq = lane >> 4;

    const unsigned short* kp = (const unsigned short*)k;
    const unsigned short* vp = (const unsigned short*)v;
    for (int idx = tid * 8; idx < SPAD * 64; idx += 2048) {
        int s = idx >> 6, d0 = idx & 63;
        short8 kv = {0, 0, 0, 0, 0, 0, 0, 0};
        short8 vv = {0, 0, 0, 0, 0, 0, 0, 0};
        if (s < SVALID) {
            size_t gb = ((size_t)(b * SVALID + s)) * 512 + h * 64 + d0;
            kv = *(const short8*)(kp + gb);
            vv = *(const short8*)(vp + gb);
        }
        int kc = (d0 >> 3) ^ (s & 7);
        *(short8*)(&Ks[s * 64 + kc * 8]) = kv;
        const unsigned short* vvp = (const unsigned short*)&vv;
#pragma unroll
        for (int i = 0; i < 8; i++) {
            int d = d0 + i;
            int sc = (s >> 3) ^ (d & 7);
            Vt[d * SPAD + sc * 8 + (s & 7)] = vvp[i];
        }
    }

    const int q0 = n0 + w * 16;
    const unsigned short* qp = (const unsigned short*)q;
    size_t qbase = ((size_t)(b * N + q0 + lm)) * 512 + h * 64 + lq * 8;
    short8 qf0 = *(const short8*)(qp + qbase);
    short8 qf1 = *(const short8*)(qp + qbase + 32);
    __syncthreads();

    floatx4 sacc[MB];
#pragma unroll
    for (int mb = 0; mb < MB; mb++) sacc[mb] = (floatx4){0.f, 0.f, 0.f, 0.f};
#pragma unroll
    for (int mb = 0; mb < MB; mb++) {
        int srow = mb * 16 + lm;
        short8 a0 = *(const short8*)(&Ks[srow * 64 + ((lq ^ (lm & 7)) * 8)]);
        short8 a1 = *(const short8*)(&Ks[srow * 64 + (((4 + lq) ^ (lm & 7)) * 8)]);
        sacc[mb] = __builtin_amdgcn_mfma_f32_16x16x32_bf16(a0, qf0, sacc[mb], 0, 0, 0);
        sacc[mb] = __builtin_amdgcn_mfma_f32_16x16x32_bf16(a1, qf1, sacc[mb], 0, 0, 0);
    }

    float mx = -1e30f;
#pragma unroll
    for (int mb = 0; mb < MB; mb++)
#pragma unroll
        for (int r = 0; r < 4; r++) {
            int s = mb * 16 + lq * 4 + r;
            if (s < SVALID) mx = fmaxf(mx, sacc[mb][r]);
        }
    mx = fmaxf(mx, __shfl_xor(mx, 16, 64));
    mx = fmaxf(mx, __shfl_xor(mx, 32, 64));
    mx *= 0.125f;
    float sum = 0.f;
#pragma unroll
    for (int mb = 0; mb < MB; mb++)
#pragma unroll
        for (int r = 0; r < 4; r++) {
            int s = mb * 16 + lq * 4 + r;
            float e = (s < SVALID) ? __expf(sacc[mb][r] * 0.125f - mx) : 0.f;
            sacc[mb][r] = e;
            sum += e;
        }
    sum += __shfl_xor(sum, 16, 64);
    sum += __shfl_xor(sum, 32, 64);
    float inv = 1.f / sum;

    __syncthreads();

    unsigned short* Pme = Pw + w * 16 * SPAD;
#pragma unroll
    for (int mb = 0; mb < MB; mb++) {
        short4v pk;
        pk[0] = (short)f2bfbits(sacc[mb][0] * inv);
        pk[1] = (short)f2bfbits(sacc[mb][1] * inv);
        pk[2] = (short)f2bfbits(sacc[mb][2] * inv);
        pk[3] = (short)f2bfbits(sacc[mb][3] * inv);
        int chunk = (mb * 2 + (lq >> 1)) ^ (lm & 7);
        *(short4v*)(&Pme[lm * SPAD + chunk * 8 + (lq & 1) * 4]) = pk;
    }

    floatx4 oacc[4];
#pragma unroll
    for (int mb2 = 0; mb2 < 4; mb2++) oacc[mb2] = (floatx4){0.f, 0.f, 0.f, 0.f};
    for (int ks = 0; ks < KS; ks++) {
        int sch = ((ks * 4 + lq) ^ (lm & 7)) * 8;
        short8 bfrag = *(const short8*)(&Pme[lm * SPAD + sch]);
#pragma unroll
        for (int mb2 = 0; mb2 < 4; mb2++) {
            int d = mb2 * 16 + lm;
            short8 afrag = *(const short8*)(&Vt[d * SPAD + sch]);
            oacc[mb2] = __builtin_amdgcn_mfma_f32_16x16x32_bf16(afrag, bfrag, oacc[mb2], 0, 0, 0);
        }
    }

#pragma unroll
    for (int mb2 = 0; mb2 < 4; mb2++) {
        short4v ok;
        ok[0] = (short)f2bfbits(oacc[mb2][0]);
        ok[1] = (short)f2bfbits(oacc[mb2][1]);
        ok[2] = (short)f2bfbits(oacc[mb2][2]);
        ok[3] = (short)f2bfbits(oacc[mb2][3]);
        int chunk = (mb2 * 2 + (lq >> 1)) ^ (lm & 7);
        *(short4v*)(&Pme[lm * 64 + chunk * 8 + (lq & 1) * 4]) = ok;
    }
    unsigned short* op = (unsigned short*)o;
#pragma unroll
    for (int p = 0; p < 2; p++) {
        int row = p * 8 + (lane >> 3);
        int chunk = lane & 7;
        short8 ov = *(const short8*)(&Pme[row * 64 + ((chunk ^ (row & 7)) * 8)]);
        *(short8*)(op + ((size_t)(b * N + n0 + w * 16 + row)) * 512 + h * 64 + chunk * 8) = ov;
    }
}

// ---------------------------------------------------------------------------
extern "C" void kernel_launch(void* const* d_in, const int* in_sizes, int n_in,
                              void* d_out, int out_size, void* d_ws, size_t ws_size,
                              hipStream_t stream)
{
    const void* x   = d_in[0];
    const void* ctx = d_in[1];
    const void* geo = d_in[2];
    const void* g1 = d_in[3];  const void* b1 = d_in[4];
    const void* g2 = d_in[5];  const void* b2 = d_in[6];
    const void* g3 = d_in[7];  const void* b3 = d_in[8];
    const void* g4 = d_in[9];  const void* b4 = d_in[10];
    const void* cWq = d_in[11]; const void* cWk = d_in[12];
    const void* cWv = d_in[13]; const void* cWo = d_in[14];
    const void* cbo = d_in[15];
    const void* gWq = d_in[16]; const void* gWk = d_in[17];
    const void* gWv = d_in[18]; const void* gWo = d_in[19];
    const void* gbo = d_in[20];
    const void* W1 = d_in[21];  const void* bf1 = d_in[22];
    const void* W2 = d_in[23];  const void* bf2 = d_in[24];

    const int B = 4, C = 512, NN = 4096;
    const int M = B * NN;  // 16384 token rows

    char* ws = (char*)d_ws;
    size_t off = 0;
    auto alloc = [&](size_t bytes) -> void* {
        void* p = ws + off; off += (bytes + 255) & ~(size_t)255; return p;
    };
    int*   flag = (int*)alloc(256);
    float* t  = (float*)alloc((size_t)M * C * 4);        // fp32 residual base (written once)
    bf16* u   = (bf16*)alloc((size_t)M * C * 2);         // LN out; ob aliases u
    bf16* qb  = (bf16*)alloc((size_t)M * C * 2);         // Q
    bf16* rc  = (bf16*)alloc((size_t)M * C * 2);         // ctx-attn branch output
    bf16* rg  = (bf16*)alloc((size_t)M * C * 2);         // geo-attn branch output
    bf16* fb  = (bf16*)alloc((size_t)M * C * 2);         // FFN branch output
    bf16* kb  = (bf16*)alloc((size_t)B * 256 * C * 2);
    bf16* vb  = (bf16*)alloc((size_t)B * 256 * C * 2);
    bf16* ctxb = (bf16*)alloc((size_t)B * 77 * 768 * 2);
    bf16* geob = (bf16*)alloc((size_t)B * 256 * 512 * 2);
    bf16* cWqT = (bf16*)alloc((size_t)512 * 512 * 2);
    bf16* cWkT = (bf16*)alloc((size_t)512 * 768 * 2);
    bf16* cWvT = (bf16*)alloc((size_t)512 * 768 * 2);
    bf16* cWoT = (bf16*)alloc((size_t)512 * 512 * 2);
    bf16* gWqT = (bf16*)alloc((size_t)512 * 512 * 2);
    bf16* gWkT = (bf16*)alloc((size_t)512 * 512 * 2);
    bf16* gWvT = (bf16*)alloc((size_t)512 * 512 * 2);
    bf16* gWoT = (bf16*)alloc((size_t)512 * 512 * 2);
    bf16* W1T  = (bf16*)alloc((size_t)2048 * 512 * 2);
    bf16* W2T  = (bf16*)alloc((size_t)512 * 2048 * 2);
    bf16* prm  = (bf16*)alloc((size_t)7680 * 2);
    bf16* ob = u;   // attention output aliases u (u dead after Q projection)

    // FFN hidden buffer: pick largest chunking the workspace allows
    int chunk;
    bf16* hb;
    size_t rem = (ws_size > off) ? (ws_size - off) : 0;
    if (rem >= (size_t)16384 * 2048 * 2) { chunk = 16384; hb = (bf16*)alloc((size_t)16384 * 2048 * 2); }
    else if (rem >= (size_t)8192 * 2048 * 2) { chunk = 8192; hb = (bf16*)alloc((size_t)8192 * 2048 * 2); }
    else { chunk = 4096; hb = qb; }  // alias qb (dead after attention)
    (void)in_sizes; (void)n_in; (void)out_size;

    // param block layout (bf16)
    bf16 *pg1 = prm, *pb1 = prm + 512, *pg2 = prm + 1024, *pb2 = prm + 1536;
    bf16 *pg3 = prm + 2048, *pb3 = prm + 2560, *pg4 = prm + 3072, *pb4 = prm + 3584;
    bf16 *pcbo = prm + 4096, *pgbo = prm + 4608, *pbf1 = prm + 5120, *pbf2 = prm + 7168;

    dim3 tb(32, 8);

    // dtype detection
    detect_kernel<<<1, 256, 0, stream>>>(x, flag);

    // ---- batched conversion: 12 params + ctx + geo in ONE launch ----
    {
        CVTab cv;
        const void* csrc[14] = {g1, b1, g2, b2, g3, b3, g4, b4, cbo, gbo, bf1, bf2, ctx, geo};
        bf16* cdst[14] = {prm, prm + 512, prm + 1024, prm + 1536, prm + 2048, prm + 2560,
                          prm + 3072, prm + 3584, prm + 4096, prm + 4608, prm + 5120,
                          prm + 7168, ctxb, geob};
        int ccnt[14] = {512, 512, 512, 512, 512, 512, 512, 512, 512, 512, 2048, 512,
                        B * 77 * 768, B * 256 * 512};
        int bacc = 0;
        for (int i = 0; i < 14; i++) {
            cv.src[i] = csrc[i]; cv.dst[i] = cdst[i]; cv.cnt[i] = ccnt[i];
            cv.bstart[i] = bacc;
            bacc += (ccnt[i] + 2047) / 2048;
        }
        convert_batch_kernel<<<bacc, 256, 0, stream>>>(cv, flag);
    }

    // fused: t = transpose(x) + LN1; u = LN2(t)
    ln_in_kernel<<<dim3(NN / 16, B), 256, 0, stream>>>(x, t, pg1, pb1, pg2, pb2, u, flag, NN);

    // ---- batched weight transposes: 10 matrices in ONE launch ----
    {
        TWTab tw;
        const void* wsrc[10] = {cWq, cWk, cWv, cWo, gWq, gWk, gWv, gWo, W1, W2};
        bf16* wdst[10] = {cWqT, cWkT, cWvT, cWoT, gWqT, gWkT, gWvT, gWoT, W1T, W2T};
        int wK[10]  = {512, 768, 768, 512, 512, 512, 512, 512, 512, 2048};
        int wNc[10] = {512, 512, 512, 512, 512, 512, 512, 512, 2048, 512};
        int tacc = 0;
        for (int i = 0; i < 10; i++) {
            tw.src[i] = wsrc[i]; tw.dst[i] = wdst[i]; tw.K[i] = wK[i]; tw.Nc[i] = wNc[i];
            tw.tstart[i] = tacc;
            tacc += (wNc[i] / 32) * (wK[i] / 32);
        }
        transpose_w_batch<<<tacc, tb, 0, stream>>>(tw, flag);
    }

    // ---- context cross-attention (branch output rc, residual deferred) ----
    gemm8p<0, 2><<<dim3(4, M / 256), 512, 0, stream>>>(u, cWqT, nullptr, qb, 512, 512);
    gemm64x2<0><<<dim3(8, (308 + 63) / 64, 2), 256, 0, stream>>>(ctxb, cWkT, cWvT, kb, vb, 308, 768, 512);
    attn_mfma_kernel<128, 77><<<dim3(B * 8, NN / 64), 256, 0, stream>>>(qb, kb, vb, ob, NN);
    gemm8p<0, 2><<<dim3(4, M / 256), 512, 0, stream>>>(ob, cWoT, pcbo, rc, 512, 512);
    ln_res_kernel<<<M / 4, 256, 0, stream>>>(t, rc, nullptr, pg3, pb3, u, M);

    // ---- geometry cross-attention (branch output rg) ----
    gemm8p<0, 2><<<dim3(4, M / 256), 512, 0, stream>>>(u, gWqT, nullptr, qb, 512, 512);
    gemm64x2<0><<<dim3(8, 1024 / 64, 2), 256, 0, stream>>>(geob, gWkT, gWvT, kb, vb, 1024, 512, 512);
    attn_mfma_kernel<256, 256><<<dim3(B * 8, NN / 64), 256, 0, stream>>>(qb, kb, vb, ob, NN);
    gemm8p<0, 2><<<dim3(4, M / 256), 512, 0, stream>>>(ob, gWoT, pgbo, rg, 512, 512);
    ln_res_kernel<<<M / 4, 256, 0, stream>>>(t, rc, rg, pg4, pb4, u, M);

    // ---- FFN (ws-adaptive chunking); branch output fb ----
    for (int mc = 0; mc < M / chunk; mc++) {
        bf16* uc = u + (size_t)mc * chunk * 512;
        bf16* fc = fb + (size_t)mc * chunk * 512;
        gemm8p<1, 4><<<dim3(2048 / 256, chunk / 256), 512, 0, stream>>>(uc, W1T, pbf1, hb, 512, 2048);
        gemm8p<0, 2><<<dim3(512 / 128, chunk / 256), 512, 0, stream>>>(hb, W2T, pbf2, fc, 2048, 512);
    }

    // out = transpose(t + rc + rg + fb) in detected dtype
    transpose_out_kernel<<<dim3(NN / 32, C / 32, B), tb, 0, stream>>>(t, rc, rg, fb, d_out, flag, C, NN);
}

// Round 11
// 443.763 us; speedup vs baseline: 1.1923x; 1.0491x over previous
//
#include <hip/hip_runtime.h>
#include <hip/hip_bf16.h>

using bf16 = __hip_bfloat16;
typedef __attribute__((ext_vector_type(8))) short short8;
typedef __attribute__((ext_vector_type(4))) short short4v;
typedef __attribute__((ext_vector_type(4))) float floatx4;

#define DEVFN __device__ __forceinline__

DEVFN float bf2f(bf16 v) { return __bfloat162float(v); }
DEVFN bf16 f2bf(float v) { return __float2bfloat16(v); }
DEVFN float us2f(unsigned short u) {
    union { unsigned int i; float f; } c; c.i = ((unsigned int)u) << 16; return c.f;
}
DEVFN unsigned short f2bfbits(float v) {
    union { bf16 h; unsigned short u; } c; c.h = f2bf(v); return c.u;
}
// dtype-dispatched load: isf=1 -> fp32 buffer, isf=0 -> bf16 buffer
DEVFN float loadF(const void* p, size_t i, int isf) {
    return isf ? ((const float*)p)[i] : us2f(((const unsigned short*)p)[i]);
}
// async global->LDS, 16B per lane; lds dest = wave-uniform base + lane*16
DEVFN void gl_lds16(const bf16* g, short* l) {
    __builtin_amdgcn_global_load_lds(
        (const __attribute__((address_space(1))) unsigned int*)g,
        (__attribute__((address_space(3))) unsigned int*)l, 16, 0, 0);
}
// tanh-form GELU, overflow-safe
DEVFN float fast_gelu(float v) {
    float u = v * (0.7978845608028654f + 0.0356774081f * v * v);
    float e = __expf(2.f * u);
    float th = 1.f - 2.f / (e + 1.f);
    return 0.5f * v * (1.f + th);
}

// ---------------------------------------------------------------------------
// Detect input dtype: fp32 N(0,1) -> low halves random -> exp==0xFF hits.
__global__ __launch_bounds__(256) void detect_kernel(const void* x, int* flag)
{
    __shared__ int any;
    if (threadIdx.x == 0) any = 0;
    __syncthreads();
    const unsigned short* p = (const unsigned short*)x;
    int hit = 0;
    for (int i = threadIdx.x; i < 8192; i += 256) {
        if ((p[i] & 0x7F80u) == 0x7F80u) hit = 1;
    }
    if (hit) any = 1;
    __syncthreads();
    if (threadIdx.x == 0) flag[0] = any;
}

// ---------------------------------------------------------------------------
// Batched convert: 14 segments (12 params + ctx + geo) in ONE launch.
struct CVTab {
    const void* src[14];
    bf16* dst[14];
    int cnt[14];
    int bstart[14];
};
__global__ __launch_bounds__(256) void convert_batch_kernel(
    CVTab tab, const int* __restrict__ flag)
{
    int isf = *flag;
    int b = blockIdx.x;
    int s = 0;
#pragma unroll
    for (int i = 1; i < 14; i++) if (b >= tab.bstart[i]) s = i;
    const void* src = tab.src[s];
    bf16* dst = tab.dst[s];
    int cnt = tab.cnt[s];
    int base = (b - tab.bstart[s]) * 2048;
    int lim = min(base + 2048, cnt);
    for (int i = base + (int)threadIdx.x; i < lim; i += 256)
        dst[i] = f2bf(loadF(src, i, isf));
}

// ---------------------------------------------------------------------------
// Fused: t[b,n,:] = x[b,:,n] + LN1(x_row)  AND  u = bf16(LN2(t_row)).
__global__ __launch_bounds__(256) void ln_in_kernel(
    const void* __restrict__ x, float* __restrict__ t,
    const bf16* __restrict__ g1c, const bf16* __restrict__ b1c,
    const bf16* __restrict__ g2c, const bf16* __restrict__ b2c,
    bf16* __restrict__ u,
    const int* __restrict__ flag, int NN)
{
    __shared__ float tile[16][516];
    int isf = *flag;
    int b = blockIdx.y;
    int n0 = blockIdx.x * 16;
    int tid = threadIdx.x;
    int nx = tid & 15, cy = tid >> 4;
#pragma unroll
    for (int p = 0; p < 32; p++) {
        int c = p * 16 + cy;
        tile[nx][c] = loadF(x, ((size_t)b * 512 + c) * NN + n0 + nx, isf);
    }
    __syncthreads();
    int w = tid >> 6, lane = tid & 63;
    for (int rr = 0; rr < 4; rr++) {
        int r = w * 4 + rr;
        float4 v0 = *(const float4*)&tile[r][lane * 8];
        float4 v1 = *(const float4*)&tile[r][lane * 8 + 4];
        float vals[8] = {v0.x, v0.y, v0.z, v0.w, v1.x, v1.y, v1.z, v1.w};
        float s = 0.f;
#pragma unroll
        for (int i = 0; i < 8; i++) s += vals[i];
#pragma unroll
        for (int off = 32; off; off >>= 1) s += __shfl_xor(s, off, 64);
        float mu = s * (1.f / 512.f);
        float sq = 0.f;
#pragma unroll
        for (int i = 0; i < 8; i++) { float d = vals[i] - mu; sq += d * d; }
#pragma unroll
        for (int off = 32; off; off >>= 1) sq += __shfl_xor(sq, off, 64);
        float rs = rsqrtf(sq * (1.f / 512.f) + 1e-5f);
        float out[8];
#pragma unroll
        for (int i = 0; i < 8; i++) {
            int c = lane * 8 + i;
            out[i] = vals[i] + (vals[i] - mu) * rs * bf2f(g1c[c]) + bf2f(b1c[c]);
        }
        size_t rbase = ((size_t)b * NN + n0 + r) * 512 + lane * 8;
        float* tp = t + rbase;
        *(float4*)tp = make_float4(out[0], out[1], out[2], out[3]);
        *(float4*)(tp + 4) = make_float4(out[4], out[5], out[6], out[7]);
        // second LN (LN2) over the just-computed row -> u
        float s2 = 0.f;
#pragma unroll
        for (int i = 0; i < 8; i++) s2 += out[i];
#pragma unroll
        for (int off = 32; off; off >>= 1) s2 += __shfl_xor(s2, off, 64);
        float mu2 = s2 * (1.f / 512.f);
        float sq2 = 0.f;
#pragma unroll
        for (int i = 0; i < 8; i++) { float d = out[i] - mu2; sq2 += d * d; }
#pragma unroll
        for (int off = 32; off; off >>= 1) sq2 += __shfl_xor(sq2, off, 64);
        float rs2 = rsqrtf(sq2 * (1.f / 512.f) + 1e-5f);
        short4v uo[2];
#pragma unroll
        for (int i = 0; i < 8; i++) {
            int c = lane * 8 + i;
            uo[i >> 2][i & 3] =
                (short)f2bfbits((out[i] - mu2) * rs2 * bf2f(g2c[c]) + bf2f(b2c[c]));
        }
        *(short4v*)((unsigned short*)u + rbase) = uo[0];
        *(short4v*)((unsigned short*)u + rbase + 4) = uo[1];
    }
}

// ---------------------------------------------------------------------------
// Fused residual + LayerNorm: u = bf16(LN(t0 + r1 [+ r2])).
__global__ __launch_bounds__(256) void ln_res_kernel(
    const float* __restrict__ t, const bf16* __restrict__ r1,
    const bf16* __restrict__ r2,
    const bf16* __restrict__ g, const bf16* __restrict__ bta,
    bf16* __restrict__ outp, int Mrows)
{
    int w = threadIdx.x >> 6, lane = threadIdx.x & 63;
    int row = blockIdx.x * 4 + w;
    if (row >= Mrows) return;
    size_t base = (size_t)row * 512 + lane * 8;
    float4 v0 = *(const float4*)(t + base);
    float4 v1 = *(const float4*)(t + base + 4);
    float vals[8] = {v0.x, v0.y, v0.z, v0.w, v1.x, v1.y, v1.z, v1.w};
    {
        short8 a = *(const short8*)((const unsigned short*)r1 + base);
#pragma unroll
        for (int i = 0; i < 8; i++) vals[i] += us2f(((unsigned short*)&a)[i]);
    }
    if (r2) {
        short8 a = *(const short8*)((const unsigned short*)r2 + base);
#pragma unroll
        for (int i = 0; i < 8; i++) vals[i] += us2f(((unsigned short*)&a)[i]);
    }
    float s = 0.f;
#pragma unroll
    for (int i = 0; i < 8; i++) s += vals[i];
#pragma unroll
    for (int off = 32; off; off >>= 1) s += __shfl_xor(s, off, 64);
    float mu = s * (1.f / 512.f);
    float sq = 0.f;
#pragma unroll
    for (int i = 0; i < 8; i++) { float d = vals[i] - mu; sq += d * d; }
#pragma unroll
    for (int off = 32; off; off >>= 1) sq += __shfl_xor(sq, off, 64);
    float rs = rsqrtf(sq * (1.f / 512.f) + 1e-5f);
    short4v uo[2];
#pragma unroll
    for (int i = 0; i < 8; i++) {
        int c = lane * 8 + i;
        uo[i >> 2][i & 3] =
            (short)f2bfbits((vals[i] - mu) * rs * bf2f(g[c]) + bf2f(bta[c]));
    }
    *(short4v*)((unsigned short*)outp + base) = uo[0];
    *(short4v*)((unsigned short*)outp + base + 4) = uo[1];
}

// Transpose (t0 + rc + rg + fb) (B,N,C) -> out (B,C,N) in detected dtype.
__global__ __launch_bounds__(256) void transpose_out_kernel(
    const float* __restrict__ t, const bf16* __restrict__ rc,
    const bf16* __restrict__ rg, const bf16* __restrict__ f,
    void* __restrict__ o, const int* __restrict__ flag,
    int C, int NN)
{
    __shared__ float tile[32][33];
    int isf = *flag;
    int b = blockIdx.z;
    int n0 = blockIdx.x * 32, c0 = blockIdx.y * 32;
    int tx = threadIdx.x, ty = threadIdx.y;
#pragma unroll
    for (int i = 0; i < 4; i++) {
        size_t idx = ((size_t)b * NN + n0 + ty + i * 8) * C + c0 + tx;
        tile[ty + i * 8][tx] = t[idx] + bf2f(rc[idx]) + bf2f(rg[idx]) + bf2f(f[idx]);
    }
    __syncthreads();
#pragma unroll
    for (int i = 0; i < 4; i++) {
        size_t oi = ((size_t)b * C + c0 + ty + i * 8) * NN + n0 + tx;
        float val = tile[tx][ty + i * 8];
        if (isf) ((float*)o)[oi] = val;
        else ((bf16*)o)[oi] = f2bf(val);
    }
}

// ---------------------------------------------------------------------------
// Batched weight transpose: 10 matrices (W KxNc row-major -> WT NcxK bf16)
struct TWTab {
    const void* src[10];
    bf16* dst[10];
    int K[10];
    int Nc[10];
    int tstart[10];
};
__global__ __launch_bounds__(256) void transpose_w_batch(
    TWTab tab, const int* __restrict__ flag)
{
    __shared__ float tile[32][33];
    int isf = *flag;
    int b = blockIdx.x;
    int s = 0;
#pragma unroll
    for (int i = 1; i < 10; i++) if (b >= tab.tstart[i]) s = i;
    const void* Wm = tab.src[s];
    bf16* WT = tab.dst[s];
    int K = tab.K[s], Nc = tab.Nc[s];
    int lt = b - tab.tstart[s];
    int ntx = Nc >> 5;
    int n0 = (lt % ntx) * 32, k0 = (lt / ntx) * 32;
    int tx = threadIdx.x, ty = threadIdx.y;
#pragma unroll
    for (int i = 0; i < 4; i++)
        tile[ty + i * 8][tx] = loadF(Wm, (size_t)(k0 + ty + i * 8) * Nc + n0 + tx, isf);
    __syncthreads();
#pragma unroll
    for (int i = 0; i < 4; i++)
        WT[(size_t)(n0 + ty + i * 8) * K + k0 + tx] = f2bf(tile[tx][ty + i * 8]);
}

// ---------------------------------------------------------------------------
// 64-tile GEMM pair: K and V projections share A; blockIdx.z picks weights.
template <int MODE>
__global__ __launch_bounds__(256) void gemm64x2(
    const bf16* __restrict__ A,
    const bf16* __restrict__ WT0, const bf16* __restrict__ WT1,
    bf16* __restrict__ o0, bf16* __restrict__ o1,
    int M, int K, int Nc)
{
    const bf16* WT = blockIdx.z ? WT1 : WT0;
    bf16* outp = blockIdx.z ? o1 : o0;
    __shared__ short As[64 * 32];
    __shared__ short Bs[64 * 32];
    const int tid = threadIdx.x;
    const int m0 = blockIdx.y * 64;
    const int n0 = blockIdx.x * 64;
    const int w = tid >> 6;
    const int lane = tid & 63;
    const int lm = lane & 15;
    const int lq = lane >> 4;

    floatx4 acc[4];
#pragma unroll
    for (int nb = 0; nb < 4; nb++) acc[nb] = (floatx4){0.f, 0.f, 0.f, 0.f};

    const int srow = tid >> 2;
    const int scol = (tid & 3) << 3;
    const int agrow = m0 + srow;
    const bool aok = agrow < M;
    const bf16* Aptr = A + (size_t)agrow * K + scol;
    const bf16* Bptr = WT + (size_t)(n0 + srow) * K + scol;

    for (int k0 = 0; k0 < K; k0 += 32) {
        __syncthreads();
        int4 av = make_int4(0, 0, 0, 0);
        if (aok) av = *(const int4*)(Aptr + k0);
        *(int4*)(&As[srow * 32 + scol]) = av;
        *(int4*)(&Bs[srow * 32 + scol]) = *(const int4*)(Bptr + k0);
        __syncthreads();
        short8 a = *(const short8*)(&As[(w * 16 + lm) * 32 + lq * 8]);
#pragma unroll
        for (int nb = 0; nb < 4; nb++) {
            short8 b = *(const short8*)(&Bs[(nb * 16 + lm) * 32 + lq * 8]);
            acc[nb] = __builtin_amdgcn_mfma_f32_16x16x32_bf16(a, b, acc[nb], 0, 0, 0);
        }
    }

#pragma unroll
    for (int nb = 0; nb < 4; nb++) {
        int col = n0 + nb * 16 + lm;
#pragma unroll
        for (int r = 0; r < 4; r++) {
            int row = m0 + w * 16 + lq * 4 + r;
            if (row < M) {
                float v = acc[nb][r];
                if (MODE == 1) v = fast_gelu(v);
                outp[(size_t)row * Nc + col] = f2bf(v);
            }
        }
    }
}

// ---------------------------------------------------------------------------
// R10/R11: occupancy-doubled GEMM "gemmO" (resubmit -- r10 bench was an
// infra failure, no data; kernel re-audited: addressing in-bounds, staging
// map wave-linear==row-linear, sigma-swizzle write/read consistent,
// conservative full-drain sync). The invariant across all prior gemm8p
// variants was 96-128KB LDS -> 1 block/CU -> 2 waves/SIMD; counters
// (MfmaUtil 21, VALUBusy 43, HBM 18, conflicts ~0, barrier-count null r9)
// point at latency/dependency-bound at low occupancy. This variant: BM=128,
// BN=128, BK=64, 8 waves (2M x 4N, per-wave 64x32, 8 acc frags), 2x16KB A +
// 2x16KB B = 64KB LDS -> 2 blocks/CU = 4 waves/SIMD; cross-block overlap
// (m114) replaces the deep in-kernel pipeline. Schedule = T3 minimum:
// STAGE(s+1); ds_read(s); setprio(1) MFMA setprio(0);
// lgkmcnt(0)+vmcnt(0)+barrier once per K-tile.
// sigma-swizzle microformat unchanged (slot j of row r holds k-chunk
// j^(r&7), pre-swizzled global source; frag slot lq^(lm&7) / (4+lq)^(lm&7))
// -- conflict-free (r2-verified). XCD-bijective block swizzle unchanged.
// MODE 0: bf16 store (+bias); MODE 1: fast_gelu+bf16 (+bias).
// REQUIRES M%128==0, Nc%128==0, K%64==0, nwg%8==0.
template <int MODE>
__global__ __launch_bounds__(512, 4) void gemmO(
    const bf16* __restrict__ A, const bf16* __restrict__ WT,
    const bf16* __restrict__ bias, bf16* __restrict__ outp,
    int K, int Nc)
{
    __shared__ short As[2 * 8192];   // 2 x [128 rows][64 shorts] = 32 KB
    __shared__ short Bs[2 * 8192];   // 32 KB

    const int tid = threadIdx.x;
    const int gx = gridDim.x;
    int g = blockIdx.y * gx + blockIdx.x;
    const int cpx = (gx * gridDim.y) >> 3;
    g = (g & 7) * cpx + (g >> 3);
    const int m0 = (g / gx) * 128;
    const int n0 = (g % gx) * 128;

    const int w = tid >> 6, lane = tid & 63;
    const int lm = lane & 15, lq = lane >> 4;
    const int wm = w >> 2, wn = w & 3;   // wm: 64-row half, wn: 32-col quarter

    floatx4 acc[2][4];
#pragma unroll
    for (int cb = 0; cb < 2; cb++)
#pragma unroll
        for (int rb = 0; rb < 4; rb++) acc[cb][rb] = (floatx4){0.f, 0.f, 0.f, 0.f};

    // staging: thread -> row rstg (0..63) of each 64-row half; 8 lanes/row.
    // Pre-swizzled global k-chunk = (tid&7) ^ (row&7); (row+64)&7 == row&7.
    // Wave-linear LDS dest (base + lane*16) == row-linear [row][slot] layout.
    const int rstg = tid >> 3;
    const int chk = (((tid & 7) ^ (rstg & 7)) << 3);
    const bf16* pA0 = A + (size_t)(m0 + rstg) * K + chk;
    const bf16* pA1 = A + (size_t)(m0 + 64 + rstg) * K + chk;
    const bf16* pB0 = WT + (size_t)(n0 + rstg) * K + chk;
    const bf16* pB1 = WT + (size_t)(n0 + 64 + rstg) * K + chk;
    const int wb = w * 512;

    auto STAGE = [&](int d, int koff) {
        short* la = As + d * 8192;
        short* lb = Bs + d * 8192;
        gl_lds16(pA0 + koff, la + wb);
        gl_lds16(pA1 + koff, la + 4096 + wb);
        gl_lds16(pB0 + koff, lb + wb);
        gl_lds16(pB1 + koff, lb + 4096 + wb);
    };

    // fragment-read constants (row bases are multiples of 16 -> row&7 == lm&7)
    const int arow = (wm * 64 + lm) * 64;
    const int brow = (wn * 32 + lm) * 64;
    const int sl0 = ((lq ^ (lm & 7)) << 3);
    const int sl1 = (((4 + lq) ^ (lm & 7)) << 3);

    const int nt = K >> 6;
    STAGE(0, 0);
    asm volatile("s_waitcnt vmcnt(0)\n\ts_barrier" ::: "memory");

    for (int s = 0; s < nt; ++s) {
        const short* cA = As + (s & 1) * 8192;
        const short* cB = Bs + (s & 1) * 8192;
        if (s + 1 < nt) STAGE((s + 1) & 1, (s + 1) << 6);
        short8 b00 = *(const short8*)&cB[brow + sl0];
        short8 b01 = *(const short8*)&cB[brow + sl1];
        short8 b10 = *(const short8*)&cB[brow + 1024 + sl0];
        short8 b11 = *(const short8*)&cB[brow + 1024 + sl1];
        short8 a0[4], a1[4];
#pragma unroll
        for (int rb = 0; rb < 4; rb++) {
            a0[rb] = *(const short8*)&cA[arow + rb * 1024 + sl0];
            a1[rb] = *(const short8*)&cA[arow + rb * 1024 + sl1];
        }
        __builtin_amdgcn_s_setprio(1);
#pragma unroll
        for (int rb = 0; rb < 4; rb++) {
            acc[0][rb] = __builtin_amdgcn_mfma_f32_16x16x32_bf16(b00, a0[rb], acc[0][rb], 0, 0, 0);
            acc[0][rb] = __builtin_amdgcn_mfma_f32_16x16x32_bf16(b01, a1[rb], acc[0][rb], 0, 0, 0);
            acc[1][rb] = __builtin_amdgcn_mfma_f32_16x16x32_bf16(b10, a0[rb], acc[1][rb], 0, 0, 0);
            acc[1][rb] = __builtin_amdgcn_mfma_f32_16x16x32_bf16(b11, a1[rb], acc[1][rb], 0, 0, 0);
        }
        __builtin_amdgcn_s_setprio(0);
        if (s + 1 < nt)
            asm volatile("s_waitcnt vmcnt(0) lgkmcnt(0)\n\ts_barrier" ::: "memory");
    }

    // D: out col = n0 + wn*32 + cb*16 + lq*4 + r, row = m0 + wm*64 + rb*16 + lm
    float4 bias2[2];
#pragma unroll
    for (int cb = 0; cb < 2; cb++) {
        if (bias) {
            const bf16* bp = bias + n0 + wn * 32 + cb * 16 + lq * 4;
            bias2[cb] = make_float4(bf2f(bp[0]), bf2f(bp[1]), bf2f(bp[2]), bf2f(bp[3]));
        } else {
            bias2[cb] = make_float4(0.f, 0.f, 0.f, 0.f);
        }
    }
    unsigned short* op = (unsigned short*)outp;
#pragma unroll
    for (int rb = 0; rb < 4; rb++) {
        size_t m = m0 + wm * 64 + rb * 16 + lm;
#pragma unroll
        for (int cb = 0; cb < 2; cb++) {
            short4v pk;
#pragma unroll
            for (int r = 0; r < 4; r++) {
                float vv = acc[cb][rb][r] + ((const float*)&bias2[cb])[r];
                if (MODE == 1) vv = fast_gelu(vv);
                pk[r] = (short)f2bfbits(vv);
            }
            *(short4v*)(op + m * Nc + n0 + wn * 32 + cb * 16 + lq * 4) = pk;
        }
    }
}

// ---------------------------------------------------------------------------
// MFMA attention. Block = one (b,h) x 64-query tile; 4 waves, 16 q each.
template <int SPAD, int SVALID>
__global__ __launch_bounds__(256) void attn_mfma_kernel(
    const bf16* __restrict__ q, const bf16* __restrict__ k, const bf16* __restrict__ v,
    bf16* __restrict__ o, int N)
{
    constexpr int MB = SPAD / 16;   // score m-blocks over s
    constexpr int KS = SPAD / 32;   // PV k-steps over s
    __shared__ unsigned short lds[SPAD * 64 + 64 * SPAD];
    unsigned short* Ks = lds;                 // [s][64], chunk-swizzled by s&7
    unsigned short* Vt = lds + SPAD * 64;     // [d][SPAD], chunk-swizzled by d&7
    unsigned short* Pw = lds;                 // alias (after barrier)

    const int tid = threadIdx.x;
    const int b = blockIdx.x >> 3;
    const int h = blockIdx.x & 7;
    const int n0 = blockIdx.y * 64;
    const int w = tid >> 6, lane = tid & 63;
    const int lm = lane & 15, lq = lane >> 4;

    const unsigned short* kp = (const unsigned short*)k;
    const unsigned short* vp = (const unsigned short*)v;
    for (int idx = tid * 8; idx < SPAD * 64; idx += 2048) {
        int s = idx >> 6, d0 = idx & 63;
        short8 kv = {0, 0, 0, 0, 0, 0, 0, 0};
        short8 vv = {0, 0, 0, 0, 0, 0, 0, 0};
        if (s < SVALID) {
            size_t gb = ((size_t)(b * SVALID + s)) * 512 + h * 64 + d0;
            kv = *(const short8*)(kp + gb);
            vv = *(const short8*)(vp + gb);
        }
        int kc = (d0 >> 3) ^ (s & 7);
        *(short8*)(&Ks[s * 64 + kc * 8]) = kv;
        const unsigned short* vvp = (const unsigned short*)&vv;
#pragma unroll
        for (int i = 0; i < 8; i++) {
            int d = d0 + i;
            int sc = (s >> 3) ^ (d & 7);
            Vt[d * SPAD + sc * 8 + (s & 7)] = vvp[i];
        }
    }

    const int q0 = n0 + w * 16;
    const unsigned short* qp = (const unsigned short*)q;
    size_t qbase = ((size_t)(b * N + q0 + lm)) * 512 + h * 64 + lq * 8;
    short8 qf0 = *(const short8*)(qp + qbase);
    short8 qf1 = *(const short8*)(qp + qbase + 32);
    __syncthreads();

    floatx4 sacc[MB];
#pragma unroll
    for (int mb = 0; mb < MB; mb++) sacc[mb] = (floatx4){0.f, 0.f, 0.f, 0.f};
#pragma unroll
    for (int mb = 0; mb < MB; mb++) {
        int srow = mb * 16 + lm;
        short8 a0 = *(const short8*)(&Ks[srow * 64 + ((lq ^ (lm & 7)) * 8)]);
        short8 a1 = *(const short8*)(&Ks[srow * 64 + (((4 + lq) ^ (lm & 7)) * 8)]);
        sacc[mb] = __builtin_amdgcn_mfma_f32_16x16x32_bf16(a0, qf0, sacc[mb], 0, 0, 0);
        sacc[mb] = __builtin_amdgcn_mfma_f32_16x16x32_bf16(a1, qf1, sacc[mb], 0, 0, 0);
    }

    float mx = -1e30f;
#pragma unroll
    for (int mb = 0; mb < MB; mb++)
#pragma unroll
        for (int r = 0; r < 4; r++) {
            int s = mb * 16 + lq * 4 + r;
            if (s < SVALID) mx = fmaxf(mx, sacc[mb][r]);
        }
    mx = fmaxf(mx, __shfl_xor(mx, 16, 64));
    mx = fmaxf(mx, __shfl_xor(mx, 32, 64));
    mx *= 0.125f;
    float sum = 0.f;
#pragma unroll
    for (int mb = 0; mb < MB; mb++)
#pragma unroll
        for (int r = 0; r < 4; r++) {
            int s = mb * 16 + lq * 4 + r;
            float e = (s < SVALID) ? __expf(sacc[mb][r] * 0.125f - mx) : 0.f;
            sacc[mb][r] = e;
            sum += e;
        }
    sum += __shfl_xor(sum, 16, 64);
    sum += __shfl_xor(sum, 32, 64);
    float inv = 1.f / sum;

    __syncthreads();

    unsigned short* Pme = Pw + w * 16 * SPAD;
#pragma unroll
    for (int mb = 0; mb < MB; mb++) {
        short4v pk;
        pk[0] = (short)f2bfbits(sacc[mb][0] * inv);
        pk[1] = (short)f2bfbits(sacc[mb][1] * inv);
        pk[2] = (short)f2bfbits(sacc[mb][2] * inv);
        pk[3] = (short)f2bfbits(sacc[mb][3] * inv);
        int chunk = (mb * 2 + (lq >> 1)) ^ (lm & 7);
        *(short4v*)(&Pme[lm * SPAD + chunk * 8 + (lq & 1) * 4]) = pk;
    }

    floatx4 oacc[4];
#pragma unroll
    for (int mb2 = 0; mb2 < 4; mb2++) oacc[mb2] = (floatx4){0.f, 0.f, 0.f, 0.f};
    for (int ks = 0; ks < KS; ks++) {
        int sch = ((ks * 4 + lq) ^ (lm & 7)) * 8;
        short8 bfrag = *(const short8*)(&Pme[lm * SPAD + sch]);
#pragma unroll
        for (int mb2 = 0; mb2 < 4; mb2++) {
            int d = mb2 * 16 + lm;
            short8 afrag = *(const short8*)(&Vt[d * SPAD + sch]);
            oacc[mb2] = __builtin_amdgcn_mfma_f32_16x16x32_bf16(afrag, bfrag, oacc[mb2], 0, 0, 0);
        }
    }

#pragma unroll
    for (int mb2 = 0; mb2 < 4; mb2++) {
        short4v ok;
        ok[0] = (short)f2bfbits(oacc[mb2][0]);
        ok[1] = (short)f2bfbits(oacc[mb2][1]);
        ok[2] = (short)f2bfbits(oacc[mb2][2]);
        ok[3] = (short)f2bfbits(oacc[mb2][3]);
        int chunk = (mb2 * 2 + (lq >> 1)) ^ (lm & 7);
        *(short4v*)(&Pme[lm * 64 + chunk * 8 + (lq & 1) * 4]) = ok;
    }
    unsigned short* op = (unsigned short*)o;
#pragma unroll
    for (int p = 0; p < 2; p++) {
        int row = p * 8 + (lane >> 3);
        int chunk = lane & 7;
        short8 ov = *(const short8*)(&Pme[row * 64 + ((chunk ^ (row & 7)) * 8)]);
        *(short8*)(op + ((size_t)(b * N + n0 + w * 16 + row)) * 512 + h * 64 + chunk * 8) = ov;
    }
}

// ---------------------------------------------------------------------------
extern "C" void kernel_launch(void* const* d_in, const int* in_sizes, int n_in,
                              void* d_out, int out_size, void* d_ws, size_t ws_size,
                              hipStream_t stream)
{
    const void* x   = d_in[0];
    const void* ctx = d_in[1];
    const void* geo = d_in[2];
    const void* g1 = d_in[3];  const void* b1 = d_in[4];
    const void* g2 = d_in[5];  const void* b2 = d_in[6];
    const void* g3 = d_in[7];  const void* b3 = d_in[8];
    const void* g4 = d_in[9];  const void* b4 = d_in[10];
    const void* cWq = d_in[11]; const void* cWk = d_in[12];
    const void* cWv = d_in[13]; const void* cWo = d_in[14];
    const void* cbo = d_in[15];
    const void* gWq = d_in[16]; const void* gWk = d_in[17];
    const void* gWv = d_in[18]; const void* gWo = d_in[19];
    const void* gbo = d_in[20];
    const void* W1 = d_in[21];  const void* bf1 = d_in[22];
    const void* W2 = d_in[23];  const void* bf2 = d_in[24];

    const int B = 4, C = 512, NN = 4096;
    const int M = B * NN;  // 16384 token rows

    char* ws = (char*)d_ws;
    size_t off = 0;
    auto alloc = [&](size_t bytes) -> void* {
        void* p = ws + off; off += (bytes + 255) & ~(size_t)255; return p;
    };
    int*   flag = (int*)alloc(256);
    float* t  = (float*)alloc((size_t)M * C * 4);        // fp32 residual base (written once)
    bf16* u   = (bf16*)alloc((size_t)M * C * 2);         // LN out; ob aliases u
    bf16* qb  = (bf16*)alloc((size_t)M * C * 2);         // Q
    bf16* rc  = (bf16*)alloc((size_t)M * C * 2);         // ctx-attn branch output
    bf16* rg  = (bf16*)alloc((size_t)M * C * 2);         // geo-attn branch output
    bf16* fb  = (bf16*)alloc((size_t)M * C * 2);         // FFN branch output
    bf16* kb  = (bf16*)alloc((size_t)B * 256 * C * 2);
    bf16* vb  = (bf16*)alloc((size_t)B * 256 * C * 2);
    bf16* ctxb = (bf16*)alloc((size_t)B * 77 * 768 * 2);
    bf16* geob = (bf16*)alloc((size_t)B * 256 * 512 * 2);
    bf16* cWqT = (bf16*)alloc((size_t)512 * 512 * 2);
    bf16* cWkT = (bf16*)alloc((size_t)512 * 768 * 2);
    bf16* cWvT = (bf16*)alloc((size_t)512 * 768 * 2);
    bf16* cWoT = (bf16*)alloc((size_t)512 * 512 * 2);
    bf16* gWqT = (bf16*)alloc((size_t)512 * 512 * 2);
    bf16* gWkT = (bf16*)alloc((size_t)512 * 512 * 2);
    bf16* gWvT = (bf16*)alloc((size_t)512 * 512 * 2);
    bf16* gWoT = (bf16*)alloc((size_t)512 * 512 * 2);
    bf16* W1T  = (bf16*)alloc((size_t)2048 * 512 * 2);
    bf16* W2T  = (bf16*)alloc((size_t)512 * 2048 * 2);
    bf16* prm  = (bf16*)alloc((size_t)7680 * 2);
    bf16* ob = u;   // attention output aliases u (u dead after Q projection)

    // FFN hidden buffer: pick largest chunking the workspace allows
    int chunk;
    bf16* hb;
    size_t rem = (ws_size > off) ? (ws_size - off) : 0;
    if (rem >= (size_t)16384 * 2048 * 2) { chunk = 16384; hb = (bf16*)alloc((size_t)16384 * 2048 * 2); }
    else if (rem >= (size_t)8192 * 2048 * 2) { chunk = 8192; hb = (bf16*)alloc((size_t)8192 * 2048 * 2); }
    else { chunk = 4096; hb = qb; }  // alias qb (dead after attention)
    (void)in_sizes; (void)n_in; (void)out_size;

    // param block layout (bf16)
    bf16 *pg1 = prm, *pb1 = prm + 512, *pg2 = prm + 1024, *pb2 = prm + 1536;
    bf16 *pg3 = prm + 2048, *pb3 = prm + 2560, *pg4 = prm + 3072, *pb4 = prm + 3584;
    bf16 *pcbo = prm + 4096, *pgbo = prm + 4608, *pbf1 = prm + 5120, *pbf2 = prm + 7168;

    dim3 tb(32, 8);

    // dtype detection
    detect_kernel<<<1, 256, 0, stream>>>(x, flag);

    // ---- batched conversion: 12 params + ctx + geo in ONE launch ----
    {
        CVTab cv;
        const void* csrc[14] = {g1, b1, g2, b2, g3, b3, g4, b4, cbo, gbo, bf1, bf2, ctx, geo};
        bf16* cdst[14] = {prm, prm + 512, prm + 1024, prm + 1536, prm + 2048, prm + 2560,
                          prm + 3072, prm + 3584, prm + 4096, prm + 4608, prm + 5120,
                          prm + 7168, ctxb, geob};
        int ccnt[14] = {512, 512, 512, 512, 512, 512, 512, 512, 512, 512, 2048, 512,
                        B * 77 * 768, B * 256 * 512};
        int bacc = 0;
        for (int i = 0; i < 14; i++) {
            cv.src[i] = csrc[i]; cv.dst[i] = cdst[i]; cv.cnt[i] = ccnt[i];
            cv.bstart[i] = bacc;
            bacc += (ccnt[i] + 2047) / 2048;
        }
        convert_batch_kernel<<<bacc, 256, 0, stream>>>(cv, flag);
    }

    // fused: t = transpose(x) + LN1; u = LN2(t)
    ln_in_kernel<<<dim3(NN / 16, B), 256, 0, stream>>>(x, t, pg1, pb1, pg2, pb2, u, flag, NN);

    // ---- batched weight transposes: 10 matrices in ONE launch ----
    {
        TWTab tw;
        const void* wsrc[10] = {cWq, cWk, cWv, cWo, gWq, gWk, gWv, gWo, W1, W2};
        bf16* wdst[10] = {cWqT, cWkT, cWvT, cWoT, gWqT, gWkT, gWvT, gWoT, W1T, W2T};
        int wK[10]  = {512, 768, 768, 512, 512, 512, 512, 512, 512, 2048};
        int wNc[10] = {512, 512, 512, 512, 512, 512, 512, 512, 2048, 512};
        int tacc = 0;
        for (int i = 0; i < 10; i++) {
            tw.src[i] = wsrc[i]; tw.dst[i] = wdst[i]; tw.K[i] = wK[i]; tw.Nc[i] = wNc[i];
            tw.tstart[i] = tacc;
            tacc += (wNc[i] / 32) * (wK[i] / 32);
        }
        transpose_w_batch<<<tacc, tb, 0, stream>>>(tw, flag);
    }

    // ---- context cross-attention (branch output rc, residual deferred) ----
    gemmO<0><<<dim3(4, M / 128), 512, 0, stream>>>(u, cWqT, nullptr, qb, 512, 512);
    gemm64x2<0><<<dim3(8, (308 + 63) / 64, 2), 256, 0, stream>>>(ctxb, cWkT, cWvT, kb, vb, 308, 768, 512);
    attn_mfma_kernel<128, 77><<<dim3(B * 8, NN / 64), 256, 0, stream>>>(qb, kb, vb, ob, NN);
    gemmO<0><<<dim3(4, M / 128), 512, 0, stream>>>(ob, cWoT, pcbo, rc, 512, 512);
    ln_res_kernel<<<M / 4, 256, 0, stream>>>(t, rc, nullptr, pg3, pb3, u, M);

    // ---- geometry cross-attention (branch output rg) ----
    gemmO<0><<<dim3(4, M / 128), 512, 0, stream>>>(u, gWqT, nullptr, qb, 512, 512);
    gemm64x2<0><<<dim3(8, 1024 / 64, 2), 256, 0, stream>>>(geob, gWkT, gWvT, kb, vb, 1024, 512, 512);
    attn_mfma_kernel<256, 256><<<dim3(B * 8, NN / 64), 256, 0, stream>>>(qb, kb, vb, ob, NN);
    gemmO<0><<<dim3(4, M / 128), 512, 0, stream>>>(ob, gWoT, pgbo, rg, 512, 512);
    ln_res_kernel<<<M / 4, 256, 0, stream>>>(t, rc, rg, pg4, pb4, u, M);

    // ---- FFN (ws-adaptive chunking); branch output fb ----
    for (int mc = 0; mc < M / chunk; mc++) {
        bf16* uc = u + (size_t)mc * chunk * 512;
        bf16* fc = fb + (size_t)mc * chunk * 512;
        gemmO<1><<<dim3(2048 / 128, chunk / 128), 512, 0, stream>>>(uc, W1T, pbf1, hb, 512, 2048);
        gemmO<0><<<dim3(512 / 128, chunk / 128), 512, 0, stream>>>(hb, W2T, pbf2, fc, 2048, 512);
    }

    // out = transpose(t + rc + rg + fb) in detected dtype
    transpose_out_kernel<<<dim3(NN / 32, C / 32, B), tb, 0, stream>>>(t, rc, rg, fb, d_out, flag, C, NN);
}